// Round 1
// baseline (5634.278 us; speedup 1.0000x reference)
//
#include <hip/hip_runtime.h>
#include <math.h>

// ---------------- constants ----------------
#define NTOK   8192
#define INDIM  1024
#define DMODEL 512
#define NHEAD  8
#define DH     64
#define N1     8282      // tokens incl cls (91*91 + 1)
#define NP     8448      // padded token count inside attention
#define PAD    166
#define NLM    256       // landmarks
#define LCH    33        // tokens per landmark chunk
#define SCALE  0.125f
#define HS     91

// ---------------- reduce helpers (256-thread blocks) ----------------
__device__ __forceinline__ float blockReduceSumF(float v, float* red, int tid) {
    red[tid] = v; __syncthreads();
    for (int s = 128; s > 0; s >>= 1) {
        if (tid < s) red[tid] += red[tid + s];
        __syncthreads();
    }
    float r = red[0]; __syncthreads();
    return r;
}
__device__ __forceinline__ float blockReduceMaxF(float v, float* red, int tid) {
    red[tid] = v; __syncthreads();
    for (int s = 128; s > 0; s >>= 1) {
        if (tid < s) red[tid] = fmaxf(red[tid], red[tid + s]);
        __syncthreads();
    }
    float r = red[0]; __syncthreads();
    return r;
}

// ---------------- generic f32 GEMM: C = [res +] A@B [+ bias] [relu] ----------------
// A: MxK row-major, B: KxN row-major, C: MxN. N%64==0, K%16==0. M guarded.
__global__ __launch_bounds__(256) void gemm_f32(
    const float* __restrict__ A, const float* __restrict__ B,
    const float* __restrict__ bias, const float* __restrict__ res,
    float* __restrict__ C, int M, int N, int K, int relu)
{
    __shared__ float As[16][68];
    __shared__ float Bs[16][64];
    int tid = threadIdx.x;
    int row0 = blockIdx.y * 64, col0 = blockIdx.x * 64;
    int tx = tid & 15, ty = tid >> 4;
    int aRow = tid >> 2, aK = (tid & 3) * 4;
    int bRow = tid >> 4, bCol = (tid & 15) * 4;
    float acc[4][4] = {};
    for (int kb = 0; kb < K; kb += 16) {
        int ar = row0 + aRow;
        float4 a4 = make_float4(0.f, 0.f, 0.f, 0.f);
        if (ar < M) a4 = *reinterpret_cast<const float4*>(A + (size_t)ar * K + kb + aK);
        As[aK + 0][aRow] = a4.x; As[aK + 1][aRow] = a4.y;
        As[aK + 2][aRow] = a4.z; As[aK + 3][aRow] = a4.w;
        float4 b4 = *reinterpret_cast<const float4*>(B + (size_t)(kb + bRow) * N + col0 + bCol);
        *reinterpret_cast<float4*>(&Bs[bRow][bCol]) = b4;
        __syncthreads();
#pragma unroll
        for (int k = 0; k < 16; ++k) {
            float a[4], b[4];
#pragma unroll
            for (int i = 0; i < 4; ++i) a[i] = As[k][ty * 4 + i];
#pragma unroll
            for (int j = 0; j < 4; ++j) b[j] = Bs[k][tx * 4 + j];
#pragma unroll
            for (int i = 0; i < 4; ++i)
#pragma unroll
                for (int j = 0; j < 4; ++j) acc[i][j] += a[i] * b[j];
        }
        __syncthreads();
    }
#pragma unroll
    for (int i = 0; i < 4; ++i) {
        int r = row0 + ty * 4 + i;
        if (r >= M) continue;
#pragma unroll
        for (int j = 0; j < 4; ++j) {
            int c = col0 + tx * 4 + j;
            float v = acc[i][j];
            if (bias) v += bias[c];
            if (res)  v += res[(size_t)r * N + c];
            if (relu) v = fmaxf(v, 0.f);
            C[(size_t)r * N + c] = v;
        }
    }
}

// ---------------- batched 256x256x256 GEMM (per head): C = diag*I + ss*(A@B) ----------------
__global__ __launch_bounds__(256) void bgemm256(
    const float* __restrict__ A, const float* __restrict__ B, float* __restrict__ C,
    float diag, float ss)
{
    __shared__ float As[16][68];
    __shared__ float Bs[16][64];
    int hH = blockIdx.z;
    const float* Ah = A + (size_t)hH * 65536;
    const float* Bh = B + (size_t)hH * 65536;
    float* Ch = C + (size_t)hH * 65536;
    int tid = threadIdx.x;
    int row0 = blockIdx.y * 64, col0 = blockIdx.x * 64;
    int tx = tid & 15, ty = tid >> 4;
    int aRow = tid >> 2, aK = (tid & 3) * 4;
    int bRow = tid >> 4, bCol = (tid & 15) * 4;
    float acc[4][4] = {};
    for (int kb = 0; kb < 256; kb += 16) {
        float4 a4 = *reinterpret_cast<const float4*>(Ah + (size_t)(row0 + aRow) * 256 + kb + aK);
        As[aK + 0][aRow] = a4.x; As[aK + 1][aRow] = a4.y;
        As[aK + 2][aRow] = a4.z; As[aK + 3][aRow] = a4.w;
        float4 b4 = *reinterpret_cast<const float4*>(Bh + (size_t)(kb + bRow) * 256 + col0 + bCol);
        *reinterpret_cast<float4*>(&Bs[bRow][bCol]) = b4;
        __syncthreads();
#pragma unroll
        for (int k = 0; k < 16; ++k) {
            float a[4], b[4];
#pragma unroll
            for (int i = 0; i < 4; ++i) a[i] = As[k][ty * 4 + i];
#pragma unroll
            for (int j = 0; j < 4; ++j) b[j] = Bs[k][tx * 4 + j];
#pragma unroll
            for (int i = 0; i < 4; ++i)
#pragma unroll
                for (int j = 0; j < 4; ++j) acc[i][j] += a[i] * b[j];
        }
        __syncthreads();
    }
#pragma unroll
    for (int i = 0; i < 4; ++i) {
        int r = row0 + ty * 4 + i;
#pragma unroll
        for (int j = 0; j < 4; ++j) {
            int c = col0 + tx * 4 + j;
            float v = ss * acc[i][j];
            if (r == c) v += diag;
            Ch[(size_t)r * 256 + c] = v;
        }
    }
}

// ---------------- fixup: cls token + wrap rows ----------------
__global__ void fixup_k(const float* __restrict__ cls, float* __restrict__ h)
{
    int i = blockIdx.x * 256 + threadIdx.x;   // 90*512
    if (i < 512) {
        h[i] = cls[i];
    } else {
        int j = i - 512;                       // j < 89*512
        h[(size_t)8193 * 512 + j] = h[512 + j];
    }
}

// ---------------- layernorm + front zero-pad: out[NP][512] ----------------
__global__ __launch_bounds__(256) void ln_pad_k(
    const float* __restrict__ h, const float* __restrict__ g, const float* __restrict__ b,
    float* __restrict__ out)
{
    int row = blockIdx.x, tid = threadIdx.x;
    __shared__ float red[256];
    float* o = out + (size_t)row * 512;
    if (row < PAD) { o[tid] = 0.f; o[tid + 256] = 0.f; return; }
    const float* x = h + (size_t)(row - PAD) * 512;
    float v0 = x[tid], v1 = x[tid + 256];
    float mu = blockReduceSumF(v0 + v1, red, tid) * (1.f / 512.f);
    float d0 = v0 - mu, d1 = v1 - mu;
    float var = blockReduceSumF(d0 * d0 + d1 * d1, red, tid) * (1.f / 512.f);
    float rstd = rsqrtf(var + 1e-5f);
    o[tid]       = d0 * rstd * g[tid] + b[tid];
    o[tid + 256] = d1 * rstd * g[tid + 256] + b[tid + 256];
}

// ---------------- landmark means (q scaled) ----------------
__global__ void landmark_k(const float* __restrict__ qkv, float* __restrict__ ql, float* __restrict__ kl)
{
    int h = blockIdx.x >> 8, m = blockIdx.x & 255, d = threadIdx.x;  // 64 threads
    const float* base = qkv + (size_t)(m * LCH) * 1536 + h * 64 + d;
    float sq = 0.f, sk = 0.f;
    for (int i = 0; i < LCH; ++i) {
        sq += base[(size_t)i * 1536];
        sk += base[(size_t)i * 1536 + 512];
    }
    ql[((size_t)h * 256 + m) * 64 + d] = sq * (SCALE / (float)LCH);
    kl[((size_t)h * 256 + m) * 64 + d] = sk * (1.f / (float)LCH);
}

// ---------------- a2 = softmax(ql @ kl^T) ----------------
__global__ __launch_bounds__(256) void a2_k(
    const float* __restrict__ ql, const float* __restrict__ kl, float* __restrict__ a2)
{
    int h = blockIdx.x >> 8, r = blockIdx.x & 255, tid = threadIdx.x;
    __shared__ float qv[64]; __shared__ float red[256];
    if (tid < 64) qv[tid] = ql[((size_t)h * 256 + r) * 64 + tid];
    __syncthreads();
    const float* kp = kl + ((size_t)h * 256 + tid) * 64;
    float dot = 0.f;
#pragma unroll
    for (int d = 0; d < 64; ++d) dot += qv[d] * kp[d];
    float mx = blockReduceMaxF(dot, red, tid);
    float e = expf(dot - mx);
    float s = blockReduceSumF(e, red, tid);
    a2[((size_t)h * 256 + r) * 256 + tid] = e / s;
}

// ---------------- pinv init helpers ----------------
__global__ __launch_bounds__(256) void rowsum_k(const float* __restrict__ a2, float* __restrict__ rs)
{
    int r = blockIdx.x; __shared__ float red[256];
    float v = fabsf(a2[(size_t)r * 256 + threadIdx.x]);
    float s = blockReduceSumF(v, red, threadIdx.x);
    if (!threadIdx.x) rs[r] = s;
}
__global__ __launch_bounds__(256) void colsum_k(const float* __restrict__ a2, float* __restrict__ cs)
{
    int h = blockIdx.x >> 8, c = blockIdx.x & 255;
    __shared__ float red[256];
    float v = fabsf(a2[(size_t)h * 65536 + (size_t)threadIdx.x * 256 + c]);
    float s = blockReduceSumF(v, red, threadIdx.x);
    if (!threadIdx.x) cs[blockIdx.x] = s;
}
__global__ __launch_bounds__(256) void pinv_scal_k(const float* __restrict__ rs, const float* __restrict__ cs,
                                                   float* __restrict__ scal)
{
    int tid = threadIdx.x; __shared__ float red[256];
    float m1 = -1e30f, m2 = -1e30f;
    for (int i = tid; i < 2048; i += 256) { m1 = fmaxf(m1, rs[i]); m2 = fmaxf(m2, cs[i]); }
    m1 = blockReduceMaxF(m1, red, tid);
    m2 = blockReduceMaxF(m2, red, tid);
    if (!tid) scal[0] = 1.f / (m1 * m2);
}
__global__ __launch_bounds__(256) void zinit_k(const float* __restrict__ a2, const float* __restrict__ scal,
                                               float* __restrict__ z)
{
    int h = blockIdx.x >> 8, r = blockIdx.x & 255, c = threadIdx.x;
    z[(size_t)h * 65536 + (size_t)r * 256 + c] = a2[(size_t)h * 65536 + (size_t)c * 256 + r] * scal[0];
}
__global__ __launch_bounds__(256) void diag7_k(const float* __restrict__ xz, float* __restrict__ t1)
{
    size_t i = (size_t)blockIdx.x * 256 + threadIdx.x;   // 8*65536
    int rc = (int)(i & 65535);
    float v = -xz[i];
    if ((rc >> 8) == (rc & 255)) v += 7.f;
    t1[i] = v;
}

// ---------------- av = softmax(ql @ k^T) @ v  (block per head,landmark) ----------------
__global__ __launch_bounds__(256) void av_k(const float* __restrict__ ql, const float* __restrict__ qkv,
                                            float* __restrict__ av)
{
    int h = blockIdx.x >> 8, m = blockIdx.x & 255, tid = threadIdx.x;
    __shared__ float sc[NP];
    __shared__ float red[256];
    __shared__ float qv[64];
    if (tid < 64) qv[tid] = ql[((size_t)h * 256 + m) * 64 + tid];
    __syncthreads();
    float lmax = -1e30f;
    for (int t = tid; t < NP; t += 256) {
        const float* kp = qkv + (size_t)t * 1536 + 512 + h * 64;
        float dot = 0.f;
#pragma unroll
        for (int d = 0; d < 64; ++d) dot += qv[d] * kp[d];
        sc[t] = dot; lmax = fmaxf(lmax, dot);
    }
    float gmax = blockReduceMaxF(lmax, red, tid);
    float lsum = 0.f;
    for (int t = tid; t < NP; t += 256) { float e = expf(sc[t] - gmax); sc[t] = e; lsum += e; }
    float gsum = blockReduceSumF(lsum, red, tid);
    __syncthreads();
    int w = tid >> 6, d = tid & 63;
    const float* vp = qkv + 1024 + (size_t)h * 64 + d;
    float acc = 0.f;
    for (int t = w * (NP / 4); t < (w + 1) * (NP / 4); ++t)
        acc += sc[t] * vp[(size_t)t * 1536];
    red[tid] = acc; __syncthreads();
    if (tid < 64) {
        float tot = red[d] + red[64 + d] + red[128 + d] + red[192 + d];
        av[((size_t)h * 256 + m) * 64 + d] = tot / gsum;
    }
}

// ---------------- W = z @ av (per head 256x256 @ 256x64) ----------------
__global__ void wmat_k(const float* __restrict__ z, const float* __restrict__ av, float* __restrict__ W)
{
    int h = blockIdx.x >> 8, m = blockIdx.x & 255, d = threadIdx.x;  // 64 threads
    const float* zp = z + (size_t)h * 65536 + (size_t)m * 256;
    const float* ap = av + (size_t)h * 16384 + d;
    float acc = 0.f;
    for (int j = 0; j < 256; ++j) acc += zp[j] * ap[(size_t)j * 64];
    W[((size_t)h * 256 + m) * 64 + d] = acc;
}

// ---------------- attn_out = softmax(q @ kl^T) @ W  (block per token,head) ----------------
__global__ __launch_bounds__(256) void a1w_k(const float* __restrict__ qkv, const float* __restrict__ kl,
                                             const float* __restrict__ W, float* __restrict__ attn)
{
    int t = blockIdx.x >> 3, h = blockIdx.x & 7, tid = threadIdx.x;
    __shared__ float qv[64]; __shared__ float p[256]; __shared__ float red[256];
    if (tid < 64) qv[tid] = qkv[(size_t)t * 1536 + h * 64 + tid] * SCALE;
    __syncthreads();
    const float* kp = kl + ((size_t)h * 256 + tid) * 64;
    float dot = 0.f;
#pragma unroll
    for (int d = 0; d < 64; ++d) dot += qv[d] * kp[d];
    float mx = blockReduceMaxF(dot, red, tid);
    float e = expf(dot - mx);
    p[tid] = e;
    float gsum = blockReduceSumF(e, red, tid);
    int w = tid >> 6, d = tid & 63;
    const float* wp = W + (size_t)h * 16384 + d;
    float acc = 0.f;
    for (int m = w * 64; m < w * 64 + 64; ++m) acc += p[m] * wp[(size_t)m * 64];
    red[tid] = acc; __syncthreads();
    if (tid < 64) {
        float tot = red[d] + red[64 + d] + red[128 + d] + red[192 + d];
        attn[(size_t)t * 512 + h * 64 + d] = tot / gsum;
    }
}

// ---------------- depthwise 33-tap conv over tokens on v, added to attn ----------------
__global__ void conv_k(const float* __restrict__ qkv, const float* __restrict__ cw, float* __restrict__ attn)
{
    int idx = blockIdx.x * 256 + threadIdx.x;   // NP*512
    int t = idx >> 9, c = idx & 511, h = c >> 6;
    float acc = 0.f;
#pragma unroll
    for (int j = 0; j < 33; ++j) {
        int tt = t + j - 16;
        if (tt >= 0 && tt < NP) acc += cw[h * 33 + j] * qkv[(size_t)tt * 1536 + 1024 + c];
    }
    attn[idx] += acc;
}

// ---------------- PPEG: depthwise 7x7+5x5+3x3 on 91x91 grid ----------------
__global__ void ppeg_k(const float* __restrict__ hin,
                       const float* __restrict__ w7, const float* __restrict__ b7,
                       const float* __restrict__ w5, const float* __restrict__ b5,
                       const float* __restrict__ w3, const float* __restrict__ b3,
                       float* __restrict__ hout)
{
    int idx = blockIdx.x * 256 + threadIdx.x;   // N1*512
    int tok = idx >> 9, c = idx & 511;
    if (tok == 0) { hout[idx] = hin[idx]; return; }
    int y = (tok - 1) / HS, x = (tok - 1) % HS;
    float acc = hin[idx] + b7[c] + b5[c] + b3[c];
    const float* wp7 = w7 + (size_t)c * 49;
#pragma unroll
    for (int ky = 0; ky < 7; ++ky) {
        int yy = y + ky - 3; if (yy < 0 || yy >= HS) continue;
#pragma unroll
        for (int kx = 0; kx < 7; ++kx) {
            int xx = x + kx - 3; if (xx < 0 || xx >= HS) continue;
            acc += wp7[ky * 7 + kx] * hin[(size_t)(1 + yy * HS + xx) * 512 + c];
        }
    }
    const float* wp5 = w5 + (size_t)c * 25;
#pragma unroll
    for (int ky = 0; ky < 5; ++ky) {
        int yy = y + ky - 2; if (yy < 0 || yy >= HS) continue;
#pragma unroll
        for (int kx = 0; kx < 5; ++kx) {
            int xx = x + kx - 2; if (xx < 0 || xx >= HS) continue;
            acc += wp5[ky * 5 + kx] * hin[(size_t)(1 + yy * HS + xx) * 512 + c];
        }
    }
    const float* wp3 = w3 + (size_t)c * 9;
#pragma unroll
    for (int ky = 0; ky < 3; ++ky) {
        int yy = y + ky - 1; if (yy < 0 || yy >= HS) continue;
#pragma unroll
        for (int kx = 0; kx < 3; ++kx) {
            int xx = x + kx - 1; if (xx < 0 || xx >= HS) continue;
            acc += wp3[ky * 3 + kx] * hin[(size_t)(1 + yy * HS + xx) * 512 + c];
        }
    }
    hout[idx] = acc;
}

// ---------------- final LN(row0) + fc2 + softmax + argmax ----------------
__global__ __launch_bounds__(256) void final_k(const float* __restrict__ h,
                                               const float* __restrict__ g, const float* __restrict__ bb,
                                               const float* __restrict__ w, const float* __restrict__ fb,
                                               float* __restrict__ out)
{
    __shared__ float red[256];
    int tid = threadIdx.x;
    float v0 = h[tid], v1 = h[tid + 256];
    float mu = blockReduceSumF(v0 + v1, red, tid) * (1.f / 512.f);
    float d0 = v0 - mu, d1 = v1 - mu;
    float var = blockReduceSumF(d0 * d0 + d1 * d1, red, tid) * (1.f / 512.f);
    float rstd = rsqrtf(var + 1e-5f);
    float e0 = d0 * rstd * g[tid] + bb[tid];
    float e1 = d1 * rstd * g[tid + 256] + bb[tid + 256];
    out[5 + tid] = e0;
    out[5 + 256 + tid] = e1;
    float l0p = e0 * w[tid * 2] + e1 * w[(tid + 256) * 2];
    float l1p = e0 * w[tid * 2 + 1] + e1 * w[(tid + 256) * 2 + 1];
    float l0 = blockReduceSumF(l0p, red, tid);
    float l1 = blockReduceSumF(l1p, red, tid);
    if (!tid) {
        l0 += fb[0]; l1 += fb[1];
        out[0] = l0; out[1] = l1;
        float mx = fmaxf(l0, l1);
        float p0 = expf(l0 - mx), p1 = expf(l1 - mx);
        float si = 1.f / (p0 + p1);
        out[2] = p0 * si; out[3] = p1 * si;
        out[4] = (l1 > l0) ? 1.f : 0.f;
    }
}

// ---------------- host orchestration ----------------
struct WsPtrs {
    float *h, *h2, *xb, *qkv, *ql, *kl, *a2, *z, *z2, *xz, *t1, *t2, *av, *W, *rs, *cs, *scal;
};

static void run_attn(float* hbuf, const float* ln_g, const float* ln_b,
                     const float* qkv_w, const float* out_w, const float* out_b,
                     const float* conv_w, const WsPtrs& P, hipStream_t s)
{
    // layernorm + pad -> xb
    ln_pad_k<<<NP, 256, 0, s>>>(hbuf, ln_g, ln_b, P.xb);
    // qkv = xb @ qkv_w   (NP x 1536)
    gemm_f32<<<dim3(1536 / 64, NP / 64), 256, 0, s>>>(P.xb, qkv_w, nullptr, nullptr, P.qkv,
                                                      NP, 1536, 512, 0);
    // landmarks
    landmark_k<<<2048, 64, 0, s>>>(P.qkv, P.ql, P.kl);
    // a2 softmax
    a2_k<<<2048, 256, 0, s>>>(P.ql, P.kl, P.a2);
    // pinv init
    rowsum_k<<<2048, 256, 0, s>>>(P.a2, P.rs);
    colsum_k<<<2048, 256, 0, s>>>(P.a2, P.cs);
    pinv_scal_k<<<1, 256, 0, s>>>(P.rs, P.cs, P.scal);
    zinit_k<<<2048, 256, 0, s>>>(P.a2, P.scal, P.z);
    // 6 pinv iterations
    float* za = P.z; float* zb = P.z2;
    for (int it = 0; it < 6; ++it) {
        bgemm256<<<dim3(4, 4, 8), 256, 0, s>>>(P.a2, za, P.xz, 0.f, 1.f);
        diag7_k<<<2048, 256, 0, s>>>(P.xz, P.t1);
        bgemm256<<<dim3(4, 4, 8), 256, 0, s>>>(P.xz, P.t1, P.t2, 15.f, -1.f);
        bgemm256<<<dim3(4, 4, 8), 256, 0, s>>>(P.xz, P.t2, P.t1, 13.f, -1.f);
        bgemm256<<<dim3(4, 4, 8), 256, 0, s>>>(za, P.t1, zb, 0.f, 0.25f);
        float* tmp = za; za = zb; zb = tmp;
    }
    // av = softmax(ql @ k^T) @ v
    av_k<<<2048, 256, 0, s>>>(P.ql, P.qkv, P.av);
    // W = z @ av
    wmat_k<<<2048, 64, 0, s>>>(za, P.av, P.W);
    // attn(token-major, into xb) = softmax(q @ kl^T) @ W
    a1w_k<<<NP * 8, 256, 0, s>>>(P.qkv, P.kl, P.W, P.xb);
    // += depthwise conv on v
    conv_k<<<NP * 512 / 256, 256, 0, s>>>(P.qkv, conv_w, P.xb);
    // h += (attn[-N1:] @ out_w + out_b)   (in-place residual)
    gemm_f32<<<dim3(512 / 64, (N1 + 63) / 64), 256, 0, s>>>(P.xb + (size_t)PAD * 512, out_w,
                                                            out_b, hbuf, hbuf, N1, 512, 512, 0);
}

extern "C" void kernel_launch(void* const* d_in, const int* in_sizes, int n_in,
                              void* d_out, int out_size, void* d_ws, size_t ws_size,
                              hipStream_t stream)
{
    (void)in_sizes; (void)n_in; (void)out_size; (void)ws_size;
    const float* x       = (const float*)d_in[0];
    const float* fc1_w   = (const float*)d_in[1];
    const float* fc1_b   = (const float*)d_in[2];
    const float* cls_tok = (const float*)d_in[3];
    const float* ln1_g   = (const float*)d_in[4];
    const float* ln1_b   = (const float*)d_in[5];
    const float* qkv1_w  = (const float*)d_in[6];
    const float* out1_w  = (const float*)d_in[7];
    const float* out1_b  = (const float*)d_in[8];
    const float* conv1_w = (const float*)d_in[9];
    const float* ln2_g   = (const float*)d_in[10];
    const float* ln2_b   = (const float*)d_in[11];
    const float* qkv2_w  = (const float*)d_in[12];
    const float* out2_w  = (const float*)d_in[13];
    const float* out2_b  = (const float*)d_in[14];
    const float* conv2_w = (const float*)d_in[15];
    const float* pg7_w   = (const float*)d_in[16];
    const float* pg7_b   = (const float*)d_in[17];
    const float* pg5_w   = (const float*)d_in[18];
    const float* pg5_b   = (const float*)d_in[19];
    const float* pg3_w   = (const float*)d_in[20];
    const float* pg3_b   = (const float*)d_in[21];
    const float* norm_g  = (const float*)d_in[22];
    const float* norm_b  = (const float*)d_in[23];
    const float* fc2_w   = (const float*)d_in[24];
    const float* fc2_b   = (const float*)d_in[25];

    float* ws = (float*)d_ws;
    WsPtrs P;
    P.h    = ws;
    P.h2   = P.h   + (size_t)N1 * 512;        // 4,240,384
    P.xb   = P.h2  + (size_t)N1 * 512;        // ln out / attn out (NP*512)
    P.qkv  = P.xb  + (size_t)NP * 512;        // NP*1536
    P.ql   = P.qkv + (size_t)NP * 1536;
    P.kl   = P.ql  + 131072;
    P.a2   = P.kl  + 131072;
    P.z    = P.a2  + 524288;
    P.z2   = P.z   + 524288;
    P.xz   = P.z2  + 524288;
    P.t1   = P.xz  + 524288;
    P.t2   = P.t1  + 524288;
    P.av   = P.t2  + 524288;
    P.W    = P.av  + 131072;
    P.rs   = P.W   + 131072;
    P.cs   = P.rs  + 2048;
    P.scal = P.cs  + 2048;

    // fc1 + relu -> h rows 1..8192
    gemm_f32<<<dim3(512 / 64, NTOK / 64), 256, 0, stream>>>(x, fc1_w, fc1_b, nullptr,
                                                            P.h + 512, NTOK, 512, INDIM, 1);
    // cls token + wrap rows
    fixup_k<<<180, 256, 0, stream>>>(cls_tok, P.h);
    // block 1
    run_attn(P.h, ln1_g, ln1_b, qkv1_w, out1_w, out1_b, conv1_w, P, stream);
    // ppeg: h -> h2
    ppeg_k<<<(N1 * 512) / 256, 256, 0, stream>>>(P.h, pg7_w, pg7_b, pg5_w, pg5_b, pg3_w, pg3_b, P.h2);
    // block 2
    run_attn(P.h2, ln2_g, ln2_b, qkv2_w, out2_w, out2_b, conv2_w, P, stream);
    // final head
    final_k<<<1, 256, 0, stream>>>(P.h2, norm_g, norm_b, fc2_w, fc2_b, (float*)d_out);
}

// Round 2
// 2965.728 us; speedup vs baseline: 1.8998x; 1.8998x over previous
//
#include <hip/hip_runtime.h>
#include <math.h>

// ---------------- constants ----------------
#define NTOK   8192
#define INDIM  1024
#define DMODEL 512
#define NHEAD  8
#define DH     64
#define N1     8282      // tokens incl cls (91*91 + 1)
#define NP     8448      // padded token count inside attention
#define PAD    166
#define NLM    256       // landmarks
#define LCH    33        // tokens per landmark chunk
#define SCALE  0.125f
#define HS     91

// ---------------- reduce helpers (256-thread blocks) ----------------
__device__ __forceinline__ float blockReduceSumF(float v, float* red, int tid) {
    red[tid] = v; __syncthreads();
    for (int s = 128; s > 0; s >>= 1) {
        if (tid < s) red[tid] += red[tid + s];
        __syncthreads();
    }
    float r = red[0]; __syncthreads();
    return r;
}
__device__ __forceinline__ float blockReduceMaxF(float v, float* red, int tid) {
    red[tid] = v; __syncthreads();
    for (int s = 128; s > 0; s >>= 1) {
        if (tid < s) red[tid] = fmaxf(red[tid], red[tid + s]);
        __syncthreads();
    }
    float r = red[0]; __syncthreads();
    return r;
}

// ---------------- generic f32 GEMM: C = [res +] A@B [+ bias] [relu] ----------------
__global__ __launch_bounds__(256) void gemm_f32(
    const float* __restrict__ A, const float* __restrict__ B,
    const float* __restrict__ bias, const float* __restrict__ res,
    float* __restrict__ C, int M, int N, int K, int relu)
{
    __shared__ float As[16][68];
    __shared__ float Bs[16][64];
    int tid = threadIdx.x;
    int row0 = blockIdx.y * 64, col0 = blockIdx.x * 64;
    int tx = tid & 15, ty = tid >> 4;
    int aRow = tid >> 2, aK = (tid & 3) * 4;
    int bRow = tid >> 4, bCol = (tid & 15) * 4;
    float acc[4][4] = {};
    for (int kb = 0; kb < K; kb += 16) {
        int ar = row0 + aRow;
        float4 a4 = make_float4(0.f, 0.f, 0.f, 0.f);
        if (ar < M) a4 = *reinterpret_cast<const float4*>(A + (size_t)ar * K + kb + aK);
        As[aK + 0][aRow] = a4.x; As[aK + 1][aRow] = a4.y;
        As[aK + 2][aRow] = a4.z; As[aK + 3][aRow] = a4.w;
        float4 b4 = *reinterpret_cast<const float4*>(B + (size_t)(kb + bRow) * N + col0 + bCol);
        *reinterpret_cast<float4*>(&Bs[bRow][bCol]) = b4;
        __syncthreads();
#pragma unroll
        for (int k = 0; k < 16; ++k) {
            float a[4], b[4];
#pragma unroll
            for (int i = 0; i < 4; ++i) a[i] = As[k][ty * 4 + i];
#pragma unroll
            for (int j = 0; j < 4; ++j) b[j] = Bs[k][tx * 4 + j];
#pragma unroll
            for (int i = 0; i < 4; ++i)
#pragma unroll
                for (int j = 0; j < 4; ++j) acc[i][j] += a[i] * b[j];
        }
        __syncthreads();
    }
#pragma unroll
    for (int i = 0; i < 4; ++i) {
        int r = row0 + ty * 4 + i;
        if (r >= M) continue;
#pragma unroll
        for (int j = 0; j < 4; ++j) {
            int c = col0 + tx * 4 + j;
            float v = acc[i][j];
            if (bias) v += bias[c];
            if (res)  v += res[(size_t)r * N + c];
            if (relu) v = fmaxf(v, 0.f);
            C[(size_t)r * N + c] = v;
        }
    }
}

// ---------------- batched 256x256x256 GEMM (per head): C = diag*I + ss*(A@B) ----------------
__global__ __launch_bounds__(256) void bgemm256(
    const float* __restrict__ A, const float* __restrict__ B, float* __restrict__ C,
    float diag, float ss)
{
    __shared__ float As[16][68];
    __shared__ float Bs[16][64];
    int hH = blockIdx.z;
    const float* Ah = A + (size_t)hH * 65536;
    const float* Bh = B + (size_t)hH * 65536;
    float* Ch = C + (size_t)hH * 65536;
    int tid = threadIdx.x;
    int row0 = blockIdx.y * 64, col0 = blockIdx.x * 64;
    int tx = tid & 15, ty = tid >> 4;
    int aRow = tid >> 2, aK = (tid & 3) * 4;
    int bRow = tid >> 4, bCol = (tid & 15) * 4;
    float acc[4][4] = {};
    for (int kb = 0; kb < 256; kb += 16) {
        float4 a4 = *reinterpret_cast<const float4*>(Ah + (size_t)(row0 + aRow) * 256 + kb + aK);
        As[aK + 0][aRow] = a4.x; As[aK + 1][aRow] = a4.y;
        As[aK + 2][aRow] = a4.z; As[aK + 3][aRow] = a4.w;
        float4 b4 = *reinterpret_cast<const float4*>(Bh + (size_t)(kb + bRow) * 256 + col0 + bCol);
        *reinterpret_cast<float4*>(&Bs[bRow][bCol]) = b4;
        __syncthreads();
#pragma unroll
        for (int k = 0; k < 16; ++k) {
            float a[4], b[4];
#pragma unroll
            for (int i = 0; i < 4; ++i) a[i] = As[k][ty * 4 + i];
#pragma unroll
            for (int j = 0; j < 4; ++j) b[j] = Bs[k][tx * 4 + j];
#pragma unroll
            for (int i = 0; i < 4; ++i)
#pragma unroll
                for (int j = 0; j < 4; ++j) acc[i][j] += a[i] * b[j];
        }
        __syncthreads();
    }
#pragma unroll
    for (int i = 0; i < 4; ++i) {
        int r = row0 + ty * 4 + i;
#pragma unroll
        for (int j = 0; j < 4; ++j) {
            int c = col0 + tx * 4 + j;
            float v = ss * acc[i][j];
            if (r == c) v += diag;
            Ch[(size_t)r * 256 + c] = v;
        }
    }
}

// ---------------- fixup: cls token + wrap rows ----------------
__global__ void fixup_k(const float* __restrict__ cls, float* __restrict__ h)
{
    int i = blockIdx.x * 256 + threadIdx.x;   // 90*512
    if (i < 512) {
        h[i] = cls[i];
    } else {
        int j = i - 512;                       // j < 89*512
        h[(size_t)8193 * 512 + j] = h[512 + j];
    }
}

// ---------------- layernorm + front zero-pad: out[NP][512] ----------------
__global__ __launch_bounds__(256) void ln_pad_k(
    const float* __restrict__ h, const float* __restrict__ g, const float* __restrict__ b,
    float* __restrict__ out)
{
    int row = blockIdx.x, tid = threadIdx.x;
    __shared__ float red[256];
    float* o = out + (size_t)row * 512;
    if (row < PAD) { o[tid] = 0.f; o[tid + 256] = 0.f; return; }
    const float* x = h + (size_t)(row - PAD) * 512;
    float v0 = x[tid], v1 = x[tid + 256];
    float mu = blockReduceSumF(v0 + v1, red, tid) * (1.f / 512.f);
    float d0 = v0 - mu, d1 = v1 - mu;
    float var = blockReduceSumF(d0 * d0 + d1 * d1, red, tid) * (1.f / 512.f);
    float rstd = rsqrtf(var + 1e-5f);
    o[tid]       = d0 * rstd * g[tid] + b[tid];
    o[tid + 256] = d1 * rstd * g[tid + 256] + b[tid + 256];
}

// ---------------- landmark means (q scaled) ----------------
__global__ void landmark_k(const float* __restrict__ qkv, float* __restrict__ ql, float* __restrict__ kl)
{
    int h = blockIdx.x >> 8, m = blockIdx.x & 255, d = threadIdx.x;  // 64 threads
    const float* base = qkv + (size_t)(m * LCH) * 1536 + h * 64 + d;
    float sq = 0.f, sk = 0.f;
    for (int i = 0; i < LCH; ++i) {
        sq += base[(size_t)i * 1536];
        sk += base[(size_t)i * 1536 + 512];
    }
    ql[((size_t)h * 256 + m) * 64 + d] = sq * (SCALE / (float)LCH);
    kl[((size_t)h * 256 + m) * 64 + d] = sk * (1.f / (float)LCH);
}

// ---------------- a2 = softmax(ql @ kl^T) ----------------
__global__ __launch_bounds__(256) void a2_k(
    const float* __restrict__ ql, const float* __restrict__ kl, float* __restrict__ a2)
{
    int h = blockIdx.x >> 8, r = blockIdx.x & 255, tid = threadIdx.x;
    __shared__ float qv[64]; __shared__ float red[256];
    if (tid < 64) qv[tid] = ql[((size_t)h * 256 + r) * 64 + tid];
    __syncthreads();
    const float* kp = kl + ((size_t)h * 256 + tid) * 64;
    float dot = 0.f;
#pragma unroll
    for (int d = 0; d < 64; ++d) dot += qv[d] * kp[d];
    float mx = blockReduceMaxF(dot, red, tid);
    float e = expf(dot - mx);
    float s = blockReduceSumF(e, red, tid);
    a2[((size_t)h * 256 + r) * 256 + tid] = e / s;
}

// ---------------- pinv init helpers ----------------
__global__ __launch_bounds__(256) void rowsum_k(const float* __restrict__ a2, float* __restrict__ rs)
{
    int r = blockIdx.x; __shared__ float red[256];
    float v = fabsf(a2[(size_t)r * 256 + threadIdx.x]);
    float s = blockReduceSumF(v, red, threadIdx.x);
    if (!threadIdx.x) rs[r] = s;
}
__global__ __launch_bounds__(256) void colsum_k(const float* __restrict__ a2, float* __restrict__ cs)
{
    int h = blockIdx.x >> 8, c = blockIdx.x & 255;
    __shared__ float red[256];
    float v = fabsf(a2[(size_t)h * 65536 + (size_t)threadIdx.x * 256 + c]);
    float s = blockReduceSumF(v, red, threadIdx.x);
    if (!threadIdx.x) cs[blockIdx.x] = s;
}
__global__ __launch_bounds__(256) void pinv_scal_k(const float* __restrict__ rs, const float* __restrict__ cs,
                                                   float* __restrict__ scal)
{
    int tid = threadIdx.x; __shared__ float red[256];
    float m1 = -1e30f, m2 = -1e30f;
    for (int i = tid; i < 2048; i += 256) { m1 = fmaxf(m1, rs[i]); m2 = fmaxf(m2, cs[i]); }
    m1 = blockReduceMaxF(m1, red, tid);
    m2 = blockReduceMaxF(m2, red, tid);
    if (!tid) scal[0] = 1.f / (m1 * m2);
}
__global__ __launch_bounds__(256) void zinit_k(const float* __restrict__ a2, const float* __restrict__ scal,
                                               float* __restrict__ z)
{
    int h = blockIdx.x >> 8, r = blockIdx.x & 255, c = threadIdx.x;
    z[(size_t)h * 65536 + (size_t)r * 256 + c] = a2[(size_t)h * 65536 + (size_t)c * 256 + r] * scal[0];
}
__global__ __launch_bounds__(256) void diag7_k(const float* __restrict__ xz, float* __restrict__ t1)
{
    size_t i = (size_t)blockIdx.x * 256 + threadIdx.x;   // 8*65536
    int rc = (int)(i & 65535);
    float v = -xz[i];
    if ((rc >> 8) == (rc & 255)) v += 7.f;
    t1[i] = v;
}

// ---------------- S3 = ql @ K^T  (per head, 256 x NP) ----------------
__global__ __launch_bounds__(256) void s3_k(const float* __restrict__ ql, const float* __restrict__ qkv,
                                            float* __restrict__ S)
{
    __shared__ float As[16][68];
    __shared__ float Bs[16][68];
    int h = blockIdx.z;
    int col0 = blockIdx.x * 64, row0 = blockIdx.y * 64;
    int tid = threadIdx.x;
    int r4 = tid >> 2, k4 = (tid & 3) * 4;
    int tx = tid & 15, ty = tid >> 4;
    const float* qlh = ql + (size_t)h * 256 * 64;
    float acc[4][4] = {};
    for (int kb = 0; kb < 64; kb += 16) {
        float4 a4 = *reinterpret_cast<const float4*>(qlh + (size_t)(row0 + r4) * 64 + kb + k4);
        As[k4 + 0][r4] = a4.x; As[k4 + 1][r4] = a4.y; As[k4 + 2][r4] = a4.z; As[k4 + 3][r4] = a4.w;
        float4 b4 = *reinterpret_cast<const float4*>(qkv + (size_t)(col0 + r4) * 1536 + 512 + h * 64 + kb + k4);
        Bs[k4 + 0][r4] = b4.x; Bs[k4 + 1][r4] = b4.y; Bs[k4 + 2][r4] = b4.z; Bs[k4 + 3][r4] = b4.w;
        __syncthreads();
#pragma unroll
        for (int k = 0; k < 16; ++k) {
            float a[4], b[4];
#pragma unroll
            for (int i = 0; i < 4; ++i) a[i] = As[k][ty * 4 + i];
#pragma unroll
            for (int j = 0; j < 4; ++j) b[j] = Bs[k][tx * 4 + j];
#pragma unroll
            for (int i = 0; i < 4; ++i)
#pragma unroll
                for (int j = 0; j < 4; ++j) acc[i][j] += a[i] * b[j];
        }
        __syncthreads();
    }
#pragma unroll
    for (int i = 0; i < 4; ++i)
#pragma unroll
        for (int j = 0; j < 4; ++j)
            S[((size_t)h * 256 + row0 + ty * 4 + i) * (size_t)NP + col0 + tx * 4 + j] = acc[i][j];
}

// ---------------- row max/sum over S3 rows (len NP) ----------------
__global__ __launch_bounds__(256) void rowstat3_k(const float* __restrict__ S,
                                                  float* __restrict__ rmax, float* __restrict__ rsum)
{
    __shared__ float red[256];
    int row = blockIdx.x, tid = threadIdx.x;
    const float* p = S + (size_t)row * NP;
    float mx = -1e30f;
    for (int i = tid; i < NP; i += 256) mx = fmaxf(mx, p[i]);
    mx = blockReduceMaxF(mx, red, tid);
    float s = 0.f;
    for (int i = tid; i < NP; i += 256) s += __expf(p[i] - mx);
    s = blockReduceSumF(s, red, tid);
    if (!tid) { rmax[row] = mx; rsum[row] = s; }
}

// ---------------- av = softmax(S3) @ V  (exp fused, per head 256 x 64) ----------------
__global__ __launch_bounds__(256) void pv_k(const float* __restrict__ S,
                                            const float* __restrict__ rmax, const float* __restrict__ rsum,
                                            const float* __restrict__ qkv, float* __restrict__ av)
{
    __shared__ float As[16][36];
    __shared__ float Bs[16][36];
    int h = blockIdx.z;
    int row0 = blockIdx.y * 32, col0 = blockIdx.x * 32;
    int tid = threadIdx.x;
    int ar = tid >> 3, ak = (tid & 7) * 2;
    int bk = tid >> 4, bn = (tid & 15) * 2;
    int tx = tid & 15, ty = tid >> 4;
    size_t rowbase = (size_t)h * 256 + row0;
    float rm = rmax[rowbase + ar];
    float acc[2][2] = {};
    for (int kb = 0; kb < NP; kb += 16) {
        float2 a2v = *reinterpret_cast<const float2*>(S + (rowbase + ar) * (size_t)NP + kb + ak);
        As[ak + 0][ar] = __expf(a2v.x - rm);
        As[ak + 1][ar] = __expf(a2v.y - rm);
        float2 b2v = *reinterpret_cast<const float2*>(qkv + (size_t)(kb + bk) * 1536 + 1024 + h * 64 + col0 + bn);
        Bs[bk][bn] = b2v.x; Bs[bk][bn + 1] = b2v.y;
        __syncthreads();
#pragma unroll
        for (int k = 0; k < 16; ++k) {
            float a0 = As[k][ty * 2], a1 = As[k][ty * 2 + 1];
            float b0 = Bs[k][tx * 2], b1 = Bs[k][tx * 2 + 1];
            acc[0][0] += a0 * b0; acc[0][1] += a0 * b1;
            acc[1][0] += a1 * b0; acc[1][1] += a1 * b1;
        }
        __syncthreads();
    }
#pragma unroll
    for (int i = 0; i < 2; ++i) {
        int r = row0 + ty * 2 + i;
        float inv = 1.f / rsum[(size_t)h * 256 + r];
#pragma unroll
        for (int j = 0; j < 2; ++j)
            av[((size_t)h * 256 + r) * 64 + col0 + tx * 2 + j] = acc[i][j] * inv;
    }
}

// ---------------- W = z @ av (per head 256x256 @ 256x64) ----------------
__global__ void wmat_k(const float* __restrict__ z, const float* __restrict__ av, float* __restrict__ W)
{
    int h = blockIdx.x >> 8, m = blockIdx.x & 255, d = threadIdx.x;  // 64 threads
    const float* zp = z + (size_t)h * 65536 + (size_t)m * 256;
    const float* ap = av + (size_t)h * 16384 + d;
    float acc = 0.f;
    for (int j = 0; j < 256; ++j) acc += zp[j] * ap[(size_t)j * 64];
    W[((size_t)h * 256 + m) * 64 + d] = acc;
}

// ---------------- S1 = (q*SCALE) @ kl^T  (per head, NP x 256) ----------------
__global__ __launch_bounds__(256) void s1_k(const float* __restrict__ qkv, const float* __restrict__ kl,
                                            float* __restrict__ S)
{
    __shared__ float As[16][68];
    __shared__ float Bs[16][68];
    int h = blockIdx.z;
    int col0 = blockIdx.x * 64, row0 = blockIdx.y * 64;
    int tid = threadIdx.x;
    int r4 = tid >> 2, k4 = (tid & 3) * 4;
    int tx = tid & 15, ty = tid >> 4;
    float acc[4][4] = {};
    for (int kb = 0; kb < 64; kb += 16) {
        float4 a4 = *reinterpret_cast<const float4*>(qkv + (size_t)(row0 + r4) * 1536 + h * 64 + kb + k4);
        As[k4 + 0][r4] = a4.x * SCALE; As[k4 + 1][r4] = a4.y * SCALE;
        As[k4 + 2][r4] = a4.z * SCALE; As[k4 + 3][r4] = a4.w * SCALE;
        float4 b4 = *reinterpret_cast<const float4*>(kl + ((size_t)h * 256 + col0 + r4) * 64 + kb + k4);
        Bs[k4 + 0][r4] = b4.x; Bs[k4 + 1][r4] = b4.y; Bs[k4 + 2][r4] = b4.z; Bs[k4 + 3][r4] = b4.w;
        __syncthreads();
#pragma unroll
        for (int k = 0; k < 16; ++k) {
            float a[4], b[4];
#pragma unroll
            for (int i = 0; i < 4; ++i) a[i] = As[k][ty * 4 + i];
#pragma unroll
            for (int j = 0; j < 4; ++j) b[j] = Bs[k][tx * 4 + j];
#pragma unroll
            for (int i = 0; i < 4; ++i)
#pragma unroll
                for (int j = 0; j < 4; ++j) acc[i][j] += a[i] * b[j];
        }
        __syncthreads();
    }
#pragma unroll
    for (int i = 0; i < 4; ++i)
#pragma unroll
        for (int j = 0; j < 4; ++j)
            S[((size_t)h * NP + row0 + ty * 4 + i) * 256 + col0 + tx * 4 + j] = acc[i][j];
}

// ---------------- row max/sum over S1 rows (len 256), wave per row ----------------
__global__ __launch_bounds__(256) void rowstat1_k(const float* __restrict__ S,
                                                  float* __restrict__ rmax, float* __restrict__ rsum)
{
    int wave = threadIdx.x >> 6, lane = threadIdx.x & 63;
    size_t row = (size_t)blockIdx.x * 4 + wave;
    const float* p = S + row * 256;
    float v0 = p[lane], v1 = p[lane + 64], v2 = p[lane + 128], v3 = p[lane + 192];
    float mx = fmaxf(fmaxf(v0, v1), fmaxf(v2, v3));
    for (int off = 32; off; off >>= 1) mx = fmaxf(mx, __shfl_xor(mx, off, 64));
    float s = __expf(v0 - mx) + __expf(v1 - mx) + __expf(v2 - mx) + __expf(v3 - mx);
    for (int off = 32; off; off >>= 1) s += __shfl_xor(s, off, 64);
    if (!lane) { rmax[row] = mx; rsum[row] = s; }
}

// ---------------- attn = softmax(S1) @ W (exp fused, token-major out) ----------------
__global__ __launch_bounds__(256) void pw_k(const float* __restrict__ S,
                                            const float* __restrict__ rmax, const float* __restrict__ rsum,
                                            const float* __restrict__ W, float* __restrict__ attn)
{
    __shared__ float As[16][68];
    __shared__ float Bs[16][68];
    int h = blockIdx.z;
    int row0 = blockIdx.y * 64;
    int tid = threadIdx.x;
    int r4 = tid >> 2, k4 = (tid & 3) * 4;
    int bk = tid >> 4, bn4 = (tid & 15) * 4;
    int tx = tid & 15, ty = tid >> 4;
    size_t rowbase = (size_t)h * NP + row0;
    float rm = rmax[rowbase + r4];
    float acc[4][4] = {};
    for (int kb = 0; kb < 256; kb += 16) {
        float4 a4 = *reinterpret_cast<const float4*>(S + (rowbase + r4) * 256 + kb + k4);
        As[k4 + 0][r4] = __expf(a4.x - rm); As[k4 + 1][r4] = __expf(a4.y - rm);
        As[k4 + 2][r4] = __expf(a4.z - rm); As[k4 + 3][r4] = __expf(a4.w - rm);
        float4 b4 = *reinterpret_cast<const float4*>(W + ((size_t)h * 256 + kb + bk) * 64 + bn4);
        *reinterpret_cast<float4*>(&Bs[bk][bn4]) = b4;
        __syncthreads();
#pragma unroll
        for (int k = 0; k < 16; ++k) {
            float a[4], b[4];
#pragma unroll
            for (int i = 0; i < 4; ++i) a[i] = As[k][ty * 4 + i];
#pragma unroll
            for (int j = 0; j < 4; ++j) b[j] = Bs[k][tx * 4 + j];
#pragma unroll
            for (int i = 0; i < 4; ++i)
#pragma unroll
                for (int j = 0; j < 4; ++j) acc[i][j] += a[i] * b[j];
        }
        __syncthreads();
    }
#pragma unroll
    for (int i = 0; i < 4; ++i) {
        int t = row0 + ty * 4 + i;
        float inv = 1.f / rsum[(size_t)h * NP + t];
#pragma unroll
        for (int j = 0; j < 4; ++j)
            attn[(size_t)t * 512 + h * 64 + tx * 4 + j] = acc[i][j] * inv;
    }
}

// ---------------- depthwise 33-tap conv over tokens on v, added to attn ----------------
__global__ void conv_k(const float* __restrict__ qkv, const float* __restrict__ cw, float* __restrict__ attn)
{
    int idx = blockIdx.x * 256 + threadIdx.x;   // NP*512
    int t = idx >> 9, c = idx & 511, h = c >> 6;
    float acc = 0.f;
#pragma unroll
    for (int j = 0; j < 33; ++j) {
        int tt = t + j - 16;
        if (tt >= 0 && tt < NP) acc += cw[h * 33 + j] * qkv[(size_t)tt * 1536 + 1024 + c];
    }
    attn[idx] += acc;
}

// ---------------- PPEG tiled: 16x16 token tile x 16 channels, combined 49-tap ----------------
#define PTS  16          // out tile side
#define PIT  22          // in tile side (halo 3)
#define PITT (PIT*PIT)   // 484
#define PCG  16          // channels per block
__global__ __launch_bounds__(256) void ppeg_tiled_k(
    const float* __restrict__ hin,
    const float* __restrict__ w7, const float* __restrict__ b7,
    const float* __restrict__ w5, const float* __restrict__ b5,
    const float* __restrict__ w3, const float* __restrict__ b3,
    float* __restrict__ hout)
{
    __shared__ float inb[PCG][PITT + 1];
    __shared__ float wc[PCG][49];
    __shared__ float bs[PCG];
    int tid = threadIdx.x;
    int c0 = blockIdx.z * PCG;
    int ty0 = blockIdx.y * PTS, tx0 = blockIdx.x * PTS;
    // cls row pass-through (once per channel group)
    if (blockIdx.x == 0 && blockIdx.y == 0 && tid < PCG)
        hout[c0 + tid] = hin[c0 + tid];
    // stage input tile (halo, zero-padded)
    for (int idx = tid; idx < PITT * (PCG / 4); idx += 256) {
        int tok = idx >> 2, q = idx & 3;
        int gy = ty0 - 3 + tok / PIT, gx = tx0 - 3 + tok % PIT;
        float4 v = make_float4(0.f, 0.f, 0.f, 0.f);
        if (gy >= 0 && gy < HS && gx >= 0 && gx < HS)
            v = *reinterpret_cast<const float4*>(hin + (size_t)(1 + gy * HS + gx) * 512 + c0 + q * 4);
        inb[q * 4 + 0][tok] = v.x; inb[q * 4 + 1][tok] = v.y;
        inb[q * 4 + 2][tok] = v.z; inb[q * 4 + 3][tok] = v.w;
    }
    // combined weights
    for (int idx = tid; idx < PCG * 49; idx += 256) {
        int c = idx / 49, t = idx % 49;
        int ky = t / 7, kx = t % 7, dy = ky - 3, dx = kx - 3;
        float w = w7[(size_t)(c0 + c) * 49 + t];
        if (dy >= -2 && dy <= 2 && dx >= -2 && dx <= 2)
            w += w5[(size_t)(c0 + c) * 25 + (dy + 2) * 5 + (dx + 2)];
        if (dy >= -1 && dy <= 1 && dx >= -1 && dx <= 1)
            w += w3[(size_t)(c0 + c) * 9 + (dy + 1) * 3 + (dx + 1)];
        wc[c][t] = w;
    }
    if (tid < PCG) bs[tid] = b7[c0 + tid] + b5[c0 + tid] + b3[c0 + tid];
    __syncthreads();
    int oy = tid >> 4, ox = tid & 15;
    int gy = ty0 + oy, gx = tx0 + ox;
    if (gy >= HS || gx >= HS) return;
    float* out = hout + (size_t)(1 + gy * HS + gx) * 512 + c0;
#pragma unroll 4
    for (int c = 0; c < PCG; ++c) {
        float acc = inb[c][(oy + 3) * PIT + ox + 3] + bs[c];
#pragma unroll
        for (int ky = 0; ky < 7; ++ky)
#pragma unroll
            for (int kx = 0; kx < 7; ++kx)
                acc += wc[c][ky * 7 + kx] * inb[c][(oy + ky) * PIT + ox + kx];
        out[c] = acc;
    }
}

// ---------------- final LN(row0) + fc2 + softmax + argmax ----------------
__global__ __launch_bounds__(256) void final_k(const float* __restrict__ h,
                                               const float* __restrict__ g, const float* __restrict__ bb,
                                               const float* __restrict__ w, const float* __restrict__ fb,
                                               float* __restrict__ out)
{
    __shared__ float red[256];
    int tid = threadIdx.x;
    float v0 = h[tid], v1 = h[tid + 256];
    float mu = blockReduceSumF(v0 + v1, red, tid) * (1.f / 512.f);
    float d0 = v0 - mu, d1 = v1 - mu;
    float var = blockReduceSumF(d0 * d0 + d1 * d1, red, tid) * (1.f / 512.f);
    float rstd = rsqrtf(var + 1e-5f);
    float e0 = d0 * rstd * g[tid] + bb[tid];
    float e1 = d1 * rstd * g[tid + 256] + bb[tid + 256];
    out[5 + tid] = e0;
    out[5 + 256 + tid] = e1;
    float l0p = e0 * w[tid * 2] + e1 * w[(tid + 256) * 2];
    float l1p = e0 * w[tid * 2 + 1] + e1 * w[(tid + 256) * 2 + 1];
    float l0 = blockReduceSumF(l0p, red, tid);
    float l1 = blockReduceSumF(l1p, red, tid);
    if (!tid) {
        l0 += fb[0]; l1 += fb[1];
        out[0] = l0; out[1] = l1;
        float mx = fmaxf(l0, l1);
        float p0 = expf(l0 - mx), p1 = expf(l1 - mx);
        float si = 1.f / (p0 + p1);
        out[2] = p0 * si; out[3] = p1 * si;
        out[4] = (l1 > l0) ? 1.f : 0.f;
    }
}

// ---------------- host orchestration ----------------
struct WsPtrs {
    float *h, *h2, *xb, *qkv, *ql, *kl, *a2, *z, *z2, *xz, *t1, *t2, *av, *W, *rs, *cs, *scal;
    float *S, *rmax3, *rsum3, *rmax1, *rsum1;
};

static void run_attn(float* hbuf, const float* ln_g, const float* ln_b,
                     const float* qkv_w, const float* out_w, const float* out_b,
                     const float* conv_w, const WsPtrs& P, hipStream_t s)
{
    ln_pad_k<<<NP, 256, 0, s>>>(hbuf, ln_g, ln_b, P.xb);
    gemm_f32<<<dim3(1536 / 64, NP / 64), 256, 0, s>>>(P.xb, qkv_w, nullptr, nullptr, P.qkv,
                                                      NP, 1536, 512, 0);
    landmark_k<<<2048, 64, 0, s>>>(P.qkv, P.ql, P.kl);
    a2_k<<<2048, 256, 0, s>>>(P.ql, P.kl, P.a2);
    rowsum_k<<<2048, 256, 0, s>>>(P.a2, P.rs);
    colsum_k<<<2048, 256, 0, s>>>(P.a2, P.cs);
    pinv_scal_k<<<1, 256, 0, s>>>(P.rs, P.cs, P.scal);
    zinit_k<<<2048, 256, 0, s>>>(P.a2, P.scal, P.z);
    float* za = P.z; float* zb = P.z2;
    for (int it = 0; it < 6; ++it) {
        bgemm256<<<dim3(4, 4, 8), 256, 0, s>>>(P.a2, za, P.xz, 0.f, 1.f);
        diag7_k<<<2048, 256, 0, s>>>(P.xz, P.t1);
        bgemm256<<<dim3(4, 4, 8), 256, 0, s>>>(P.xz, P.t1, P.t2, 15.f, -1.f);
        bgemm256<<<dim3(4, 4, 8), 256, 0, s>>>(P.xz, P.t2, P.t1, 13.f, -1.f);
        bgemm256<<<dim3(4, 4, 8), 256, 0, s>>>(za, P.t1, zb, 0.f, 0.25f);
        float* tmp = za; za = zb; zb = tmp;
    }
    // av path: S3 scores -> row stats -> PV
    s3_k<<<dim3(NP / 64, 4, 8), 256, 0, s>>>(P.ql, P.qkv, P.S);
    rowstat3_k<<<2048, 256, 0, s>>>(P.S, P.rmax3, P.rsum3);
    pv_k<<<dim3(2, 8, 8), 256, 0, s>>>(P.S, P.rmax3, P.rsum3, P.qkv, P.av);
    wmat_k<<<2048, 64, 0, s>>>(za, P.av, P.W);
    // a1 path: S1 scores -> row stats -> PW (token-major attn into xb)
    s1_k<<<dim3(4, NP / 64, 8), 256, 0, s>>>(P.qkv, P.kl, P.S);
    rowstat1_k<<<(NP * 8) / 4, 256, 0, s>>>(P.S, P.rmax1, P.rsum1);
    pw_k<<<dim3(1, NP / 64, 8), 256, 0, s>>>(P.S, P.rmax1, P.rsum1, P.W, P.xb);
    conv_k<<<NP * 512 / 256, 256, 0, s>>>(P.qkv, conv_w, P.xb);
    gemm_f32<<<dim3(512 / 64, (N1 + 63) / 64), 256, 0, s>>>(P.xb + (size_t)PAD * 512, out_w,
                                                            out_b, hbuf, hbuf, N1, 512, 512, 0);
}

extern "C" void kernel_launch(void* const* d_in, const int* in_sizes, int n_in,
                              void* d_out, int out_size, void* d_ws, size_t ws_size,
                              hipStream_t stream)
{
    (void)in_sizes; (void)n_in; (void)out_size; (void)ws_size;
    const float* x       = (const float*)d_in[0];
    const float* fc1_w   = (const float*)d_in[1];
    const float* fc1_b   = (const float*)d_in[2];
    const float* cls_tok = (const float*)d_in[3];
    const float* ln1_g   = (const float*)d_in[4];
    const float* ln1_b   = (const float*)d_in[5];
    const float* qkv1_w  = (const float*)d_in[6];
    const float* out1_w  = (const float*)d_in[7];
    const float* out1_b  = (const float*)d_in[8];
    const float* conv1_w = (const float*)d_in[9];
    const float* ln2_g   = (const float*)d_in[10];
    const float* ln2_b   = (const float*)d_in[11];
    const float* qkv2_w  = (const float*)d_in[12];
    const float* out2_w  = (const float*)d_in[13];
    const float* out2_b  = (const float*)d_in[14];
    const float* conv2_w = (const float*)d_in[15];
    const float* pg7_w   = (const float*)d_in[16];
    const float* pg7_b   = (const float*)d_in[17];
    const float* pg5_w   = (const float*)d_in[18];
    const float* pg5_b   = (const float*)d_in[19];
    const float* pg3_w   = (const float*)d_in[20];
    const float* pg3_b   = (const float*)d_in[21];
    const float* norm_g  = (const float*)d_in[22];
    const float* norm_b  = (const float*)d_in[23];
    const float* fc2_w   = (const float*)d_in[24];
    const float* fc2_b   = (const float*)d_in[25];

    float* ws = (float*)d_ws;
    WsPtrs P;
    P.h     = ws;
    P.h2    = P.h    + (size_t)N1 * 512;
    P.xb    = P.h2   + (size_t)N1 * 512;
    P.qkv   = P.xb   + (size_t)NP * 512;
    P.ql    = P.qkv  + (size_t)NP * 1536;
    P.kl    = P.ql   + 131072;
    P.a2    = P.kl   + 131072;
    P.z     = P.a2   + 524288;
    P.z2    = P.z    + 524288;
    P.xz    = P.z2   + 524288;
    P.t1    = P.xz   + 524288;
    P.t2    = P.t1   + 524288;
    P.av    = P.t2   + 524288;
    P.W     = P.av   + 131072;
    P.rs    = P.W    + 131072;
    P.cs    = P.rs   + 2048;
    P.scal  = P.cs   + 2048;
    P.S     = P.scal + 64;                       // 8*256*8448 floats (shared by S1/S3)
    P.rmax3 = P.S    + (size_t)8 * 256 * NP;
    P.rsum3 = P.rmax3 + 2048;
    P.rmax1 = P.rsum3 + 2048;
    P.rsum1 = P.rmax1 + (size_t)8 * NP;

    gemm_f32<<<dim3(512 / 64, NTOK / 64), 256, 0, stream>>>(x, fc1_w, fc1_b, nullptr,
                                                            P.h + 512, NTOK, 512, INDIM, 1);
    fixup_k<<<180, 256, 0, stream>>>(cls_tok, P.h);
    run_attn(P.h, ln1_g, ln1_b, qkv1_w, out1_w, out1_b, conv1_w, P, stream);
    ppeg_tiled_k<<<dim3(6, 6, 512 / PCG), 256, 0, stream>>>(P.h, pg7_w, pg7_b, pg5_w, pg5_b,
                                                            pg3_w, pg3_b, P.h2);
    run_attn(P.h2, ln2_g, ln2_b, qkv2_w, out2_w, out2_b, conv2_w, P, stream);
    final_k<<<1, 256, 0, stream>>>(P.h2, norm_g, norm_b, fc2_w, fc2_b, (float*)d_out);
}

// Round 3
// 2151.862 us; speedup vs baseline: 2.6183x; 1.3782x over previous
//
#include <hip/hip_runtime.h>
#include <math.h>

// ---------------- constants ----------------
#define NTOK   8192
#define INDIM  1024
#define DMODEL 512
#define NHEAD  8
#define DH     64
#define N1     8282      // tokens incl cls (91*91 + 1)
#define NP     8448      // padded token count inside attention
#define PAD    166
#define NLM    256       // landmarks
#define LCH    33        // tokens per landmark chunk
#define SCALE  0.125f
#define HS     91
#define KSPLIT 8
#define KCH    (NP / KSPLIT)   // 1056

// ---------------- reduce helpers (256-thread blocks) ----------------
__device__ __forceinline__ float blockReduceSumF(float v, float* red, int tid) {
    red[tid] = v; __syncthreads();
    for (int s = 128; s > 0; s >>= 1) {
        if (tid < s) red[tid] += red[tid + s];
        __syncthreads();
    }
    float r = red[0]; __syncthreads();
    return r;
}
__device__ __forceinline__ float blockReduceMaxF(float v, float* red, int tid) {
    red[tid] = v; __syncthreads();
    for (int s = 128; s > 0; s >>= 1) {
        if (tid < s) red[tid] = fmaxf(red[tid], red[tid + s]);
        __syncthreads();
    }
    float r = red[0]; __syncthreads();
    return r;
}

// ---------------- generic f32 GEMM: C = [res +] A@B [+ bias] [relu] ----------------
__global__ __launch_bounds__(256) void gemm_f32(
    const float* __restrict__ A, const float* __restrict__ B,
    const float* __restrict__ bias, const float* __restrict__ res,
    float* __restrict__ C, int M, int N, int K, int relu)
{
    __shared__ float As[16][68];
    __shared__ float Bs[16][64];
    int tid = threadIdx.x;
    int row0 = blockIdx.y * 64, col0 = blockIdx.x * 64;
    int tx = tid & 15, ty = tid >> 4;
    int aRow = tid >> 2, aK = (tid & 3) * 4;
    int bRow = tid >> 4, bCol = (tid & 15) * 4;
    float acc[4][4] = {};
    for (int kb = 0; kb < K; kb += 16) {
        int ar = row0 + aRow;
        float4 a4 = make_float4(0.f, 0.f, 0.f, 0.f);
        if (ar < M) a4 = *reinterpret_cast<const float4*>(A + (size_t)ar * K + kb + aK);
        As[aK + 0][aRow] = a4.x; As[aK + 1][aRow] = a4.y;
        As[aK + 2][aRow] = a4.z; As[aK + 3][aRow] = a4.w;
        float4 b4 = *reinterpret_cast<const float4*>(B + (size_t)(kb + bRow) * N + col0 + bCol);
        *reinterpret_cast<float4*>(&Bs[bRow][bCol]) = b4;
        __syncthreads();
#pragma unroll
        for (int k = 0; k < 16; ++k) {
            float a[4], b[4];
#pragma unroll
            for (int i = 0; i < 4; ++i) a[i] = As[k][ty * 4 + i];
#pragma unroll
            for (int j = 0; j < 4; ++j) b[j] = Bs[k][tx * 4 + j];
#pragma unroll
            for (int i = 0; i < 4; ++i)
#pragma unroll
                for (int j = 0; j < 4; ++j) acc[i][j] += a[i] * b[j];
        }
        __syncthreads();
    }
#pragma unroll
    for (int i = 0; i < 4; ++i) {
        int r = row0 + ty * 4 + i;
        if (r >= M) continue;
#pragma unroll
        for (int j = 0; j < 4; ++j) {
            int c = col0 + tx * 4 + j;
            float v = acc[i][j];
            if (bias) v += bias[c];
            if (res)  v += res[(size_t)r * N + c];
            if (relu) v = fmaxf(v, 0.f);
            C[(size_t)r * N + c] = v;
        }
    }
}

// ---------------- batched 256x256x256 GEMM (per head): C = diag*I + ss*(A@B) ----------------
// optional second output C2 = diag2*I + ss2*(A@B)
__global__ __launch_bounds__(256) void bgemm256(
    const float* __restrict__ A, const float* __restrict__ B, float* __restrict__ C,
    float diag, float ss, float* __restrict__ C2, float diag2, float ss2)
{
    __shared__ float As[16][68];
    __shared__ float Bs[16][64];
    int hH = blockIdx.z;
    const float* Ah = A + (size_t)hH * 65536;
    const float* Bh = B + (size_t)hH * 65536;
    float* Ch = C + (size_t)hH * 65536;
    int tid = threadIdx.x;
    int row0 = blockIdx.y * 64, col0 = blockIdx.x * 64;
    int tx = tid & 15, ty = tid >> 4;
    int aRow = tid >> 2, aK = (tid & 3) * 4;
    int bRow = tid >> 4, bCol = (tid & 15) * 4;
    float acc[4][4] = {};
    for (int kb = 0; kb < 256; kb += 16) {
        float4 a4 = *reinterpret_cast<const float4*>(Ah + (size_t)(row0 + aRow) * 256 + kb + aK);
        As[aK + 0][aRow] = a4.x; As[aK + 1][aRow] = a4.y;
        As[aK + 2][aRow] = a4.z; As[aK + 3][aRow] = a4.w;
        float4 b4 = *reinterpret_cast<const float4*>(Bh + (size_t)(kb + bRow) * 256 + col0 + bCol);
        *reinterpret_cast<float4*>(&Bs[bRow][bCol]) = b4;
        __syncthreads();
#pragma unroll
        for (int k = 0; k < 16; ++k) {
            float a[4], b[4];
#pragma unroll
            for (int i = 0; i < 4; ++i) a[i] = As[k][ty * 4 + i];
#pragma unroll
            for (int j = 0; j < 4; ++j) b[j] = Bs[k][tx * 4 + j];
#pragma unroll
            for (int i = 0; i < 4; ++i)
#pragma unroll
                for (int j = 0; j < 4; ++j) acc[i][j] += a[i] * b[j];
        }
        __syncthreads();
    }
#pragma unroll
    for (int i = 0; i < 4; ++i) {
        int r = row0 + ty * 4 + i;
#pragma unroll
        for (int j = 0; j < 4; ++j) {
            int c = col0 + tx * 4 + j;
            float v = ss * acc[i][j];
            if (r == c) v += diag;
            Ch[(size_t)r * 256 + c] = v;
            if (C2) {
                float v2 = ss2 * acc[i][j];
                if (r == c) v2 += diag2;
                C2[(size_t)hH * 65536 + (size_t)r * 256 + c] = v2;
            }
        }
    }
}

// ---------------- fixup: cls token + wrap rows ----------------
__global__ void fixup_k(const float* __restrict__ cls, float* __restrict__ h)
{
    int i = blockIdx.x * 256 + threadIdx.x;   // 90*512
    if (i < 512) {
        h[i] = cls[i];
    } else {
        int j = i - 512;                       // j < 89*512
        h[(size_t)8193 * 512 + j] = h[512 + j];
    }
}

// ---------------- layernorm + front zero-pad: out[NP][512] ----------------
__global__ __launch_bounds__(256) void ln_pad_k(
    const float* __restrict__ h, const float* __restrict__ g, const float* __restrict__ b,
    float* __restrict__ out)
{
    int row = blockIdx.x, tid = threadIdx.x;
    __shared__ float red[256];
    float* o = out + (size_t)row * 512;
    if (row < PAD) { o[tid] = 0.f; o[tid + 256] = 0.f; return; }
    const float* x = h + (size_t)(row - PAD) * 512;
    float v0 = x[tid], v1 = x[tid + 256];
    float mu = blockReduceSumF(v0 + v1, red, tid) * (1.f / 512.f);
    float d0 = v0 - mu, d1 = v1 - mu;
    float var = blockReduceSumF(d0 * d0 + d1 * d1, red, tid) * (1.f / 512.f);
    float rstd = rsqrtf(var + 1e-5f);
    o[tid]       = d0 * rstd * g[tid] + b[tid];
    o[tid + 256] = d1 * rstd * g[tid + 256] + b[tid + 256];
}

// ---------------- landmark means (q scaled) ----------------
__global__ void landmark_k(const float* __restrict__ qkv, float* __restrict__ ql, float* __restrict__ kl)
{
    int h = blockIdx.x >> 8, m = blockIdx.x & 255, d = threadIdx.x;  // 64 threads
    const float* base = qkv + (size_t)(m * LCH) * 1536 + h * 64 + d;
    float sq = 0.f, sk = 0.f;
    for (int i = 0; i < LCH; ++i) {
        sq += base[(size_t)i * 1536];
        sk += base[(size_t)i * 1536 + 512];
    }
    ql[((size_t)h * 256 + m) * 64 + d] = sq * (SCALE / (float)LCH);
    kl[((size_t)h * 256 + m) * 64 + d] = sk * (1.f / (float)LCH);
}

// ---------------- a2 = softmax(ql @ kl^T) ----------------
__global__ __launch_bounds__(256) void a2_k(
    const float* __restrict__ ql, const float* __restrict__ kl, float* __restrict__ a2)
{
    int h = blockIdx.x >> 8, r = blockIdx.x & 255, tid = threadIdx.x;
    __shared__ float qv[64]; __shared__ float red[256];
    if (tid < 64) qv[tid] = ql[((size_t)h * 256 + r) * 64 + tid];
    __syncthreads();
    const float* kp = kl + ((size_t)h * 256 + tid) * 64;
    float dot = 0.f;
#pragma unroll
    for (int d = 0; d < 64; ++d) dot += qv[d] * kp[d];
    float mx = blockReduceMaxF(dot, red, tid);
    float e = expf(dot - mx);
    float s = blockReduceSumF(e, red, tid);
    a2[((size_t)h * 256 + r) * 256 + tid] = e / s;
}

// ---------------- pinv init helpers ----------------
__global__ __launch_bounds__(256) void rowsum_k(const float* __restrict__ a2, float* __restrict__ rs)
{
    int r = blockIdx.x; __shared__ float red[256];
    float v = fabsf(a2[(size_t)r * 256 + threadIdx.x]);
    float s = blockReduceSumF(v, red, threadIdx.x);
    if (!threadIdx.x) rs[r] = s;
}
__global__ __launch_bounds__(256) void colsum_k(const float* __restrict__ a2, float* __restrict__ cs)
{
    int h = blockIdx.x >> 8, c = blockIdx.x & 255;
    __shared__ float red[256];
    float v = fabsf(a2[(size_t)h * 65536 + (size_t)threadIdx.x * 256 + c]);
    float s = blockReduceSumF(v, red, threadIdx.x);
    if (!threadIdx.x) cs[blockIdx.x] = s;
}
__global__ __launch_bounds__(256) void pinv_scal_k(const float* __restrict__ rs, const float* __restrict__ cs,
                                                   float* __restrict__ scal)
{
    int tid = threadIdx.x; __shared__ float red[256];
    float m1 = -1e30f, m2 = -1e30f;
    for (int i = tid; i < 2048; i += 256) { m1 = fmaxf(m1, rs[i]); m2 = fmaxf(m2, cs[i]); }
    m1 = blockReduceMaxF(m1, red, tid);
    m2 = blockReduceMaxF(m2, red, tid);
    if (!tid) scal[0] = 1.f / (m1 * m2);
}
__global__ __launch_bounds__(256) void zinit_k(const float* __restrict__ a2, const float* __restrict__ scal,
                                               float* __restrict__ z)
{
    int h = blockIdx.x >> 8, r = blockIdx.x & 255, c = threadIdx.x;
    z[(size_t)h * 65536 + (size_t)r * 256 + c] = a2[(size_t)h * 65536 + (size_t)c * 256 + r] * scal[0];
}

// ---------------- S3 = ql @ K^T  (per head, 256 x NP) ----------------
__global__ __launch_bounds__(256) void s3_k(const float* __restrict__ ql, const float* __restrict__ qkv,
                                            float* __restrict__ S)
{
    __shared__ float As[16][68];
    __shared__ float Bs[16][68];
    int h = blockIdx.z;
    int col0 = blockIdx.x * 64, row0 = blockIdx.y * 64;
    int tid = threadIdx.x;
    int r4 = tid >> 2, k4 = (tid & 3) * 4;
    int tx = tid & 15, ty = tid >> 4;
    const float* qlh = ql + (size_t)h * 256 * 64;
    float acc[4][4] = {};
    for (int kb = 0; kb < 64; kb += 16) {
        float4 a4 = *reinterpret_cast<const float4*>(qlh + (size_t)(row0 + r4) * 64 + kb + k4);
        As[k4 + 0][r4] = a4.x; As[k4 + 1][r4] = a4.y; As[k4 + 2][r4] = a4.z; As[k4 + 3][r4] = a4.w;
        float4 b4 = *reinterpret_cast<const float4*>(qkv + (size_t)(col0 + r4) * 1536 + 512 + h * 64 + kb + k4);
        Bs[k4 + 0][r4] = b4.x; Bs[k4 + 1][r4] = b4.y; Bs[k4 + 2][r4] = b4.z; Bs[k4 + 3][r4] = b4.w;
        __syncthreads();
#pragma unroll
        for (int k = 0; k < 16; ++k) {
            float a[4], b[4];
#pragma unroll
            for (int i = 0; i < 4; ++i) a[i] = As[k][ty * 4 + i];
#pragma unroll
            for (int j = 0; j < 4; ++j) b[j] = Bs[k][tx * 4 + j];
#pragma unroll
            for (int i = 0; i < 4; ++i)
#pragma unroll
                for (int j = 0; j < 4; ++j) acc[i][j] += a[i] * b[j];
        }
        __syncthreads();
    }
#pragma unroll
    for (int i = 0; i < 4; ++i)
#pragma unroll
        for (int j = 0; j < 4; ++j)
            S[((size_t)h * 256 + row0 + ty * 4 + i) * (size_t)NP + col0 + tx * 4 + j] = acc[i][j];
}

// ---------------- row max/sum over S3 rows (len NP) ----------------
__global__ __launch_bounds__(256) void rowstat3_k(const float* __restrict__ S,
                                                  float* __restrict__ rmax, float* __restrict__ rsum)
{
    __shared__ float red[256];
    int row = blockIdx.x, tid = threadIdx.x;
    const float* p = S + (size_t)row * NP;
    float mx = -1e30f;
    for (int i = tid; i < NP; i += 256) mx = fmaxf(mx, p[i]);
    mx = blockReduceMaxF(mx, red, tid);
    float s = 0.f;
    for (int i = tid; i < NP; i += 256) s += __expf(p[i] - mx);
    s = blockReduceSumF(s, red, tid);
    if (!tid) { rmax[row] = mx; rsum[row] = s; }
}

// ---------------- av partials: split-K GEMM with fused exp ----------------
__global__ __launch_bounds__(256) void pv_split_k(const float* __restrict__ S,
                                                  const float* __restrict__ rmax,
                                                  const float* __restrict__ qkv,
                                                  float* __restrict__ part)
{
    __shared__ float As[32][34];
    __shared__ float Bs[16][68];
    int ks = blockIdx.x, r0 = blockIdx.y * 32, h = blockIdx.z;
    int tid = threadIdx.x;
    int ar = tid >> 3, ak = (tid & 7) * 2;
    int bk = tid >> 4, bn4 = (tid & 15) * 4;
    int tx = tid & 15, ty = tid >> 4;
    size_t rowbase = (size_t)h * 256 + r0;
    float rmA = rmax[rowbase + ar];
    float acc[2][4] = {};
    int k0 = ks * KCH;
    for (int kb = k0; kb < k0 + KCH; kb += 16) {
        float2 a2v = *reinterpret_cast<const float2*>(S + (rowbase + ar) * (size_t)NP + kb + ak);
        As[ar][ak]     = __expf(a2v.x - rmA);
        As[ar][ak + 1] = __expf(a2v.y - rmA);
        float4 b4 = *reinterpret_cast<const float4*>(qkv + (size_t)(kb + bk) * 1536 + 1024 + h * 64 + bn4);
        *reinterpret_cast<float4*>(&Bs[bk][bn4]) = b4;
        __syncthreads();
#pragma unroll
        for (int k = 0; k < 16; ++k) {
            float a0 = As[ty * 2][k], a1 = As[ty * 2 + 1][k];
            float b[4];
#pragma unroll
            for (int j = 0; j < 4; ++j) b[j] = Bs[k][tx * 4 + j];
#pragma unroll
            for (int j = 0; j < 4; ++j) { acc[0][j] += a0 * b[j]; acc[1][j] += a1 * b[j]; }
        }
        __syncthreads();
    }
    float* pp = part + ((size_t)(ks * 8 + h) * 256 + r0) * 64;
#pragma unroll
    for (int i = 0; i < 2; ++i)
#pragma unroll
        for (int j = 0; j < 4; ++j)
            pp[(ty * 2 + i) * 64 + tx * 4 + j] = acc[i][j];
}

__global__ __launch_bounds__(256) void pv_reduce_k(const float* __restrict__ part,
                                                   const float* __restrict__ rsum,
                                                   float* __restrict__ av)
{
    int idx = blockIdx.x * 256 + threadIdx.x;   // 131072
    int rc = idx >> 6;                           // h*256+r
    float s = 0.f;
#pragma unroll
    for (int ks = 0; ks < KSPLIT; ++ks)
        s += part[(size_t)ks * 131072 + idx];
    av[idx] = s / rsum[rc];
}

// ---------------- W = z @ av (per head 256x256 @ 256x64) ----------------
__global__ void wmat_k(const float* __restrict__ z, const float* __restrict__ av, float* __restrict__ W)
{
    int h = blockIdx.x >> 8, m = blockIdx.x & 255, d = threadIdx.x;  // 64 threads
    const float* zp = z + (size_t)h * 65536 + (size_t)m * 256;
    const float* ap = av + (size_t)h * 16384 + d;
    float acc = 0.f;
    for (int j = 0; j < 256; ++j) acc += zp[j] * ap[(size_t)j * 64];
    W[((size_t)h * 256 + m) * 64 + d] = acc;
}

// ---------------- S1 = (q*SCALE) @ kl^T  (per head, NP x 256) ----------------
__global__ __launch_bounds__(256) void s1_k(const float* __restrict__ qkv, const float* __restrict__ kl,
                                            float* __restrict__ S)
{
    __shared__ float As[16][68];
    __shared__ float Bs[16][68];
    int h = blockIdx.z;
    int col0 = blockIdx.x * 64, row0 = blockIdx.y * 64;
    int tid = threadIdx.x;
    int r4 = tid >> 2, k4 = (tid & 3) * 4;
    int tx = tid & 15, ty = tid >> 4;
    float acc[4][4] = {};
    for (int kb = 0; kb < 64; kb += 16) {
        float4 a4 = *reinterpret_cast<const float4*>(qkv + (size_t)(row0 + r4) * 1536 + h * 64 + kb + k4);
        As[k4 + 0][r4] = a4.x * SCALE; As[k4 + 1][r4] = a4.y * SCALE;
        As[k4 + 2][r4] = a4.z * SCALE; As[k4 + 3][r4] = a4.w * SCALE;
        float4 b4 = *reinterpret_cast<const float4*>(kl + ((size_t)h * 256 + col0 + r4) * 64 + kb + k4);
        Bs[k4 + 0][r4] = b4.x; Bs[k4 + 1][r4] = b4.y; Bs[k4 + 2][r4] = b4.z; Bs[k4 + 3][r4] = b4.w;
        __syncthreads();
#pragma unroll
        for (int k = 0; k < 16; ++k) {
            float a[4], b[4];
#pragma unroll
            for (int i = 0; i < 4; ++i) a[i] = As[k][ty * 4 + i];
#pragma unroll
            for (int j = 0; j < 4; ++j) b[j] = Bs[k][tx * 4 + j];
#pragma unroll
            for (int i = 0; i < 4; ++i)
#pragma unroll
                for (int j = 0; j < 4; ++j) acc[i][j] += a[i] * b[j];
        }
        __syncthreads();
    }
#pragma unroll
    for (int i = 0; i < 4; ++i)
#pragma unroll
        for (int j = 0; j < 4; ++j)
            S[((size_t)h * NP + row0 + ty * 4 + i) * 256 + col0 + tx * 4 + j] = acc[i][j];
}

// ---------------- row max/sum over S1 rows (len 256), wave per row ----------------
__global__ __launch_bounds__(256) void rowstat1_k(const float* __restrict__ S,
                                                  float* __restrict__ rmax, float* __restrict__ rsum)
{
    int wave = threadIdx.x >> 6, lane = threadIdx.x & 63;
    size_t row = (size_t)blockIdx.x * 4 + wave;
    const float* p = S + row * 256;
    float v0 = p[lane], v1 = p[lane + 64], v2 = p[lane + 128], v3 = p[lane + 192];
    float mx = fmaxf(fmaxf(v0, v1), fmaxf(v2, v3));
    for (int off = 32; off; off >>= 1) mx = fmaxf(mx, __shfl_xor(mx, off, 64));
    float s = __expf(v0 - mx) + __expf(v1 - mx) + __expf(v2 - mx) + __expf(v3 - mx);
    for (int off = 32; off; off >>= 1) s += __shfl_xor(s, off, 64);
    if (!lane) { rmax[row] = mx; rsum[row] = s; }
}

// ---------------- attn = softmax(S1) @ W (exp fused, token-major out) ----------------
__global__ __launch_bounds__(256) void pw_k(const float* __restrict__ S,
                                            const float* __restrict__ rmax, const float* __restrict__ rsum,
                                            const float* __restrict__ W, float* __restrict__ attn)
{
    __shared__ float As[16][68];
    __shared__ float Bs[16][68];
    int h = blockIdx.z;
    int row0 = blockIdx.y * 64;
    int tid = threadIdx.x;
    int r4 = tid >> 2, k4 = (tid & 3) * 4;
    int bk = tid >> 4, bn4 = (tid & 15) * 4;
    int tx = tid & 15, ty = tid >> 4;
    size_t rowbase = (size_t)h * NP + row0;
    float rm = rmax[rowbase + r4];
    float acc[4][4] = {};
    for (int kb = 0; kb < 256; kb += 16) {
        float4 a4 = *reinterpret_cast<const float4*>(S + (rowbase + r4) * 256 + kb + k4);
        As[k4 + 0][r4] = __expf(a4.x - rm); As[k4 + 1][r4] = __expf(a4.y - rm);
        As[k4 + 2][r4] = __expf(a4.z - rm); As[k4 + 3][r4] = __expf(a4.w - rm);
        float4 b4 = *reinterpret_cast<const float4*>(W + ((size_t)h * 256 + kb + bk) * 64 + bn4);
        *reinterpret_cast<float4*>(&Bs[bk][bn4]) = b4;
        __syncthreads();
#pragma unroll
        for (int k = 0; k < 16; ++k) {
            float a[4], b[4];
#pragma unroll
            for (int i = 0; i < 4; ++i) a[i] = As[k][ty * 4 + i];
#pragma unroll
            for (int j = 0; j < 4; ++j) b[j] = Bs[k][tx * 4 + j];
#pragma unroll
            for (int i = 0; i < 4; ++i)
#pragma unroll
                for (int j = 0; j < 4; ++j) acc[i][j] += a[i] * b[j];
        }
        __syncthreads();
    }
#pragma unroll
    for (int i = 0; i < 4; ++i) {
        int t = row0 + ty * 4 + i;
        float inv = 1.f / rsum[(size_t)h * NP + t];
#pragma unroll
        for (int j = 0; j < 4; ++j)
            attn[(size_t)t * 512 + h * 64 + tx * 4 + j] = acc[i][j] * inv;
    }
}

// ---------------- tiled depthwise 33-tap conv over tokens on v, added to attn ----------------
#define CTT 64
__global__ __launch_bounds__(256) void conv2_k(const float* __restrict__ qkv,
                                               const float* __restrict__ cw,
                                               float* __restrict__ attn)
{
    __shared__ float vt[CTT + 32][64];
    int t0 = blockIdx.x * CTT;
    int h = blockIdx.y;
    int tid = threadIdx.x;
    for (int s = tid; s < (CTT + 32) * 16; s += 256) {
        int row = s >> 4, q = s & 15;
        int tt = t0 - 16 + row;
        float4 v = make_float4(0.f, 0.f, 0.f, 0.f);
        if (tt >= 0 && tt < NP)
            v = *reinterpret_cast<const float4*>(qkv + (size_t)tt * 1536 + 1024 + h * 64 + q * 4);
        *reinterpret_cast<float4*>(&vt[row][q * 4]) = v;
    }
    float w33[33];
#pragma unroll
    for (int j = 0; j < 33; ++j) w33[j] = cw[h * 33 + j];
    __syncthreads();
    int c = tid & 63, tr = tid >> 6;   // tr uniform per wave
    float win[48];
#pragma unroll
    for (int j = 0; j < 48; ++j) win[j] = vt[tr * 16 + j][c];
#pragma unroll
    for (int i = 0; i < 16; ++i) {
        float acc = 0.f;
#pragma unroll
        for (int j = 0; j < 33; ++j) acc += w33[j] * win[i + j];
        attn[(size_t)(t0 + tr * 16 + i) * 512 + h * 64 + c] += acc;
    }
}

// ---------------- PPEG tiled: 16x16 token tile x 16 channels, combined 49-tap ----------------
#define PTS  16          // out tile side
#define PIT  22          // in tile side (halo 3)
#define PITT (PIT*PIT)   // 484
#define PCG  16          // channels per block
__global__ __launch_bounds__(256) void ppeg_tiled_k(
    const float* __restrict__ hin,
    const float* __restrict__ w7, const float* __restrict__ b7,
    const float* __restrict__ w5, const float* __restrict__ b5,
    const float* __restrict__ w3, const float* __restrict__ b3,
    float* __restrict__ hout)
{
    __shared__ float inb[PCG][PITT + 1];
    __shared__ float wc[PCG][49];
    __shared__ float bs[PCG];
    int tid = threadIdx.x;
    int c0 = blockIdx.z * PCG;
    int ty0 = blockIdx.y * PTS, tx0 = blockIdx.x * PTS;
    if (blockIdx.x == 0 && blockIdx.y == 0 && tid < PCG)
        hout[c0 + tid] = hin[c0 + tid];
    for (int idx = tid; idx < PITT * (PCG / 4); idx += 256) {
        int tok = idx >> 2, q = idx & 3;
        int gy = ty0 - 3 + tok / PIT, gx = tx0 - 3 + tok % PIT;
        float4 v = make_float4(0.f, 0.f, 0.f, 0.f);
        if (gy >= 0 && gy < HS && gx >= 0 && gx < HS)
            v = *reinterpret_cast<const float4*>(hin + (size_t)(1 + gy * HS + gx) * 512 + c0 + q * 4);
        inb[q * 4 + 0][tok] = v.x; inb[q * 4 + 1][tok] = v.y;
        inb[q * 4 + 2][tok] = v.z; inb[q * 4 + 3][tok] = v.w;
    }
    for (int idx = tid; idx < PCG * 49; idx += 256) {
        int c = idx / 49, t = idx % 49;
        int ky = t / 7, kx = t % 7, dy = ky - 3, dx = kx - 3;
        float w = w7[(size_t)(c0 + c) * 49 + t];
        if (dy >= -2 && dy <= 2 && dx >= -2 && dx <= 2)
            w += w5[(size_t)(c0 + c) * 25 + (dy + 2) * 5 + (dx + 2)];
        if (dy >= -1 && dy <= 1 && dx >= -1 && dx <= 1)
            w += w3[(size_t)(c0 + c) * 9 + (dy + 1) * 3 + (dx + 1)];
        wc[c][t] = w;
    }
    if (tid < PCG) bs[tid] = b7[c0 + tid] + b5[c0 + tid] + b3[c0 + tid];
    __syncthreads();
    int oy = tid >> 4, ox = tid & 15;
    int gy = ty0 + oy, gx = tx0 + ox;
    if (gy >= HS || gx >= HS) return;
    float* out = hout + (size_t)(1 + gy * HS + gx) * 512 + c0;
#pragma unroll 4
    for (int c = 0; c < PCG; ++c) {
        float acc = inb[c][(oy + 3) * PIT + ox + 3] + bs[c];
#pragma unroll
        for (int ky = 0; ky < 7; ++ky)
#pragma unroll
            for (int kx = 0; kx < 7; ++kx)
                acc += wc[c][ky * 7 + kx] * inb[c][(oy + ky) * PIT + ox + kx];
        out[c] = acc;
    }
}

// ---------------- final LN(row0) + fc2 + softmax + argmax ----------------
__global__ __launch_bounds__(256) void final_k(const float* __restrict__ h,
                                               const float* __restrict__ g, const float* __restrict__ bb,
                                               const float* __restrict__ w, const float* __restrict__ fb,
                                               float* __restrict__ out)
{
    __shared__ float red[256];
    int tid = threadIdx.x;
    float v0 = h[tid], v1 = h[tid + 256];
    float mu = blockReduceSumF(v0 + v1, red, tid) * (1.f / 512.f);
    float d0 = v0 - mu, d1 = v1 - mu;
    float var = blockReduceSumF(d0 * d0 + d1 * d1, red, tid) * (1.f / 512.f);
    float rstd = rsqrtf(var + 1e-5f);
    float e0 = d0 * rstd * g[tid] + bb[tid];
    float e1 = d1 * rstd * g[tid + 256] + bb[tid + 256];
    out[5 + tid] = e0;
    out[5 + 256 + tid] = e1;
    float l0p = e0 * w[tid * 2] + e1 * w[(tid + 256) * 2];
    float l1p = e0 * w[tid * 2 + 1] + e1 * w[(tid + 256) * 2 + 1];
    float l0 = blockReduceSumF(l0p, red, tid);
    float l1 = blockReduceSumF(l1p, red, tid);
    if (!tid) {
        l0 += fb[0]; l1 += fb[1];
        out[0] = l0; out[1] = l1;
        float mx = fmaxf(l0, l1);
        float p0 = expf(l0 - mx), p1 = expf(l1 - mx);
        float si = 1.f / (p0 + p1);
        out[2] = p0 * si; out[3] = p1 * si;
        out[4] = (l1 > l0) ? 1.f : 0.f;
    }
}

// ---------------- host orchestration ----------------
struct WsPtrs {
    float *h, *h2, *xb, *qkv, *ql, *kl, *a2, *z, *z2, *xz, *t1, *t2, *av, *W, *rs, *cs, *scal;
    float *S, *rmax3, *rsum3, *rmax1, *rsum1, *part;
};

static void run_attn(float* hbuf, const float* ln_g, const float* ln_b,
                     const float* qkv_w, const float* out_w, const float* out_b,
                     const float* conv_w, const WsPtrs& P, hipStream_t s)
{
    ln_pad_k<<<NP, 256, 0, s>>>(hbuf, ln_g, ln_b, P.xb);
    gemm_f32<<<dim3(1536 / 64, NP / 64), 256, 0, s>>>(P.xb, qkv_w, nullptr, nullptr, P.qkv,
                                                      NP, 1536, 512, 0);
    landmark_k<<<2048, 64, 0, s>>>(P.qkv, P.ql, P.kl);
    a2_k<<<2048, 256, 0, s>>>(P.ql, P.kl, P.a2);
    rowsum_k<<<2048, 256, 0, s>>>(P.a2, P.rs);
    colsum_k<<<2048, 256, 0, s>>>(P.a2, P.cs);
    pinv_scal_k<<<1, 256, 0, s>>>(P.rs, P.cs, P.scal);
    zinit_k<<<2048, 256, 0, s>>>(P.a2, P.scal, P.z);
    float* za = P.z; float* zb = P.z2;
    for (int it = 0; it < 6; ++it) {
        // xz = a2@za ; t1 = 7I - xz  (fused dual output)
        bgemm256<<<dim3(4, 4, 8), 256, 0, s>>>(P.a2, za, P.xz, 0.f, 1.f, P.t1, 7.f, -1.f);
        bgemm256<<<dim3(4, 4, 8), 256, 0, s>>>(P.xz, P.t1, P.t2, 15.f, -1.f, nullptr, 0.f, 0.f);
        bgemm256<<<dim3(4, 4, 8), 256, 0, s>>>(P.xz, P.t2, P.t1, 13.f, -1.f, nullptr, 0.f, 0.f);
        bgemm256<<<dim3(4, 4, 8), 256, 0, s>>>(za, P.t1, zb, 0.f, 0.25f, nullptr, 0.f, 0.f);
        float* tmp = za; za = zb; zb = tmp;
    }
    // av path: S3 scores -> row stats -> split-K PV -> reduce
    s3_k<<<dim3(NP / 64, 4, 8), 256, 0, s>>>(P.ql, P.qkv, P.S);
    rowstat3_k<<<2048, 256, 0, s>>>(P.S, P.rmax3, P.rsum3);
    pv_split_k<<<dim3(KSPLIT, 8, 8), 256, 0, s>>>(P.S, P.rmax3, P.qkv, P.part);
    pv_reduce_k<<<512, 256, 0, s>>>(P.part, P.rsum3, P.av);
    wmat_k<<<2048, 64, 0, s>>>(za, P.av, P.W);
    // a1 path: S1 scores -> row stats -> PW (token-major attn into xb)
    s1_k<<<dim3(4, NP / 64, 8), 256, 0, s>>>(P.qkv, P.kl, P.S);
    rowstat1_k<<<(NP * 8) / 4, 256, 0, s>>>(P.S, P.rmax1, P.rsum1);
    pw_k<<<dim3(1, NP / 64, 8), 256, 0, s>>>(P.S, P.rmax1, P.rsum1, P.W, P.xb);
    conv2_k<<<dim3(NP / CTT, 8), 256, 0, s>>>(P.qkv, conv_w, P.xb);
    gemm_f32<<<dim3(512 / 64, (N1 + 63) / 64), 256, 0, s>>>(P.xb + (size_t)PAD * 512, out_w,
                                                            out_b, hbuf, hbuf, N1, 512, 512, 0);
}

extern "C" void kernel_launch(void* const* d_in, const int* in_sizes, int n_in,
                              void* d_out, int out_size, void* d_ws, size_t ws_size,
                              hipStream_t stream)
{
    (void)in_sizes; (void)n_in; (void)out_size; (void)ws_size;
    const float* x       = (const float*)d_in[0];
    const float* fc1_w   = (const float*)d_in[1];
    const float* fc1_b   = (const float*)d_in[2];
    const float* cls_tok = (const float*)d_in[3];
    const float* ln1_g   = (const float*)d_in[4];
    const float* ln1_b   = (const float*)d_in[5];
    const float* qkv1_w  = (const float*)d_in[6];
    const float* out1_w  = (const float*)d_in[7];
    const float* out1_b  = (const float*)d_in[8];
    const float* conv1_w = (const float*)d_in[9];
    const float* ln2_g   = (const float*)d_in[10];
    const float* ln2_b   = (const float*)d_in[11];
    const float* qkv2_w  = (const float*)d_in[12];
    const float* out2_w  = (const float*)d_in[13];
    const float* out2_b  = (const float*)d_in[14];
    const float* conv2_w = (const float*)d_in[15];
    const float* pg7_w   = (const float*)d_in[16];
    const float* pg7_b   = (const float*)d_in[17];
    const float* pg5_w   = (const float*)d_in[18];
    const float* pg5_b   = (const float*)d_in[19];
    const float* pg3_w   = (const float*)d_in[20];
    const float* pg3_b   = (const float*)d_in[21];
    const float* norm_g  = (const float*)d_in[22];
    const float* norm_b  = (const float*)d_in[23];
    const float* fc2_w   = (const float*)d_in[24];
    const float* fc2_b   = (const float*)d_in[25];

    float* ws = (float*)d_ws;
    WsPtrs P;
    P.h     = ws;
    P.h2    = P.h    + (size_t)N1 * 512;
    P.xb    = P.h2   + (size_t)N1 * 512;
    P.qkv   = P.xb   + (size_t)NP * 512;
    P.ql    = P.qkv  + (size_t)NP * 1536;
    P.kl    = P.ql   + 131072;
    P.a2    = P.kl   + 131072;
    P.z     = P.a2   + 524288;
    P.z2    = P.z    + 524288;
    P.xz    = P.z2   + 524288;
    P.t1    = P.xz   + 524288;
    P.t2    = P.t1   + 524288;
    P.av    = P.t2   + 524288;
    P.W     = P.av   + 131072;
    P.rs    = P.W    + 131072;
    P.cs    = P.rs   + 2048;
    P.scal  = P.cs   + 2048;
    P.S     = P.scal + 64;                       // 8*256*8448 floats (shared by S1/S3)
    P.rmax3 = P.S    + (size_t)8 * 256 * NP;
    P.rsum3 = P.rmax3 + 2048;
    P.rmax1 = P.rsum3 + 2048;
    P.rsum1 = P.rmax1 + (size_t)8 * NP;
    // pv partials (8*131072 = 1M floats) alias the pinv temporaries xz+t1,
    // which are dead by the time pv_split_k runs (za holds the final z).
    P.part  = P.xz;

    gemm_f32<<<dim3(512 / 64, NTOK / 64), 256, 0, stream>>>(x, fc1_w, fc1_b, nullptr,
                                                            P.h + 512, NTOK, 512, INDIM, 1);
    fixup_k<<<180, 256, 0, stream>>>(cls_tok, P.h);
    run_attn(P.h, ln1_g, ln1_b, qkv1_w, out1_w, out1_b, conv1_w, P, stream);
    ppeg_tiled_k<<<dim3(6, 6, 512 / PCG), 256, 0, stream>>>(P.h, pg7_w, pg7_b, pg5_w, pg5_b,
                                                            pg3_w, pg3_b, P.h2);
    run_attn(P.h2, ln2_g, ln2_b, qkv2_w, out2_w, out2_b, conv2_w, P, stream);
    final_k<<<1, 256, 0, stream>>>(P.h2, norm_g, norm_b, fc2_w, fc2_b, (float*)d_out);
}

// Round 7
// 1699.805 us; speedup vs baseline: 3.3147x; 1.2659x over previous
//
#include <hip/hip_runtime.h>
#include <math.h>

// ---------------- constants ----------------
#define NTOK   8192
#define INDIM  1024
#define DMODEL 512
#define NHEAD  8
#define DH     64
#define N1     8282      // tokens incl cls (91*91 + 1)
#define NP     8448      // padded token count inside attention
#define PAD    166
#define NLM    256       // landmarks
#define LCH    33        // tokens per landmark chunk
#define SCALE  0.125f
#define HS     91
#define KSPLIT 8
#define KCH    (NP / KSPLIT)   // 1056

typedef __attribute__((ext_vector_type(8))) _Float16 half8;
typedef __attribute__((ext_vector_type(4))) float f32x4;
typedef unsigned short ushort_t;

#define GPTR(p) ((const __attribute__((address_space(1))) void*)(p))
#define LPTR(p) ((__attribute__((address_space(3))) void*)(p))

// f32 <-> fp16 helpers (RNE via hardware convert)
__device__ __forceinline__ ushort_t f2h(float f) {
    union { _Float16 h; ushort_t u; } v; v.h = (_Float16)f;
    return v.u;
}
__device__ __forceinline__ float h2f(ushort_t u) {
    union { ushort_t u; _Float16 h; } v; v.u = u;
    return (float)v.h;
}

// ---------------- reduce helpers (256-thread blocks) ----------------
__device__ __forceinline__ float blockReduceSumF(float v, float* red, int tid) {
    red[tid] = v; __syncthreads();
    for (int s = 128; s > 0; s >>= 1) {
        if (tid < s) red[tid] += red[tid + s];
        __syncthreads();
    }
    float r = red[0]; __syncthreads();
    return r;
}
__device__ __forceinline__ float blockReduceMaxF(float v, float* red, int tid) {
    red[tid] = v; __syncthreads();
    for (int s = 128; s > 0; s >>= 1) {
        if (tid < s) red[tid] = fmaxf(red[tid], red[tid + s]);
        __syncthreads();
    }
    float r = red[0]; __syncthreads();
    return r;
}

// ---------------- weight transpose+cast: wT[n][k] = fp16(w[k][n]) ----------------
__global__ __launch_bounds__(256) void tcast_k(const float* __restrict__ w, ushort_t* __restrict__ wT,
                                               int K, int N)
{
    __shared__ float tb[32][33];
    int tx = threadIdx.x & 31, ty = threadIdx.x >> 5;   // ty 0..7
    int n0 = blockIdx.x * 32, k0 = blockIdx.y * 32;
#pragma unroll
    for (int i = 0; i < 4; ++i)
        tb[ty + i * 8][tx] = w[(size_t)(k0 + ty + i * 8) * N + n0 + tx];
    __syncthreads();
#pragma unroll
    for (int i = 0; i < 4; ++i)
        wT[(size_t)(n0 + ty + i * 8) * K + k0 + tx] = f2h(tb[tx][ty + i * 8]);
}

// ---------------- cast f32 -> fp16 (4 els/thread) ----------------
__global__ void bcast_k(const float* __restrict__ x, ushort_t* __restrict__ o)
{
    int i = blockIdx.x * 256 + threadIdx.x;
    float4 v = reinterpret_cast<const float4*>(x)[i];
    ushort4 u;
    u.x = f2h(v.x); u.y = f2h(v.y); u.z = f2h(v.z); u.w = f2h(v.w);
    reinterpret_cast<ushort4*>(o)[i] = u;
}

// ---------------- fp16 MFMA GEMM: C(f32) = [res +] A@B [+ bias] [relu] ----------------
// A: fp16 [.][lda] row-major; BT: fp16 [N][ldb] = B^T; C: f32 [.][ldc].
// Tile 128x128, BK=32, 4 waves (2x2), each wave 64x64 via 4x4 16x16x32 frags.
__global__ __launch_bounds__(256) void gemm_f16(
    const ushort_t* __restrict__ A, const ushort_t* __restrict__ BT,
    const float* __restrict__ bias, const float* __restrict__ res,
    float* __restrict__ C, int Mvalid, int K, int lda, int ldb, int ldc, int relu)
{
    __shared__ ushort_t As[128 * 32];
    __shared__ ushort_t Bs[128 * 32];
    const int tid = threadIdx.x;
    const int wave = tid >> 6, lane = tid & 63;
    const int row0 = blockIdx.y * 128, col0 = blockIdx.x * 128;
    const int wr = (wave >> 1) * 64, wc = (wave & 1) * 64;
    const int sRow = wave * 16 + (lane >> 2);     // row within 64-row staging group
    const int sCh = (lane & 3) * 8;               // k-chunk (8 fp16 = 16B)
    const int lr = lane & 15, lk = (lane >> 4) * 8, lq = (lane >> 4) * 4;
    f32x4 acc[4][4] = {};
    for (int k0 = 0; k0 < K; k0 += 32) {
        __syncthreads();
#pragma unroll
        for (int i = 0; i < 2; ++i) {
            const ushort_t* gp = A + (size_t)(row0 + i * 64 + sRow) * lda + k0 + sCh;
            __builtin_amdgcn_global_load_lds(GPTR(gp), LPTR(As + (i * 64 + wave * 16) * 32), 16, 0, 0);
            const ushort_t* gq = BT + (size_t)(col0 + i * 64 + sRow) * ldb + k0 + sCh;
            __builtin_amdgcn_global_load_lds(GPTR(gq), LPTR(Bs + (i * 64 + wave * 16) * 32), 16, 0, 0);
        }
        __syncthreads();
        half8 af[4], bfr[4];
#pragma unroll
        for (int mi = 0; mi < 4; ++mi)
            af[mi] = *reinterpret_cast<const half8*>(&As[(wr + mi * 16 + lr) * 32 + lk]);
#pragma unroll
        for (int ni = 0; ni < 4; ++ni)
            bfr[ni] = *reinterpret_cast<const half8*>(&Bs[(wc + ni * 16 + lr) * 32 + lk]);
#pragma unroll
        for (int mi = 0; mi < 4; ++mi)
#pragma unroll
            for (int ni = 0; ni < 4; ++ni)
                acc[mi][ni] = __builtin_amdgcn_mfma_f32_16x16x32_f16(af[mi], bfr[ni], acc[mi][ni], 0, 0, 0);
    }
#pragma unroll
    for (int mi = 0; mi < 4; ++mi) {
#pragma unroll
        for (int q = 0; q < 4; ++q) {
            int r = row0 + wr + mi * 16 + lq + q;
            if (r >= Mvalid) continue;
#pragma unroll
            for (int ni = 0; ni < 4; ++ni) {
                int c = col0 + wc + ni * 16 + lr;
                float v = acc[mi][ni][q];
                if (bias) v += bias[c];
                if (res)  v += res[(size_t)r * ldc + c];
                if (relu) v = fmaxf(v, 0.f);
                C[(size_t)r * ldc + c] = v;
            }
        }
    }
}

// ---------------- batched 256x256x256 f32 GEMM (per head): C = diag*I + ss*(A@B) ----------------
// optional second output C2 = diag2*I + ss2*(A@B)
__global__ __launch_bounds__(256) void bgemm256(
    const float* __restrict__ A, const float* __restrict__ B, float* __restrict__ C,
    float diag, float ss, float* __restrict__ C2, float diag2, float ss2)
{
    __shared__ float As[16][68];
    __shared__ float Bs[16][64];
    int hH = blockIdx.z;
    const float* Ah = A + (size_t)hH * 65536;
    const float* Bh = B + (size_t)hH * 65536;
    float* Ch = C + (size_t)hH * 65536;
    int tid = threadIdx.x;
    int row0 = blockIdx.y * 64, col0 = blockIdx.x * 64;
    int tx = tid & 15, ty = tid >> 4;
    int aRow = tid >> 2, aK = (tid & 3) * 4;
    int bRow = tid >> 4, bCol = (tid & 15) * 4;
    float acc[4][4] = {};
    for (int kb = 0; kb < 256; kb += 16) {
        float4 a4 = *reinterpret_cast<const float4*>(Ah + (size_t)(row0 + aRow) * 256 + kb + aK);
        As[aK + 0][aRow] = a4.x; As[aK + 1][aRow] = a4.y;
        As[aK + 2][aRow] = a4.z; As[aK + 3][aRow] = a4.w;
        float4 b4 = *reinterpret_cast<const float4*>(Bh + (size_t)(kb + bRow) * 256 + col0 + bCol);
        *reinterpret_cast<float4*>(&Bs[bRow][bCol]) = b4;
        __syncthreads();
#pragma unroll
        for (int k = 0; k < 16; ++k) {
            float a[4], b[4];
#pragma unroll
            for (int i = 0; i < 4; ++i) a[i] = As[k][ty * 4 + i];
#pragma unroll
            for (int j = 0; j < 4; ++j) b[j] = Bs[k][tx * 4 + j];
#pragma unroll
            for (int i = 0; i < 4; ++i)
#pragma unroll
                for (int j = 0; j < 4; ++j) acc[i][j] += a[i] * b[j];
        }
        __syncthreads();
    }
#pragma unroll
    for (int i = 0; i < 4; ++i) {
        int r = row0 + ty * 4 + i;
#pragma unroll
        for (int j = 0; j < 4; ++j) {
            int c = col0 + tx * 4 + j;
            float v = ss * acc[i][j];
            if (r == c) v += diag;
            Ch[(size_t)r * 256 + c] = v;
            if (C2) {
                float v2 = ss2 * acc[i][j];
                if (r == c) v2 += diag2;
                C2[(size_t)hH * 65536 + (size_t)r * 256 + c] = v2;
            }
        }
    }
}

// ---------------- fixup: cls token + wrap rows ----------------
__global__ void fixup_k(const float* __restrict__ cls, float* __restrict__ h)
{
    int i = blockIdx.x * 256 + threadIdx.x;   // 90*512
    if (i < 512) {
        h[i] = cls[i];
    } else {
        int j = i - 512;                       // j < 89*512
        h[(size_t)8193 * 512 + j] = h[512 + j];
    }
}

// ---------------- layernorm + front zero-pad: out[NP][512] fp16 ----------------
__global__ __launch_bounds__(256) void ln_pad_k(
    const float* __restrict__ h, const float* __restrict__ g, const float* __restrict__ b,
    ushort_t* __restrict__ out)
{
    int row = blockIdx.x, tid = threadIdx.x;
    __shared__ float red[256];
    ushort_t* o = out + (size_t)row * 512;
    if (row < PAD) { o[tid] = 0; o[tid + 256] = 0; return; }
    const float* x = h + (size_t)(row - PAD) * 512;
    float v0 = x[tid], v1 = x[tid + 256];
    float mu = blockReduceSumF(v0 + v1, red, tid) * (1.f / 512.f);
    float d0 = v0 - mu, d1 = v1 - mu;
    float var = blockReduceSumF(d0 * d0 + d1 * d1, red, tid) * (1.f / 512.f);
    float rstd = rsqrtf(var + 1e-5f);
    o[tid]       = f2h(d0 * rstd * g[tid] + b[tid]);
    o[tid + 256] = f2h(d1 * rstd * g[tid + 256] + b[tid + 256]);
}

// ---------------- landmark means (q scaled) ----------------
__global__ void landmark_k(const float* __restrict__ qkv, float* __restrict__ ql, float* __restrict__ kl)
{
    int h = blockIdx.x >> 8, m = blockIdx.x & 255, d = threadIdx.x;  // 64 threads
    const float* base = qkv + (size_t)(m * LCH) * 1536 + h * 64 + d;
    float sq = 0.f, sk = 0.f;
    for (int i = 0; i < LCH; ++i) {
        sq += base[(size_t)i * 1536];
        sk += base[(size_t)i * 1536 + 512];
    }
    ql[((size_t)h * 256 + m) * 64 + d] = sq * (SCALE / (float)LCH);
    kl[((size_t)h * 256 + m) * 64 + d] = sk * (1.f / (float)LCH);
}

// ---------------- a2 = softmax(ql @ kl^T), f32 ----------------
__global__ __launch_bounds__(256) void a2_k(
    const float* __restrict__ ql, const float* __restrict__ kl, float* __restrict__ a2)
{
    int h = blockIdx.x >> 8, r = blockIdx.x & 255, tid = threadIdx.x;
    __shared__ float qv[64]; __shared__ float red[256];
    if (tid < 64) qv[tid] = ql[((size_t)h * 256 + r) * 64 + tid];
    __syncthreads();
    const float* kp = kl + ((size_t)h * 256 + tid) * 64;
    float dot = 0.f;
#pragma unroll
    for (int d = 0; d < 64; ++d) dot += qv[d] * kp[d];
    float mx = blockReduceMaxF(dot, red, tid);
    float e = expf(dot - mx);
    float s = blockReduceSumF(e, red, tid);
    a2[((size_t)h * 256 + r) * 256 + tid] = e / s;
}

// ---------------- pinv init helpers (f32) ----------------
__global__ __launch_bounds__(256) void rowsum_k(const float* __restrict__ a2, float* __restrict__ rs)
{
    int r = blockIdx.x; __shared__ float red[256];
    float v = fabsf(a2[(size_t)r * 256 + threadIdx.x]);
    float s = blockReduceSumF(v, red, threadIdx.x);
    if (!threadIdx.x) rs[r] = s;
}
__global__ __launch_bounds__(256) void colsum_k(const float* __restrict__ a2, float* __restrict__ cs)
{
    int h = blockIdx.x >> 8, c = blockIdx.x & 255;
    __shared__ float red[256];
    float v = fabsf(a2[(size_t)h * 65536 + (size_t)threadIdx.x * 256 + c]);
    float s = blockReduceSumF(v, red, threadIdx.x);
    if (!threadIdx.x) cs[blockIdx.x] = s;
}
__global__ __launch_bounds__(256) void pinv_scal_k(const float* __restrict__ rs, const float* __restrict__ cs,
                                                   float* __restrict__ scal)
{
    int tid = threadIdx.x; __shared__ float red[256];
    float m1 = -1e30f, m2 = -1e30f;
    for (int i = tid; i < 2048; i += 256) { m1 = fmaxf(m1, rs[i]); m2 = fmaxf(m2, cs[i]); }
    m1 = blockReduceMaxF(m1, red, tid);
    m2 = blockReduceMaxF(m2, red, tid);
    if (!tid) scal[0] = 1.f / (m1 * m2);
}
__global__ __launch_bounds__(256) void zinit_k(const float* __restrict__ a2, const float* __restrict__ scal,
                                               float* __restrict__ z)
{
    int h = blockIdx.x >> 8, r = blockIdx.x & 255, c = threadIdx.x;
    z[(size_t)h * 65536 + (size_t)r * 256 + c] = a2[(size_t)h * 65536 + (size_t)c * 256 + r] * scal[0];
}

// ---------------- S3 = ql @ K^T  (per head, 256 x NP) ----------------
__global__ __launch_bounds__(256) void s3_k(const float* __restrict__ ql, const float* __restrict__ qkv,
                                            float* __restrict__ S)
{
    __shared__ float As[16][68];
    __shared__ float Bs[16][68];
    int h = blockIdx.z;
    int col0 = blockIdx.x * 64, row0 = blockIdx.y * 64;
    int tid = threadIdx.x;
    int r4 = tid >> 2, k4 = (tid & 3) * 4;
    int tx = tid & 15, ty = tid >> 4;
    const float* qlh = ql + (size_t)h * 256 * 64;
    float acc[4][4] = {};
    for (int kb = 0; kb < 64; kb += 16) {
        float4 a4 = *reinterpret_cast<const float4*>(qlh + (size_t)(row0 + r4) * 64 + kb + k4);
        As[k4 + 0][r4] = a4.x; As[k4 + 1][r4] = a4.y; As[k4 + 2][r4] = a4.z; As[k4 + 3][r4] = a4.w;
        float4 b4 = *reinterpret_cast<const float4*>(qkv + (size_t)(col0 + r4) * 1536 + 512 + h * 64 + kb + k4);
        Bs[k4 + 0][r4] = b4.x; Bs[k4 + 1][r4] = b4.y; Bs[k4 + 2][r4] = b4.z; Bs[k4 + 3][r4] = b4.w;
        __syncthreads();
#pragma unroll
        for (int k = 0; k < 16; ++k) {
            float a[4], b[4];
#pragma unroll
            for (int i = 0; i < 4; ++i) a[i] = As[k][ty * 4 + i];
#pragma unroll
            for (int j = 0; j < 4; ++j) b[j] = Bs[k][tx * 4 + j];
#pragma unroll
            for (int i = 0; i < 4; ++i)
#pragma unroll
                for (int j = 0; j < 4; ++j) acc[i][j] += a[i] * b[j];
        }
        __syncthreads();
    }
#pragma unroll
    for (int i = 0; i < 4; ++i)
#pragma unroll
        for (int j = 0; j < 4; ++j)
            S[((size_t)h * 256 + row0 + ty * 4 + i) * (size_t)NP + col0 + tx * 4 + j] = acc[i][j];
}

// ---------------- row max/sum over S3 rows (len NP) ----------------
__global__ __launch_bounds__(256) void rowstat3_k(const float* __restrict__ S,
                                                  float* __restrict__ rmax, float* __restrict__ rsum)
{
    __shared__ float red[256];
    int row = blockIdx.x, tid = threadIdx.x;
    const float* p = S + (size_t)row * NP;
    float mx = -1e30f;
    for (int i = tid; i < NP; i += 256) mx = fmaxf(mx, p[i]);
    mx = blockReduceMaxF(mx, red, tid);
    float s = 0.f;
    for (int i = tid; i < NP; i += 256) s += __expf(p[i] - mx);
    s = blockReduceSumF(s, red, tid);
    if (!tid) { rmax[row] = mx; rsum[row] = s; }
}

// ---------------- av partials: split-K GEMM with fused exp ----------------
__global__ __launch_bounds__(256) void pv_split_k(const float* __restrict__ S,
                                                  const float* __restrict__ rmax,
                                                  const float* __restrict__ qkv,
                                                  float* __restrict__ part)
{
    __shared__ float As[32][34];
    __shared__ float Bs[16][68];
    int ks = blockIdx.x, r0 = blockIdx.y * 32, h = blockIdx.z;
    int tid = threadIdx.x;
    int ar = tid >> 3, ak = (tid & 7) * 2;
    int bk = tid >> 4, bn4 = (tid & 15) * 4;
    int tx = tid & 15, ty = tid >> 4;
    size_t rowbase = (size_t)h * 256 + r0;
    float rmA = rmax[rowbase + ar];
    float acc[2][4] = {};
    int k0 = ks * KCH;
    for (int kb = k0; kb < k0 + KCH; kb += 16) {
        float2 a2v = *reinterpret_cast<const float2*>(S + (rowbase + ar) * (size_t)NP + kb + ak);
        As[ar][ak]     = __expf(a2v.x - rmA);
        As[ar][ak + 1] = __expf(a2v.y - rmA);
        float4 b4 = *reinterpret_cast<const float4*>(qkv + (size_t)(kb + bk) * 1536 + 1024 + h * 64 + bn4);
        *reinterpret_cast<float4*>(&Bs[bk][bn4]) = b4;
        __syncthreads();
#pragma unroll
        for (int k = 0; k < 16; ++k) {
            float a0 = As[ty * 2][k], a1 = As[ty * 2 + 1][k];
            float b[4];
#pragma unroll
            for (int j = 0; j < 4; ++j) b[j] = Bs[k][tx * 4 + j];
#pragma unroll
            for (int j = 0; j < 4; ++j) { acc[0][j] += a0 * b[j]; acc[1][j] += a1 * b[j]; }
        }
        __syncthreads();
    }
    float* pp = part + ((size_t)(ks * 8 + h) * 256 + r0) * 64;
#pragma unroll
    for (int i = 0; i < 2; ++i)
#pragma unroll
        for (int j = 0; j < 4; ++j)
            pp[(ty * 2 + i) * 64 + tx * 4 + j] = acc[i][j];
}

__global__ __launch_bounds__(256) void pv_reduce_k(const float* __restrict__ part,
                                                   const float* __restrict__ rsum,
                                                   float* __restrict__ av)
{
    int idx = blockIdx.x * 256 + threadIdx.x;   // 131072
    int rc = idx >> 6;                           // h*256+r
    float s = 0.f;
#pragma unroll
    for (int ks = 0; ks < KSPLIT; ++ks)
        s += part[(size_t)ks * 131072 + idx];
    av[idx] = s / rsum[rc];
}

// ---------------- W = z @ av (per head 256x256 @ 256x64), f32 ----------------
__global__ void wmat_k(const float* __restrict__ z, const float* __restrict__ av, float* __restrict__ W)
{
    int h = blockIdx.x >> 8, m = blockIdx.x & 255, d = threadIdx.x;  // 64 threads
    const float* zp = z + (size_t)h * 65536 + (size_t)m * 256;
    const float* ap = av + (size_t)h * 16384 + d;
    float acc = 0.f;
    for (int j = 0; j < 256; ++j) acc += zp[j] * ap[(size_t)j * 64];
    W[((size_t)h * 256 + m) * 64 + d] = acc;
}

// ---------------- S1 = (q*SCALE) @ kl^T  (per head, NP x 256) ----------------
__global__ __launch_bounds__(256) void s1_k(const float* __restrict__ qkv, const float* __restrict__ kl,
                                            float* __restrict__ S)
{
    __shared__ float As[16][68];
    __shared__ float Bs[16][68];
    int h = blockIdx.z;
    int col0 = blockIdx.x * 64, row0 = blockIdx.y * 64;
    int tid = threadIdx.x;
    int r4 = tid >> 2, k4 = (tid & 3) * 4;
    int tx = tid & 15, ty = tid >> 4;
    float acc[4][4] = {};
    for (int kb = 0; kb < 64; kb += 16) {
        float4 a4 = *reinterpret_cast<const float4*>(qkv + (size_t)(row0 + r4) * 1536 + h * 64 + kb + k4);
        As[k4 + 0][r4] = a4.x * SCALE; As[k4 + 1][r4] = a4.y * SCALE;
        As[k4 + 2][r4] = a4.z * SCALE; As[k4 + 3][r4] = a4.w * SCALE;
        float4 b4 = *reinterpret_cast<const float4*>(kl + ((size_t)h * 256 + col0 + r4) * 64 + kb + k4);
        Bs[k4 + 0][r4] = b4.x; Bs[k4 + 1][r4] = b4.y; Bs[k4 + 2][r4] = b4.z; Bs[k4 + 3][r4] = b4.w;
        __syncthreads();
#pragma unroll
        for (int k = 0; k < 16; ++k) {
            float a[4], b[4];
#pragma unroll
            for (int i = 0; i < 4; ++i) a[i] = As[k][ty * 4 + i];
#pragma unroll
            for (int j = 0; j < 4; ++j) b[j] = Bs[k][tx * 4 + j];
#pragma unroll
            for (int i = 0; i < 4; ++i)
#pragma unroll
                for (int j = 0; j < 4; ++j) acc[i][j] += a[i] * b[j];
        }
        __syncthreads();
    }
#pragma unroll
    for (int i = 0; i < 4; ++i)
#pragma unroll
        for (int j = 0; j < 4; ++j)
            S[((size_t)h * NP + row0 + ty * 4 + i) * 256 + col0 + tx * 4 + j] = acc[i][j];
}

// ---------------- row max/sum over S1 rows (len 256), wave per row ----------------
__global__ __launch_bounds__(256) void rowstat1_k(const float* __restrict__ S,
                                                  float* __restrict__ rmax, float* __restrict__ rsum)
{
    int wave = threadIdx.x >> 6, lane = threadIdx.x & 63;
    size_t row = (size_t)blockIdx.x * 4 + wave;
    const float* p = S + row * 256;
    float v0 = p[lane], v1 = p[lane + 64], v2 = p[lane + 128], v3 = p[lane + 192];
    float mx = fmaxf(fmaxf(v0, v1), fmaxf(v2, v3));
    for (int off = 32; off; off >>= 1) mx = fmaxf(mx, __shfl_xor(mx, off, 64));
    float s = __expf(v0 - mx) + __expf(v1 - mx) + __expf(v2 - mx) + __expf(v3 - mx);
    for (int off = 32; off; off >>= 1) s += __shfl_xor(s, off, 64);
    if (!lane) { rmax[row] = mx; rsum[row] = s; }
}

// ---------------- attn = softmax(S1) @ W (exp fused, token-major fp16 out) ----------------
__global__ __launch_bounds__(256) void pw_k(const float* __restrict__ S,
                                            const float* __restrict__ rmax, const float* __restrict__ rsum,
                                            const float* __restrict__ W, ushort_t* __restrict__ attn)
{
    __shared__ float As[16][68];
    __shared__ float Bs[16][68];
    int h = blockIdx.z;
    int row0 = blockIdx.y * 64;
    int tid = threadIdx.x;
    int r4 = tid >> 2, k4 = (tid & 3) * 4;
    int bk = tid >> 4, bn4 = (tid & 15) * 4;
    int tx = tid & 15, ty = tid >> 4;
    size_t rowbase = (size_t)h * NP + row0;
    float rm = rmax[rowbase + r4];
    float acc[4][4] = {};
    for (int kb = 0; kb < 256; kb += 16) {
        float4 a4 = *reinterpret_cast<const float4*>(S + (rowbase + r4) * 256 + kb + k4);
        As[k4 + 0][r4] = __expf(a4.x - rm); As[k4 + 1][r4] = __expf(a4.y - rm);
        As[k4 + 2][r4] = __expf(a4.z - rm); As[k4 + 3][r4] = __expf(a4.w - rm);
        float4 b4 = *reinterpret_cast<const float4*>(W + ((size_t)h * 256 + kb + bk) * 64 + bn4);
        *reinterpret_cast<float4*>(&Bs[bk][bn4]) = b4;
        __syncthreads();
#pragma unroll
        for (int k = 0; k < 16; ++k) {
            float a[4], b[4];
#pragma unroll
            for (int i = 0; i < 4; ++i) a[i] = As[k][ty * 4 + i];
#pragma unroll
            for (int j = 0; j < 4; ++j) b[j] = Bs[k][tx * 4 + j];
#pragma unroll
            for (int i = 0; i < 4; ++i)
#pragma unroll
                for (int j = 0; j < 4; ++j) acc[i][j] += a[i] * b[j];
        }
        __syncthreads();
    }
#pragma unroll
    for (int i = 0; i < 4; ++i) {
        int t = row0 + ty * 4 + i;
        float inv = 1.f / rsum[(size_t)h * NP + t];
#pragma unroll
        for (int j = 0; j < 4; ++j)
            attn[(size_t)t * 512 + h * 64 + tx * 4 + j] = f2h(acc[i][j] * inv);
    }
}

// ---------------- tiled depthwise 33-tap conv over tokens on v, added to fp16 attn ----------------
#define CTT 64
__global__ __launch_bounds__(256) void conv2_k(const float* __restrict__ qkv,
                                               const float* __restrict__ cw,
                                               ushort_t* __restrict__ attn)
{
    __shared__ float vt[CTT + 32][64];
    int t0 = blockIdx.x * CTT;
    int h = blockIdx.y;
    int tid = threadIdx.x;
    for (int s = tid; s < (CTT + 32) * 16; s += 256) {
        int row = s >> 4, q = s & 15;
        int tt = t0 - 16 + row;
        float4 v = make_float4(0.f, 0.f, 0.f, 0.f);
        if (tt >= 0 && tt < NP)
            v = *reinterpret_cast<const float4*>(qkv + (size_t)tt * 1536 + 1024 + h * 64 + q * 4);
        *reinterpret_cast<float4*>(&vt[row][q * 4]) = v;
    }
    float w33[33];
#pragma unroll
    for (int j = 0; j < 33; ++j) w33[j] = cw[h * 33 + j];
    __syncthreads();
    int c = tid & 63, tr = tid >> 6;   // tr uniform per wave
    float win[48];
#pragma unroll
    for (int j = 0; j < 48; ++j) win[j] = vt[tr * 16 + j][c];
#pragma unroll
    for (int i = 0; i < 16; ++i) {
        float acc = 0.f;
#pragma unroll
        for (int j = 0; j < 33; ++j) acc += w33[j] * win[i + j];
        size_t idx = (size_t)(t0 + tr * 16 + i) * 512 + h * 64 + c;
        attn[idx] = f2h(h2f(attn[idx]) + acc);
    }
}

// ---------------- PPEG tiled: 16x16 token tile x 16 channels, combined 49-tap ----------------
#define PTS  16          // out tile side
#define PIT  22          // in tile side (halo 3)
#define PITT (PIT*PIT)   // 484
#define PCG  16          // channels per block
__global__ __launch_bounds__(256) void ppeg_tiled_k(
    const float* __restrict__ hin,
    const float* __restrict__ w7, const float* __restrict__ b7,
    const float* __restrict__ w5, const float* __restrict__ b5,
    const float* __restrict__ w3, const float* __restrict__ b3,
    float* __restrict__ hout)
{
    __shared__ float inb[PCG][PITT + 1];
    __shared__ float wc[PCG][49];
    __shared__ float bs[PCG];
    int tid = threadIdx.x;
    int c0 = blockIdx.z * PCG;
    int ty0 = blockIdx.y * PTS, tx0 = blockIdx.x * PTS;
    if (blockIdx.x == 0 && blockIdx.y == 0 && tid < PCG)
        hout[c0 + tid] = hin[c0 + tid];
    for (int idx = tid; idx < PITT * (PCG / 4); idx += 256) {
        int tok = idx >> 2, q = idx & 3;
        int gy = ty0 - 3 + tok / PIT, gx = tx0 - 3 + tok % PIT;
        float4 v = make_float4(0.f, 0.f, 0.f, 0.f);
        if (gy >= 0 && gy < HS && gx >= 0 && gx < HS)
            v = *reinterpret_cast<const float4*>(hin + (size_t)(1 + gy * HS + gx) * 512 + c0 + q * 4);
        inb[q * 4 + 0][tok] = v.x; inb[q * 4 + 1][tok] = v.y;
        inb[q * 4 + 2][tok] = v.z; inb[q * 4 + 3][tok] = v.w;
    }
    for (int idx = tid; idx < PCG * 49; idx += 256) {
        int c = idx / 49, t = idx % 49;
        int ky = t / 7, kx = t % 7, dy = ky - 3, dx = kx - 3;
        float w = w7[(size_t)(c0 + c) * 49 + t];
        if (dy >= -2 && dy <= 2 && dx >= -2 && dx <= 2)
            w += w5[(size_t)(c0 + c) * 25 + (dy + 2) * 5 + (dx + 2)];
        if (dy >= -1 && dy <= 1 && dx >= -1 && dx <= 1)
            w += w3[(size_t)(c0 + c) * 9 + (dy + 1) * 3 + (dx + 1)];
        wc[c][t] = w;
    }
    if (tid < PCG) bs[tid] = b7[c0 + tid] + b5[c0 + tid] + b3[c0 + tid];
    __syncthreads();
    int oy = tid >> 4, ox = tid & 15;
    int gy = ty0 + oy, gx = tx0 + ox;
    if (gy >= HS || gx >= HS) return;
    float* out = hout + (size_t)(1 + gy * HS + gx) * 512 + c0;
#pragma unroll 4
    for (int c = 0; c < PCG; ++c) {
        float acc = inb[c][(oy + 3) * PIT + ox + 3] + bs[c];
#pragma unroll
        for (int ky = 0; ky < 7; ++ky)
#pragma unroll
            for (int kx = 0; kx < 7; ++kx)
                acc += wc[c][ky * 7 + kx] * inb[c][(oy + ky) * PIT + ox + kx];
        out[c] = acc;
    }
}

// ---------------- final LN(row0) + fc2 + softmax + argmax ----------------
__global__ __launch_bounds__(256) void final_k(const float* __restrict__ h,
                                               const float* __restrict__ g, const float* __restrict__ bb,
                                               const float* __restrict__ w, const float* __restrict__ fb,
                                               float* __restrict__ out)
{
    __shared__ float red[256];
    int tid = threadIdx.x;
    float v0 = h[tid], v1 = h[tid + 256];
    float mu = blockReduceSumF(v0 + v1, red, tid) * (1.f / 512.f);
    float d0 = v0 - mu, d1 = v1 - mu;
    float var = blockReduceSumF(d0 * d0 + d1 * d1, red, tid) * (1.f / 512.f);
    float rstd = rsqrtf(var + 1e-5f);
    float e0 = d0 * rstd * g[tid] + bb[tid];
    float e1 = d1 * rstd * g[tid + 256] + bb[tid + 256];
    out[5 + tid] = e0;
    out[5 + 256 + tid] = e1;
    float l0p = e0 * w[tid * 2] + e1 * w[(tid + 256) * 2];
    float l1p = e0 * w[tid * 2 + 1] + e1 * w[(tid + 256) * 2 + 1];
    float l0 = blockReduceSumF(l0p, red, tid);
    float l1 = blockReduceSumF(l1p, red, tid);
    if (!tid) {
        l0 += fb[0]; l1 += fb[1];
        out[0] = l0; out[1] = l1;
        float mx = fmaxf(l0, l1);
        float p0 = expf(l0 - mx), p1 = expf(l1 - mx);
        float si = 1.f / (p0 + p1);
        out[2] = p0 * si; out[3] = p1 * si;
        out[4] = (l1 > l0) ? 1.f : 0.f;
    }
}

// ---------------- host orchestration ----------------
struct WsPtrs {
    float *h, *h2, *qkv, *ql, *kl, *a2, *z, *z2, *xz, *t1, *t2, *av, *W, *rs, *cs, *scal;
    float *S, *rmax3, *rsum3, *rmax1, *rsum1, *part;
    ushort_t *xbB, *qkvT, *outT, *x16, *fc1T;
};

static void run_attn(float* hbuf, const float* ln_g, const float* ln_b,
                     const float* qkv_w, const float* out_w, const float* out_b,
                     const float* conv_w, const WsPtrs& P, hipStream_t s)
{
    // weight prep (fp16 transposed)
    tcast_k<<<dim3(1536 / 32, 512 / 32), 256, 0, s>>>(qkv_w, P.qkvT, 512, 1536);
    tcast_k<<<dim3(512 / 32, 512 / 32), 256, 0, s>>>(out_w, P.outT, 512, 512);
    // layernorm + pad (fp16)
    ln_pad_k<<<NP, 256, 0, s>>>(hbuf, ln_g, ln_b, P.xbB);
    // qkv = xb @ qkv_w  (MFMA, f32 out)
    gemm_f16<<<dim3(1536 / 128, NP / 128), 256, 0, s>>>(P.xbB, P.qkvT, nullptr, nullptr,
                                                        P.qkv, NP, 512, 512, 512, 1536, 0);
    landmark_k<<<2048, 64, 0, s>>>(P.qkv, P.ql, P.kl);
    a2_k<<<2048, 256, 0, s>>>(P.ql, P.kl, P.a2);
    rowsum_k<<<2048, 256, 0, s>>>(P.a2, P.rs);
    colsum_k<<<2048, 256, 0, s>>>(P.a2, P.cs);
    pinv_scal_k<<<1, 256, 0, s>>>(P.rs, P.cs, P.scal);
    zinit_k<<<2048, 256, 0, s>>>(P.a2, P.scal, P.z);
    float* za = P.z; float* zb = P.z2;
    for (int it = 0; it < 6; ++it) {
        bgemm256<<<dim3(4, 4, 8), 256, 0, s>>>(P.a2, za, P.xz, 0.f, 1.f, P.t1, 7.f, -1.f);
        bgemm256<<<dim3(4, 4, 8), 256, 0, s>>>(P.xz, P.t1, P.t2, 15.f, -1.f, nullptr, 0.f, 0.f);
        bgemm256<<<dim3(4, 4, 8), 256, 0, s>>>(P.xz, P.t2, P.t1, 13.f, -1.f, nullptr, 0.f, 0.f);
        bgemm256<<<dim3(4, 4, 8), 256, 0, s>>>(za, P.t1, zb, 0.f, 0.25f, nullptr, 0.f, 0.f);
        float* tmp = za; za = zb; zb = tmp;
    }
    // av path
    s3_k<<<dim3(NP / 64, 4, 8), 256, 0, s>>>(P.ql, P.qkv, P.S);
    rowstat3_k<<<2048, 256, 0, s>>>(P.S, P.rmax3, P.rsum3);
    pv_split_k<<<dim3(KSPLIT, 8, 8), 256, 0, s>>>(P.S, P.rmax3, P.qkv, P.part);
    pv_reduce_k<<<512, 256, 0, s>>>(P.part, P.rsum3, P.av);
    wmat_k<<<2048, 64, 0, s>>>(za, P.av, P.W);
    // a1 path (attn -> xbB fp16, token-major)
    s1_k<<<dim3(4, NP / 64, 8), 256, 0, s>>>(P.qkv, P.kl, P.S);
    rowstat1_k<<<(NP * 8) / 4, 256, 0, s>>>(P.S, P.rmax1, P.rsum1);
    pw_k<<<dim3(1, NP / 64, 8), 256, 0, s>>>(P.S, P.rmax1, P.rsum1, P.W, P.xbB);
    conv2_k<<<dim3(NP / CTT, 8), 256, 0, s>>>(P.qkv, conv_w, P.xbB);
    // h += attn[-N1:] @ out_w + out_b  (MFMA, f32 residual epilogue)
    gemm_f16<<<dim3(512 / 128, (N1 + 127) / 128), 256, 0, s>>>(P.xbB + (size_t)PAD * 512, P.outT,
                                                               out_b, hbuf, hbuf, N1, 512, 512, 512, 512, 0);
}

extern "C" void kernel_launch(void* const* d_in, const int* in_sizes, int n_in,
                              void* d_out, int out_size, void* d_ws, size_t ws_size,
                              hipStream_t stream)
{
    (void)in_sizes; (void)n_in; (void)out_size; (void)ws_size;
    const float* x       = (const float*)d_in[0];
    const float* fc1_w   = (const float*)d_in[1];
    const float* fc1_b   = (const float*)d_in[2];
    const float* cls_tok = (const float*)d_in[3];
    const float* ln1_g   = (const float*)d_in[4];
    const float* ln1_b   = (const float*)d_in[5];
    const float* qkv1_w  = (const float*)d_in[6];
    const float* out1_w  = (const float*)d_in[7];
    const float* out1_b  = (const float*)d_in[8];
    const float* conv1_w = (const float*)d_in[9];
    const float* ln2_g   = (const float*)d_in[10];
    const float* ln2_b   = (const float*)d_in[11];
    const float* qkv2_w  = (const float*)d_in[12];
    const float* out2_w  = (const float*)d_in[13];
    const float* out2_b  = (const float*)d_in[14];
    const float* conv2_w = (const float*)d_in[15];
    const float* pg7_w   = (const float*)d_in[16];
    const float* pg7_b   = (const float*)d_in[17];
    const float* pg5_w   = (const float*)d_in[18];
    const float* pg5_b   = (const float*)d_in[19];
    const float* pg3_w   = (const float*)d_in[20];
    const float* pg3_b   = (const float*)d_in[21];
    const float* norm_g  = (const float*)d_in[22];
    const float* norm_b  = (const float*)d_in[23];
    const float* fc2_w   = (const float*)d_in[24];
    const float* fc2_b   = (const float*)d_in[25];

    float* ws = (float*)d_ws;
    WsPtrs P;
    float* cur = ws;
    P.h     = cur; cur += (size_t)N1 * 512;
    P.h2    = cur; cur += (size_t)N1 * 512;
    P.xbB   = (ushort_t*)cur; cur += (size_t)NP * 512 / 2;
    P.qkv   = cur; cur += (size_t)NP * 1536;
    P.ql    = cur; cur += 131072;
    P.kl    = cur; cur += 131072;
    P.a2    = cur; cur += 524288;
    P.z     = cur; cur += 524288;
    P.z2    = cur; cur += 524288;
    P.xz    = cur; cur += 524288;
    P.t1    = cur; cur += 524288;
    P.t2    = cur; cur += 524288;
    P.av    = cur; cur += 131072;
    P.W     = cur; cur += 131072;
    P.rs    = cur; cur += 2048;
    P.cs    = cur; cur += 2048;
    P.scal  = cur; cur += 64;
    // qkvT: 1536 x 512 halfs = 786432 ushorts = 393216 float-slots
    // (R4-R6 BUG: was 196608 -> overflow trampled by outT tcast => corrupted K/V weights)
    P.qkvT  = (ushort_t*)cur; cur += 393216 + 64;
    P.outT  = (ushort_t*)cur; cur += 131072 + 64;   // 512x512 halfs = 131072 float-slots
    P.rmax3 = cur; cur += 2048;
    P.rsum3 = cur; cur += 2048;
    P.rmax1 = cur; cur += (size_t)8 * NP;
    P.rsum1 = cur; cur += (size_t)8 * NP;
    P.part  = cur; cur += (size_t)KSPLIT * 131072;
    P.S     = cur; cur += (size_t)8 * 256 * NP;
    // x16 / fc1T alias S (only used before block 1's S-path)
    P.x16   = (ushort_t*)P.S;                                   // 8192x1024 halfs = 4194304 float-slots
    P.fc1T  = (ushort_t*)(P.S + (size_t)NTOK * INDIM / 2);      // 512x1024 halfs = 262144 float-slots

    // prep: x -> fp16, fc1_w -> fp16 transposed
    bcast_k<<<(NTOK * INDIM) / 1024, 256, 0, stream>>>(x, P.x16);
    tcast_k<<<dim3(512 / 32, 1024 / 32), 256, 0, stream>>>(fc1_w, P.fc1T, 1024, 512);
    // fc1 + relu -> h rows 1..8192 (MFMA)
    gemm_f16<<<dim3(512 / 128, NTOK / 128), 256, 0, stream>>>(P.x16, P.fc1T, fc1_b, nullptr,
                                                              P.h + 512, NTOK, 1024, 1024, 1024, 512, 1);
    fixup_k<<<180, 256, 0, stream>>>(cls_tok, P.h);
    run_attn(P.h, ln1_g, ln1_b, qkv1_w, out1_w, out1_b, conv1_w, P, stream);
    ppeg_tiled_k<<<dim3(6, 6, 512 / PCG), 256, 0, stream>>>(P.h, pg7_w, pg7_b, pg5_w, pg5_b,
                                                            pg3_w, pg3_b, P.h2);
    run_attn(P.h2, ln2_g, ln2_b, qkv2_w, out2_w, out2_b, conv2_w, P, stream);
    final_k<<<1, 256, 0, stream>>>(P.h2, norm_g, norm_b, fc2_w, fc2_b, (float*)d_out);
}

// Round 8
// 1353.959 us; speedup vs baseline: 4.1613x; 1.2554x over previous
//
#include <hip/hip_runtime.h>
#include <math.h>

// ---------------- constants ----------------
#define NTOK   8192
#define INDIM  1024
#define DMODEL 512
#define NHEAD  8
#define DH     64
#define N1     8282      // tokens incl cls (91*91 + 1)
#define NP     8448      // padded token count inside attention
#define PAD    166
#define NLM    256       // landmarks
#define LCH    33        // tokens per landmark chunk
#define SCALE  0.125f
#define HS     91
#define KSPLIT 8
#define KCH    (NP / KSPLIT)   // 1056

typedef __attribute__((ext_vector_type(8))) _Float16 half8;
typedef __attribute__((ext_vector_type(8))) short short8;
typedef __attribute__((ext_vector_type(4))) float f32x4;
typedef unsigned short ushort_t;

#define GPTR(p) ((const __attribute__((address_space(1))) void*)(p))
#define LPTR(p) ((__attribute__((address_space(3))) void*)(p))

// f32 <-> fp16 helpers (RNE via hardware convert)
__device__ __forceinline__ ushort_t f2h(float f) {
    union { _Float16 h; ushort_t u; } v; v.h = (_Float16)f;
    return v.u;
}
__device__ __forceinline__ float h2f(ushort_t u) {
    union { ushort_t u; _Float16 h; } v; v.u = u;
    return (float)v.h;
}

// ---------------- reduce helpers (256-thread blocks) ----------------
__device__ __forceinline__ float blockReduceSumF(float v, float* red, int tid) {
    red[tid] = v; __syncthreads();
    for (int s = 128; s > 0; s >>= 1) {
        if (tid < s) red[tid] += red[tid + s];
        __syncthreads();
    }
    float r = red[0]; __syncthreads();
    return r;
}
__device__ __forceinline__ float blockReduceMaxF(float v, float* red, int tid) {
    red[tid] = v; __syncthreads();
    for (int s = 128; s > 0; s >>= 1) {
        if (tid < s) red[tid] = fmaxf(red[tid], red[tid + s]);
        __syncthreads();
    }
    float r = red[0]; __syncthreads();
    return r;
}

// ---------------- weight transpose+cast: wT[n][k] = fp16(w[k][n]) ----------------
__global__ __launch_bounds__(256) void tcast_k(const float* __restrict__ w, ushort_t* __restrict__ wT,
                                               int K, int N)
{
    __shared__ float tb[32][33];
    int tx = threadIdx.x & 31, ty = threadIdx.x >> 5;   // ty 0..7
    int n0 = blockIdx.x * 32, k0 = blockIdx.y * 32;
#pragma unroll
    for (int i = 0; i < 4; ++i)
        tb[ty + i * 8][tx] = w[(size_t)(k0 + ty + i * 8) * N + n0 + tx];
    __syncthreads();
#pragma unroll
    for (int i = 0; i < 4; ++i)
        wT[(size_t)(n0 + ty + i * 8) * K + k0 + tx] = f2h(tb[tx][ty + i * 8]);
}

// ---------------- cast f32 -> fp16 (4 els/thread) ----------------
__global__ void bcast_k(const float* __restrict__ x, ushort_t* __restrict__ o)
{
    int i = blockIdx.x * 256 + threadIdx.x;
    float4 v = reinterpret_cast<const float4*>(x)[i];
    ushort4 u;
    u.x = f2h(v.x); u.y = f2h(v.y); u.z = f2h(v.z); u.w = f2h(v.w);
    reinterpret_cast<ushort4*>(o)[i] = u;
}

// ---------------- fp16 MFMA GEMM: C(f32) = [res +] A@B [+ bias] [relu] ----------------
// A: fp16 [.][lda] row-major; BT: fp16 [N][ldb] = B^T; C: f32 [.][ldc].
// Tile 128x128, BK=32, 4 waves (2x2), each wave 64x64 via 4x4 16x16x32 frags.
__global__ __launch_bounds__(256) void gemm_f16(
    const ushort_t* __restrict__ A, const ushort_t* __restrict__ BT,
    const float* __restrict__ bias, const float* __restrict__ res,
    float* __restrict__ C, int Mvalid, int K, int lda, int ldb, int ldc, int relu)
{
    __shared__ ushort_t As[128 * 32];
    __shared__ ushort_t Bs[128 * 32];
    const int tid = threadIdx.x;
    const int wave = tid >> 6, lane = tid & 63;
    const int row0 = blockIdx.y * 128, col0 = blockIdx.x * 128;
    const int wr = (wave >> 1) * 64, wc = (wave & 1) * 64;
    const int sRow = wave * 16 + (lane >> 2);     // row within 64-row staging group
    const int sCh = (lane & 3) * 8;               // k-chunk (8 fp16 = 16B)
    const int lr = lane & 15, lk = (lane >> 4) * 8, lq = (lane >> 4) * 4;
    f32x4 acc[4][4] = {};
    for (int k0 = 0; k0 < K; k0 += 32) {
        __syncthreads();
#pragma unroll
        for (int i = 0; i < 2; ++i) {
            const ushort_t* gp = A + (size_t)(row0 + i * 64 + sRow) * lda + k0 + sCh;
            __builtin_amdgcn_global_load_lds(GPTR(gp), LPTR(As + (i * 64 + wave * 16) * 32), 16, 0, 0);
            const ushort_t* gq = BT + (size_t)(col0 + i * 64 + sRow) * ldb + k0 + sCh;
            __builtin_amdgcn_global_load_lds(GPTR(gq), LPTR(Bs + (i * 64 + wave * 16) * 32), 16, 0, 0);
        }
        __syncthreads();
        half8 af[4], bfr[4];
#pragma unroll
        for (int mi = 0; mi < 4; ++mi)
            af[mi] = *reinterpret_cast<const half8*>(&As[(wr + mi * 16 + lr) * 32 + lk]);
#pragma unroll
        for (int ni = 0; ni < 4; ++ni)
            bfr[ni] = *reinterpret_cast<const half8*>(&Bs[(wc + ni * 16 + lr) * 32 + lk]);
#pragma unroll
        for (int mi = 0; mi < 4; ++mi)
#pragma unroll
            for (int ni = 0; ni < 4; ++ni)
                acc[mi][ni] = __builtin_amdgcn_mfma_f32_16x16x32_f16(af[mi], bfr[ni], acc[mi][ni], 0, 0, 0);
    }
#pragma unroll
    for (int mi = 0; mi < 4; ++mi) {
#pragma unroll
        for (int q = 0; q < 4; ++q) {
            int r = row0 + wr + mi * 16 + lq + q;
            if (r >= Mvalid) continue;
#pragma unroll
            for (int ni = 0; ni < 4; ++ni) {
                int c = col0 + wc + ni * 16 + lr;
                float v = acc[mi][ni][q];
                if (bias) v += bias[c];
                if (res)  v += res[(size_t)r * ldc + c];
                if (relu) v = fmaxf(v, 0.f);
                C[(size_t)r * ldc + c] = v;
            }
        }
    }
}

// ---------------- batched fp16 MFMA 256x256x256 (per head): C = diag*I + ss*(A@B) ----------------
// A, B: fp16 row-major [256][256] per head; C (and optional C2) fp16.
// Tile 128x128, grid (2,2,8). B transpose-staged through LDS with XOR swizzle.
__global__ __launch_bounds__(256) void bgemm_f16(
    const ushort_t* __restrict__ A, const ushort_t* __restrict__ B,
    ushort_t* __restrict__ C, float diag, float ss,
    ushort_t* __restrict__ C2, float diag2, float ss2)
{
    __shared__ ushort_t As[128 * 32];
    __shared__ ushort_t Bs[128 * 32];   // Bs[n][k^swz]
    const int h = blockIdx.z;
    const ushort_t* Ah = A + (size_t)h * 65536;
    const ushort_t* Bh = B + (size_t)h * 65536;
    const int tid = threadIdx.x;
    const int wave = tid >> 6, lane = tid & 63;
    const int row0 = blockIdx.y * 128, col0 = blockIdx.x * 128;
    const int wr = (wave >> 1) * 64, wc = (wave & 1) * 64;
    const int sRow = lane >> 2;                    // + wave*16 handled in dst offset
    const int sCh = (lane & 3) * 8;
    const int kp = tid >> 4;                       // 0..15 k-pair -> k = 2kp, 2kp+1
    const int nc = tid & 15;                       // 0..15 n-chunk of 8
    const int kk = (kp * 2) ^ ((nc & 3) << 3);     // swizzled k position (even)
    const int lr = lane & 15, lk = (lane >> 4) * 8, lq = (lane >> 4) * 4;
    f32x4 acc[4][4] = {};
    for (int k0 = 0; k0 < 256; k0 += 32) {
        __syncthreads();
#pragma unroll
        for (int i = 0; i < 2; ++i) {
            const ushort_t* gp = Ah + (size_t)(row0 + i * 64 + wave * 16 + sRow) * 256 + k0 + sCh;
            __builtin_amdgcn_global_load_lds(GPTR(gp), LPTR(As + (i * 64 + wave * 16) * 32), 16, 0, 0);
        }
        // B transpose-stage: rows k0+2kp, k0+2kp+1, cols col0+nc*8..+7
        const ushort_t* bp = Bh + (size_t)(k0 + kp * 2) * 256 + col0 + nc * 8;
        short8 v0 = *reinterpret_cast<const short8*>(bp);
        short8 v1 = *reinterpret_cast<const short8*>(bp + 256);
#pragma unroll
        for (int j = 0; j < 8; ++j) {
            unsigned int pk = ((unsigned int)(ushort_t)v1[j] << 16) | (unsigned int)(ushort_t)v0[j];
            *reinterpret_cast<unsigned int*>(&Bs[(nc * 8 + j) * 32 + kk]) = pk;
        }
        __syncthreads();
        half8 af[4], bfr[4];
#pragma unroll
        for (int mi = 0; mi < 4; ++mi)
            af[mi] = *reinterpret_cast<const half8*>(&As[(wr + mi * 16 + lr) * 32 + lk]);
#pragma unroll
        for (int ni = 0; ni < 4; ++ni) {
            int nn = wc + ni * 16 + lr;
            bfr[ni] = *reinterpret_cast<const half8*>(&Bs[nn * 32 + (lk ^ (((nn >> 3) & 3) << 3))]);
        }
#pragma unroll
        for (int mi = 0; mi < 4; ++mi)
#pragma unroll
            for (int ni = 0; ni < 4; ++ni)
                acc[mi][ni] = __builtin_amdgcn_mfma_f32_16x16x32_f16(af[mi], bfr[ni], acc[mi][ni], 0, 0, 0);
    }
    ushort_t* Ch = C + (size_t)h * 65536;
#pragma unroll
    for (int mi = 0; mi < 4; ++mi)
#pragma unroll
        for (int ni = 0; ni < 4; ++ni)
#pragma unroll
            for (int q = 0; q < 4; ++q) {
                int r = row0 + wr + mi * 16 + lq + q;
                int c = col0 + wc + ni * 16 + lr;
                float v = ss * acc[mi][ni][q];
                if (r == c) v += diag;
                Ch[(size_t)r * 256 + c] = f2h(v);
                if (C2) {
                    float v2 = ss2 * acc[mi][ni][q];
                    if (r == c) v2 += diag2;
                    C2[(size_t)h * 65536 + (size_t)r * 256 + c] = f2h(v2);
                }
            }
}

// ---------------- fixup: cls token + wrap rows ----------------
__global__ void fixup_k(const float* __restrict__ cls, float* __restrict__ h)
{
    int i = blockIdx.x * 256 + threadIdx.x;   // 90*512
    if (i < 512) {
        h[i] = cls[i];
    } else {
        int j = i - 512;                       // j < 89*512
        h[(size_t)8193 * 512 + j] = h[512 + j];
    }
}

// ---------------- layernorm + front zero-pad: out[NP][512] fp16 ----------------
__global__ __launch_bounds__(256) void ln_pad_k(
    const float* __restrict__ h, const float* __restrict__ g, const float* __restrict__ b,
    ushort_t* __restrict__ out)
{
    int row = blockIdx.x, tid = threadIdx.x;
    __shared__ float red[256];
    ushort_t* o = out + (size_t)row * 512;
    if (row < PAD) { o[tid] = 0; o[tid + 256] = 0; return; }
    const float* x = h + (size_t)(row - PAD) * 512;
    float v0 = x[tid], v1 = x[tid + 256];
    float mu = blockReduceSumF(v0 + v1, red, tid) * (1.f / 512.f);
    float d0 = v0 - mu, d1 = v1 - mu;
    float var = blockReduceSumF(d0 * d0 + d1 * d1, red, tid) * (1.f / 512.f);
    float rstd = rsqrtf(var + 1e-5f);
    o[tid]       = f2h(d0 * rstd * g[tid] + b[tid]);
    o[tid + 256] = f2h(d1 * rstd * g[tid + 256] + b[tid + 256]);
}

// ---------------- landmark means (q scaled) ----------------
__global__ void landmark_k(const float* __restrict__ qkv, float* __restrict__ ql, float* __restrict__ kl)
{
    int h = blockIdx.x >> 8, m = blockIdx.x & 255, d = threadIdx.x;  // 64 threads
    const float* base = qkv + (size_t)(m * LCH) * 1536 + h * 64 + d;
    float sq = 0.f, sk = 0.f;
    for (int i = 0; i < LCH; ++i) {
        sq += base[(size_t)i * 1536];
        sk += base[(size_t)i * 1536 + 512];
    }
    ql[((size_t)h * 256 + m) * 64 + d] = sq * (SCALE / (float)LCH);
    kl[((size_t)h * 256 + m) * 64 + d] = sk * (1.f / (float)LCH);
}

// ---------------- a2 = softmax(ql @ kl^T), fp16 out ----------------
__global__ __launch_bounds__(256) void a2_k(
    const float* __restrict__ ql, const float* __restrict__ kl, ushort_t* __restrict__ a2)
{
    int h = blockIdx.x >> 8, r = blockIdx.x & 255, tid = threadIdx.x;
    __shared__ float qv[64]; __shared__ float red[256];
    if (tid < 64) qv[tid] = ql[((size_t)h * 256 + r) * 64 + tid];
    __syncthreads();
    const float* kp = kl + ((size_t)h * 256 + tid) * 64;
    float dot = 0.f;
#pragma unroll
    for (int d = 0; d < 64; ++d) dot += qv[d] * kp[d];
    float mx = blockReduceMaxF(dot, red, tid);
    float e = expf(dot - mx);
    float s = blockReduceSumF(e, red, tid);
    a2[((size_t)h * 256 + r) * 256 + tid] = f2h(e / s);
}

// ---------------- pinv init helpers (fp16 a2) ----------------
__global__ __launch_bounds__(256) void rowsum_k(const ushort_t* __restrict__ a2, float* __restrict__ rs)
{
    int r = blockIdx.x; __shared__ float red[256];
    float v = fabsf(h2f(a2[(size_t)r * 256 + threadIdx.x]));
    float s = blockReduceSumF(v, red, threadIdx.x);
    if (!threadIdx.x) rs[r] = s;
}
__global__ __launch_bounds__(256) void colsum_k(const ushort_t* __restrict__ a2, float* __restrict__ cs)
{
    int h = blockIdx.x >> 8, c = blockIdx.x & 255;
    __shared__ float red[256];
    float v = fabsf(h2f(a2[(size_t)h * 65536 + (size_t)threadIdx.x * 256 + c]));
    float s = blockReduceSumF(v, red, threadIdx.x);
    if (!threadIdx.x) cs[blockIdx.x] = s;
}
__global__ __launch_bounds__(256) void pinv_scal_k(const float* __restrict__ rs, const float* __restrict__ cs,
                                                   float* __restrict__ scal)
{
    int tid = threadIdx.x; __shared__ float red[256];
    float m1 = -1e30f, m2 = -1e30f;
    for (int i = tid; i < 2048; i += 256) { m1 = fmaxf(m1, rs[i]); m2 = fmaxf(m2, cs[i]); }
    m1 = blockReduceMaxF(m1, red, tid);
    m2 = blockReduceMaxF(m2, red, tid);
    if (!tid) scal[0] = 1.f / (m1 * m2);
}
__global__ __launch_bounds__(256) void zinit_k(const ushort_t* __restrict__ a2, const float* __restrict__ scal,
                                               ushort_t* __restrict__ z)
{
    int h = blockIdx.x >> 8, r = blockIdx.x & 255, c = threadIdx.x;
    z[(size_t)h * 65536 + (size_t)r * 256 + c] =
        f2h(h2f(a2[(size_t)h * 65536 + (size_t)c * 256 + r]) * scal[0]);
}

// ---------------- S3 = ql @ K^T  (per head, 256 x NP) ----------------
__global__ __launch_bounds__(256) void s3_k(const float* __restrict__ ql, const float* __restrict__ qkv,
                                            float* __restrict__ S)
{
    __shared__ float As[16][68];
    __shared__ float Bs[16][68];
    int h = blockIdx.z;
    int col0 = blockIdx.x * 64, row0 = blockIdx.y * 64;
    int tid = threadIdx.x;
    int r4 = tid >> 2, k4 = (tid & 3) * 4;
    int tx = tid & 15, ty = tid >> 4;
    const float* qlh = ql + (size_t)h * 256 * 64;
    float acc[4][4] = {};
    for (int kb = 0; kb < 64; kb += 16) {
        float4 a4 = *reinterpret_cast<const float4*>(qlh + (size_t)(row0 + r4) * 64 + kb + k4);
        As[k4 + 0][r4] = a4.x; As[k4 + 1][r4] = a4.y; As[k4 + 2][r4] = a4.z; As[k4 + 3][r4] = a4.w;
        float4 b4 = *reinterpret_cast<const float4*>(qkv + (size_t)(col0 + r4) * 1536 + 512 + h * 64 + kb + k4);
        Bs[k4 + 0][r4] = b4.x; Bs[k4 + 1][r4] = b4.y; Bs[k4 + 2][r4] = b4.z; Bs[k4 + 3][r4] = b4.w;
        __syncthreads();
#pragma unroll
        for (int k = 0; k < 16; ++k) {
            float a[4], b[4];
#pragma unroll
            for (int i = 0; i < 4; ++i) a[i] = As[k][ty * 4 + i];
#pragma unroll
            for (int j = 0; j < 4; ++j) b[j] = Bs[k][tx * 4 + j];
#pragma unroll
            for (int i = 0; i < 4; ++i)
#pragma unroll
                for (int j = 0; j < 4; ++j) acc[i][j] += a[i] * b[j];
        }
        __syncthreads();
    }
#pragma unroll
    for (int i = 0; i < 4; ++i)
#pragma unroll
        for (int j = 0; j < 4; ++j)
            S[((size_t)h * 256 + row0 + ty * 4 + i) * (size_t)NP + col0 + tx * 4 + j] = acc[i][j];
}

// ---------------- row max/sum over S3 rows (len NP) ----------------
__global__ __launch_bounds__(256) void rowstat3_k(const float* __restrict__ S,
                                                  float* __restrict__ rmax, float* __restrict__ rsum)
{
    __shared__ float red[256];
    int row = blockIdx.x, tid = threadIdx.x;
    const float* p = S + (size_t)row * NP;
    float mx = -1e30f;
    for (int i = tid; i < NP; i += 256) mx = fmaxf(mx, p[i]);
    mx = blockReduceMaxF(mx, red, tid);
    float s = 0.f;
    for (int i = tid; i < NP; i += 256) s += __expf(p[i] - mx);
    s = blockReduceSumF(s, red, tid);
    if (!tid) { rmax[row] = mx; rsum[row] = s; }
}

// ---------------- av partials: split-K GEMM with fused exp ----------------
__global__ __launch_bounds__(256) void pv_split_k(const float* __restrict__ S,
                                                  const float* __restrict__ rmax,
                                                  const float* __restrict__ qkv,
                                                  float* __restrict__ part)
{
    __shared__ float As[32][34];
    __shared__ float Bs[16][68];
    int ks = blockIdx.x, r0 = blockIdx.y * 32, h = blockIdx.z;
    int tid = threadIdx.x;
    int ar = tid >> 3, ak = (tid & 7) * 2;
    int bk = tid >> 4, bn4 = (tid & 15) * 4;
    int tx = tid & 15, ty = tid >> 4;
    size_t rowbase = (size_t)h * 256 + r0;
    float rmA = rmax[rowbase + ar];
    float acc[2][4] = {};
    int k0 = ks * KCH;
    for (int kb = k0; kb < k0 + KCH; kb += 16) {
        float2 a2v = *reinterpret_cast<const float2*>(S + (rowbase + ar) * (size_t)NP + kb + ak);
        As[ar][ak]     = __expf(a2v.x - rmA);
        As[ar][ak + 1] = __expf(a2v.y - rmA);
        float4 b4 = *reinterpret_cast<const float4*>(qkv + (size_t)(kb + bk) * 1536 + 1024 + h * 64 + bn4);
        *reinterpret_cast<float4*>(&Bs[bk][bn4]) = b4;
        __syncthreads();
#pragma unroll
        for (int k = 0; k < 16; ++k) {
            float a0 = As[ty * 2][k], a1 = As[ty * 2 + 1][k];
            float b[4];
#pragma unroll
            for (int j = 0; j < 4; ++j) b[j] = Bs[k][tx * 4 + j];
#pragma unroll
            for (int j = 0; j < 4; ++j) { acc[0][j] += a0 * b[j]; acc[1][j] += a1 * b[j]; }
        }
        __syncthreads();
    }
    float* pp = part + ((size_t)(ks * 8 + h) * 256 + r0) * 64;
#pragma unroll
    for (int i = 0; i < 2; ++i)
#pragma unroll
        for (int j = 0; j < 4; ++j)
            pp[(ty * 2 + i) * 64 + tx * 4 + j] = acc[i][j];
}

__global__ __launch_bounds__(256) void pv_reduce_k(const float* __restrict__ part,
                                                   const float* __restrict__ rsum,
                                                   float* __restrict__ av)
{
    int idx = blockIdx.x * 256 + threadIdx.x;   // 131072
    int rc = idx >> 6;                           // h*256+r
    float s = 0.f;
#pragma unroll
    for (int ks = 0; ks < KSPLIT; ++ks)
        s += part[(size_t)ks * 131072 + idx];
    av[idx] = s / rsum[rc];
}

// ---------------- W = z @ av (per head 256x256 @ 256x64), z fp16 ----------------
__global__ void wmat_k(const ushort_t* __restrict__ z, const float* __restrict__ av, float* __restrict__ W)
{
    int h = blockIdx.x >> 8, m = blockIdx.x & 255, d = threadIdx.x;  // 64 threads
    const ushort_t* zp = z + (size_t)h * 65536 + (size_t)m * 256;
    const float* ap = av + (size_t)h * 16384 + d;
    float acc = 0.f;
    for (int j = 0; j < 256; ++j) acc += h2f(zp[j]) * ap[(size_t)j * 64];
    W[((size_t)h * 256 + m) * 64 + d] = acc;
}

// ---------------- S1 = (q*SCALE) @ kl^T  (per head, NP x 256) ----------------
__global__ __launch_bounds__(256) void s1_k(const float* __restrict__ qkv, const float* __restrict__ kl,
                                            float* __restrict__ S)
{
    __shared__ float As[16][68];
    __shared__ float Bs[16][68];
    int h = blockIdx.z;
    int col0 = blockIdx.x * 64, row0 = blockIdx.y * 64;
    int tid = threadIdx.x;
    int r4 = tid >> 2, k4 = (tid & 3) * 4;
    int tx = tid & 15, ty = tid >> 4;
    float acc[4][4] = {};
    for (int kb = 0; kb < 64; kb += 16) {
        float4 a4 = *reinterpret_cast<const float4*>(qkv + (size_t)(row0 + r4) * 1536 + h * 64 + kb + k4);
        As[k4 + 0][r4] = a4.x * SCALE; As[k4 + 1][r4] = a4.y * SCALE;
        As[k4 + 2][r4] = a4.z * SCALE; As[k4 + 3][r4] = a4.w * SCALE;
        float4 b4 = *reinterpret_cast<const float4*>(kl + ((size_t)h * 256 + col0 + r4) * 64 + kb + k4);
        Bs[k4 + 0][r4] = b4.x; Bs[k4 + 1][r4] = b4.y; Bs[k4 + 2][r4] = b4.z; Bs[k4 + 3][r4] = b4.w;
        __syncthreads();
#pragma unroll
        for (int k = 0; k < 16; ++k) {
            float a[4], b[4];
#pragma unroll
            for (int i = 0; i < 4; ++i) a[i] = As[k][ty * 4 + i];
#pragma unroll
            for (int j = 0; j < 4; ++j) b[j] = Bs[k][tx * 4 + j];
#pragma unroll
            for (int i = 0; i < 4; ++i)
#pragma unroll
                for (int j = 0; j < 4; ++j) acc[i][j] += a[i] * b[j];
        }
        __syncthreads();
    }
#pragma unroll
    for (int i = 0; i < 4; ++i)
#pragma unroll
        for (int j = 0; j < 4; ++j)
            S[((size_t)h * NP + row0 + ty * 4 + i) * 256 + col0 + tx * 4 + j] = acc[i][j];
}

// ---------------- row max/sum over S1 rows (len 256), wave per row ----------------
__global__ __launch_bounds__(256) void rowstat1_k(const float* __restrict__ S,
                                                  float* __restrict__ rmax, float* __restrict__ rsum)
{
    int wave = threadIdx.x >> 6, lane = threadIdx.x & 63;
    size_t row = (size_t)blockIdx.x * 4 + wave;
    const float* p = S + row * 256;
    float v0 = p[lane], v1 = p[lane + 64], v2 = p[lane + 128], v3 = p[lane + 192];
    float mx = fmaxf(fmaxf(v0, v1), fmaxf(v2, v3));
    for (int off = 32; off; off >>= 1) mx = fmaxf(mx, __shfl_xor(mx, off, 64));
    float s = __expf(v0 - mx) + __expf(v1 - mx) + __expf(v2 - mx) + __expf(v3 - mx);
    for (int off = 32; off; off >>= 1) s += __shfl_xor(s, off, 64);
    if (!lane) { rmax[row] = mx; rsum[row] = s; }
}

// ---------------- attn = softmax(S1) @ W (exp fused, token-major fp16 out) ----------------
__global__ __launch_bounds__(256) void pw_k(const float* __restrict__ S,
                                            const float* __restrict__ rmax, const float* __restrict__ rsum,
                                            const float* __restrict__ W, ushort_t* __restrict__ attn)
{
    __shared__ float As[16][68];
    __shared__ float Bs[16][68];
    int h = blockIdx.z;
    int row0 = blockIdx.y * 64;
    int tid = threadIdx.x;
    int r4 = tid >> 2, k4 = (tid & 3) * 4;
    int bk = tid >> 4, bn4 = (tid & 15) * 4;
    int tx = tid & 15, ty = tid >> 4;
    size_t rowbase = (size_t)h * NP + row0;
    float rm = rmax[rowbase + r4];
    float acc[4][4] = {};
    for (int kb = 0; kb < 256; kb += 16) {
        float4 a4 = *reinterpret_cast<const float4*>(S + (rowbase + r4) * 256 + kb + k4);
        As[k4 + 0][r4] = __expf(a4.x - rm); As[k4 + 1][r4] = __expf(a4.y - rm);
        As[k4 + 2][r4] = __expf(a4.z - rm); As[k4 + 3][r4] = __expf(a4.w - rm);
        float4 b4 = *reinterpret_cast<const float4*>(W + ((size_t)h * 256 + kb + bk) * 64 + bn4);
        *reinterpret_cast<float4*>(&Bs[bk][bn4]) = b4;
        __syncthreads();
#pragma unroll
        for (int k = 0; k < 16; ++k) {
            float a[4], b[4];
#pragma unroll
            for (int i = 0; i < 4; ++i) a[i] = As[k][ty * 4 + i];
#pragma unroll
            for (int j = 0; j < 4; ++j) b[j] = Bs[k][tx * 4 + j];
#pragma unroll
            for (int i = 0; i < 4; ++i)
#pragma unroll
                for (int j = 0; j < 4; ++j) acc[i][j] += a[i] * b[j];
        }
        __syncthreads();
    }
#pragma unroll
    for (int i = 0; i < 4; ++i) {
        int t = row0 + ty * 4 + i;
        float inv = 1.f / rsum[(size_t)h * NP + t];
#pragma unroll
        for (int j = 0; j < 4; ++j)
            attn[(size_t)t * 512 + h * 64 + tx * 4 + j] = f2h(acc[i][j] * inv);
    }
}

// ---------------- tiled depthwise 33-tap conv over tokens on v, added to fp16 attn ----------------
#define CTT 64
__global__ __launch_bounds__(256) void conv2_k(const float* __restrict__ qkv,
                                               const float* __restrict__ cw,
                                               ushort_t* __restrict__ attn)
{
    __shared__ float vt[CTT + 32][64];
    int t0 = blockIdx.x * CTT;
    int h = blockIdx.y;
    int tid = threadIdx.x;
    for (int s = tid; s < (CTT + 32) * 16; s += 256) {
        int row = s >> 4, q = s & 15;
        int tt = t0 - 16 + row;
        float4 v = make_float4(0.f, 0.f, 0.f, 0.f);
        if (tt >= 0 && tt < NP)
            v = *reinterpret_cast<const float4*>(qkv + (size_t)tt * 1536 + 1024 + h * 64 + q * 4);
        *reinterpret_cast<float4*>(&vt[row][q * 4]) = v;
    }
    float w33[33];
#pragma unroll
    for (int j = 0; j < 33; ++j) w33[j] = cw[h * 33 + j];
    __syncthreads();
    int c = tid & 63, tr = tid >> 6;   // tr uniform per wave
    float win[48];
#pragma unroll
    for (int j = 0; j < 48; ++j) win[j] = vt[tr * 16 + j][c];
#pragma unroll
    for (int i = 0; i < 16; ++i) {
        float acc = 0.f;
#pragma unroll
        for (int j = 0; j < 33; ++j) acc += w33[j] * win[i + j];
        size_t idx = (size_t)(t0 + tr * 16 + i) * 512 + h * 64 + c;
        attn[idx] = f2h(h2f(attn[idx]) + acc);
    }
}

// ---------------- PPEG tiled: 16x16 token tile x 16 channels, combined 49-tap ----------------
#define PTS  16          // out tile side
#define PIT  22          // in tile side (halo 3)
#define PITT (PIT*PIT)   // 484
#define PCG  16          // channels per block
__global__ __launch_bounds__(256) void ppeg_tiled_k(
    const float* __restrict__ hin,
    const float* __restrict__ w7, const float* __restrict__ b7,
    const float* __restrict__ w5, const float* __restrict__ b5,
    const float* __restrict__ w3, const float* __restrict__ b3,
    float* __restrict__ hout)
{
    __shared__ float inb[PCG][PITT + 1];
    __shared__ float wc[PCG][49];
    __shared__ float bs[PCG];
    int tid = threadIdx.x;
    int c0 = blockIdx.z * PCG;
    int ty0 = blockIdx.y * PTS, tx0 = blockIdx.x * PTS;
    if (blockIdx.x == 0 && blockIdx.y == 0 && tid < PCG)
        hout[c0 + tid] = hin[c0 + tid];
    for (int idx = tid; idx < PITT * (PCG / 4); idx += 256) {
        int tok = idx >> 2, q = idx & 3;
        int gy = ty0 - 3 + tok / PIT, gx = tx0 - 3 + tok % PIT;
        float4 v = make_float4(0.f, 0.f, 0.f, 0.f);
        if (gy >= 0 && gy < HS && gx >= 0 && gx < HS)
            v = *reinterpret_cast<const float4*>(hin + (size_t)(1 + gy * HS + gx) * 512 + c0 + q * 4);
        inb[q * 4 + 0][tok] = v.x; inb[q * 4 + 1][tok] = v.y;
        inb[q * 4 + 2][tok] = v.z; inb[q * 4 + 3][tok] = v.w;
    }
    for (int idx = tid; idx < PCG * 49; idx += 256) {
        int c = idx / 49, t = idx % 49;
        int ky = t / 7, kx = t % 7, dy = ky - 3, dx = kx - 3;
        float w = w7[(size_t)(c0 + c) * 49 + t];
        if (dy >= -2 && dy <= 2 && dx >= -2 && dx <= 2)
            w += w5[(size_t)(c0 + c) * 25 + (dy + 2) * 5 + (dx + 2)];
        if (dy >= -1 && dy <= 1 && dx >= -1 && dx <= 1)
            w += w3[(size_t)(c0 + c) * 9 + (dy + 1) * 3 + (dx + 1)];
        wc[c][t] = w;
    }
    if (tid < PCG) bs[tid] = b7[c0 + tid] + b5[c0 + tid] + b3[c0 + tid];
    __syncthreads();
    int oy = tid >> 4, ox = tid & 15;
    int gy = ty0 + oy, gx = tx0 + ox;
    if (gy >= HS || gx >= HS) return;
    float* out = hout + (size_t)(1 + gy * HS + gx) * 512 + c0;
#pragma unroll 4
    for (int c = 0; c < PCG; ++c) {
        float acc = inb[c][(oy + 3) * PIT + ox + 3] + bs[c];
#pragma unroll
        for (int ky = 0; ky < 7; ++ky)
#pragma unroll
            for (int kx = 0; kx < 7; ++kx)
                acc += wc[c][ky * 7 + kx] * inb[c][(oy + ky) * PIT + ox + kx];
        out[c] = acc;
    }
}

// ---------------- final LN(row0) + fc2 + softmax + argmax ----------------
__global__ __launch_bounds__(256) void final_k(const float* __restrict__ h,
                                               const float* __restrict__ g, const float* __restrict__ bb,
                                               const float* __restrict__ w, const float* __restrict__ fb,
                                               float* __restrict__ out)
{
    __shared__ float red[256];
    int tid = threadIdx.x;
    float v0 = h[tid], v1 = h[tid + 256];
    float mu = blockReduceSumF(v0 + v1, red, tid) * (1.f / 512.f);
    float d0 = v0 - mu, d1 = v1 - mu;
    float var = blockReduceSumF(d0 * d0 + d1 * d1, red, tid) * (1.f / 512.f);
    float rstd = rsqrtf(var + 1e-5f);
    float e0 = d0 * rstd * g[tid] + bb[tid];
    float e1 = d1 * rstd * g[tid + 256] + bb[tid + 256];
    out[5 + tid] = e0;
    out[5 + 256 + tid] = e1;
    float l0p = e0 * w[tid * 2] + e1 * w[(tid + 256) * 2];
    float l1p = e0 * w[tid * 2 + 1] + e1 * w[(tid + 256) * 2 + 1];
    float l0 = blockReduceSumF(l0p, red, tid);
    float l1 = blockReduceSumF(l1p, red, tid);
    if (!tid) {
        l0 += fb[0]; l1 += fb[1];
        out[0] = l0; out[1] = l1;
        float mx = fmaxf(l0, l1);
        float p0 = expf(l0 - mx), p1 = expf(l1 - mx);
        float si = 1.f / (p0 + p1);
        out[2] = p0 * si; out[3] = p1 * si;
        out[4] = (l1 > l0) ? 1.f : 0.f;
    }
}

// ---------------- host orchestration ----------------
struct WsPtrs {
    float *h, *h2, *qkv, *ql, *kl, *av, *W, *rs, *cs, *scal;
    float *S, *rmax3, *rsum3, *rmax1, *rsum1, *part;
    ushort_t *xbB, *qkvT, *outT, *x16, *fc1T;
    ushort_t *a2h, *zh, *z2h, *xzh, *t1h, *t2h;
};

static void run_attn(float* hbuf, const float* ln_g, const float* ln_b,
                     const float* qkv_w, const float* out_w, const float* out_b,
                     const float* conv_w, const WsPtrs& P, hipStream_t s)
{
    // weight prep (fp16 transposed)
    tcast_k<<<dim3(1536 / 32, 512 / 32), 256, 0, s>>>(qkv_w, P.qkvT, 512, 1536);
    tcast_k<<<dim3(512 / 32, 512 / 32), 256, 0, s>>>(out_w, P.outT, 512, 512);
    // layernorm + pad (fp16)
    ln_pad_k<<<NP, 256, 0, s>>>(hbuf, ln_g, ln_b, P.xbB);
    // qkv = xb @ qkv_w  (MFMA, f32 out)
    gemm_f16<<<dim3(1536 / 128, NP / 128), 256, 0, s>>>(P.xbB, P.qkvT, nullptr, nullptr,
                                                        P.qkv, NP, 512, 512, 512, 1536, 0);
    landmark_k<<<2048, 64, 0, s>>>(P.qkv, P.ql, P.kl);
    a2_k<<<2048, 256, 0, s>>>(P.ql, P.kl, P.a2h);
    rowsum_k<<<2048, 256, 0, s>>>(P.a2h, P.rs);
    colsum_k<<<2048, 256, 0, s>>>(P.a2h, P.cs);
    pinv_scal_k<<<1, 256, 0, s>>>(P.rs, P.cs, P.scal);
    zinit_k<<<2048, 256, 0, s>>>(P.a2h, P.scal, P.zh);
    ushort_t* za = P.zh; ushort_t* zb = P.z2h;
    for (int it = 0; it < 6; ++it) {
        // xz = a2@z ; t1 = 7I - xz  (fused dual output, fp16 MFMA)
        bgemm_f16<<<dim3(2, 2, 8), 256, 0, s>>>(P.a2h, za, P.xzh, 0.f, 1.f, P.t1h, 7.f, -1.f);
        bgemm_f16<<<dim3(2, 2, 8), 256, 0, s>>>(P.xzh, P.t1h, P.t2h, 15.f, -1.f, nullptr, 0.f, 0.f);
        bgemm_f16<<<dim3(2, 2, 8), 256, 0, s>>>(P.xzh, P.t2h, P.t1h, 13.f, -1.f, nullptr, 0.f, 0.f);
        bgemm_f16<<<dim3(2, 2, 8), 256, 0, s>>>(za, P.t1h, zb, 0.f, 0.25f, nullptr, 0.f, 0.f);
        ushort_t* tmp = za; za = zb; zb = tmp;
    }
    // av path
    s3_k<<<dim3(NP / 64, 4, 8), 256, 0, s>>>(P.ql, P.qkv, P.S);
    rowstat3_k<<<2048, 256, 0, s>>>(P.S, P.rmax3, P.rsum3);
    pv_split_k<<<dim3(KSPLIT, 8, 8), 256, 0, s>>>(P.S, P.rmax3, P.qkv, P.part);
    pv_reduce_k<<<512, 256, 0, s>>>(P.part, P.rsum3, P.av);
    wmat_k<<<2048, 64, 0, s>>>(za, P.av, P.W);
    // a1 path (attn -> xbB fp16, token-major)
    s1_k<<<dim3(4, NP / 64, 8), 256, 0, s>>>(P.qkv, P.kl, P.S);
    rowstat1_k<<<(NP * 8) / 4, 256, 0, s>>>(P.S, P.rmax1, P.rsum1);
    pw_k<<<dim3(1, NP / 64, 8), 256, 0, s>>>(P.S, P.rmax1, P.rsum1, P.W, P.xbB);
    conv2_k<<<dim3(NP / CTT, 8), 256, 0, s>>>(P.qkv, conv_w, P.xbB);
    // h += attn[-N1:] @ out_w + out_b  (MFMA, f32 residual epilogue)
    gemm_f16<<<dim3(512 / 128, (N1 + 127) / 128), 256, 0, s>>>(P.xbB + (size_t)PAD * 512, P.outT,
                                                               out_b, hbuf, hbuf, N1, 512, 512, 512, 512, 0);
}

extern "C" void kernel_launch(void* const* d_in, const int* in_sizes, int n_in,
                              void* d_out, int out_size, void* d_ws, size_t ws_size,
                              hipStream_t stream)
{
    (void)in_sizes; (void)n_in; (void)out_size; (void)ws_size;
    const float* x       = (const float*)d_in[0];
    const float* fc1_w   = (const float*)d_in[1];
    const float* fc1_b   = (const float*)d_in[2];
    const float* cls_tok = (const float*)d_in[3];
    const float* ln1_g   = (const float*)d_in[4];
    const float* ln1_b   = (const float*)d_in[5];
    const float* qkv1_w  = (const float*)d_in[6];
    const float* out1_w  = (const float*)d_in[7];
    const float* out1_b  = (const float*)d_in[8];
    const float* conv1_w = (const float*)d_in[9];
    const float* ln2_g   = (const float*)d_in[10];
    const float* ln2_b   = (const float*)d_in[11];
    const float* qkv2_w  = (const float*)d_in[12];
    const float* out2_w  = (const float*)d_in[13];
    const float* out2_b  = (const float*)d_in[14];
    const float* conv2_w = (const float*)d_in[15];
    const float* pg7_w   = (const float*)d_in[16];
    const float* pg7_b   = (const float*)d_in[17];
    const float* pg5_w   = (const float*)d_in[18];
    const float* pg5_b   = (const float*)d_in[19];
    const float* pg3_w   = (const float*)d_in[20];
    const float* pg3_b   = (const float*)d_in[21];
    const float* norm_g  = (const float*)d_in[22];
    const float* norm_b  = (const float*)d_in[23];
    const float* fc2_w   = (const float*)d_in[24];
    const float* fc2_b   = (const float*)d_in[25];

    float* ws = (float*)d_ws;
    WsPtrs P;
    float* cur = ws;
    P.h     = cur; cur += (size_t)N1 * 512;
    P.h2    = cur; cur += (size_t)N1 * 512;
    P.xbB   = (ushort_t*)cur; cur += (size_t)NP * 512 / 2;
    P.qkv   = cur; cur += (size_t)NP * 1536;
    P.ql    = cur; cur += 131072;
    P.kl    = cur; cur += 131072;
    // pinv chain fp16 buffers: 8 heads x 256x256 halfs = 524288 ushorts = 262144 f32-slots each
    P.a2h   = (ushort_t*)cur; cur += 262144;
    P.zh    = (ushort_t*)cur; cur += 262144;
    P.z2h   = (ushort_t*)cur; cur += 262144;
    P.xzh   = (ushort_t*)cur; cur += 262144;
    P.t1h   = (ushort_t*)cur; cur += 262144;
    P.t2h   = (ushort_t*)cur; cur += 262144;
    P.av    = cur; cur += 131072;
    P.W     = cur; cur += 131072;
    P.rs    = cur; cur += 2048;
    P.cs    = cur; cur += 2048;
    P.scal  = cur; cur += 64;
    // qkvT: 1536 x 512 halfs = 786432 ushorts = 393216 f32-slots
    P.qkvT  = (ushort_t*)cur; cur += 393216 + 64;
    P.outT  = (ushort_t*)cur; cur += 131072 + 64;   // 512x512 halfs
    P.rmax3 = cur; cur += 2048;
    P.rsum3 = cur; cur += 2048;
    P.rmax1 = cur; cur += (size_t)8 * NP;
    P.rsum1 = cur; cur += (size_t)8 * NP;
    P.part  = cur; cur += (size_t)KSPLIT * 131072;
    P.S     = cur; cur += (size_t)8 * 256 * NP;
    // x16 / fc1T alias S (only used before block 1's S-path)
    P.x16   = (ushort_t*)P.S;                                   // 8192x1024 halfs
    P.fc1T  = (ushort_t*)(P.S + (size_t)NTOK * INDIM / 2);      // 512x1024 halfs

    // prep: x -> fp16, fc1_w -> fp16 transposed
    bcast_k<<<(NTOK * INDIM) / 1024, 256, 0, stream>>>(x, P.x16);
    tcast_k<<<dim3(512 / 32, 1024 / 32), 256, 0, stream>>>(fc1_w, P.fc1T, 1024, 512);
    // fc1 + relu -> h rows 1..8192 (MFMA)
    gemm_f16<<<dim3(512 / 128, NTOK / 128), 256, 0, stream>>>(P.x16, P.fc1T, fc1_b, nullptr,
                                                              P.h + 512, NTOK, 1024, 1024, 1024, 512, 1);
    fixup_k<<<180, 256, 0, stream>>>(cls_tok, P.h);
    run_attn(P.h, ln1_g, ln1_b, qkv1_w, out1_w, out1_b, conv1_w, P, stream);
    ppeg_tiled_k<<<dim3(6, 6, 512 / PCG), 256, 0, stream>>>(P.h, pg7_w, pg7_b, pg5_w, pg5_b,
                                                            pg3_w, pg3_b, P.h2);
    run_attn(P.h2, ln2_g, ln2_b, qkv2_w, out2_w, out2_b, conv2_w, P, stream);
    final_k<<<1, 256, 0, stream>>>(P.h2, norm_g, norm_b, fc2_w, fc2_b, (float*)d_out);
}

// Round 9
// 1121.072 us; speedup vs baseline: 5.0258x; 1.2077x over previous
//
#include <hip/hip_runtime.h>
#include <math.h>

// ---------------- constants ----------------
#define NTOK   8192
#define INDIM  1024
#define NHEAD  8
#define N1     8282      // tokens incl cls (91*91 + 1)
#define NP     8448      // padded token count inside attention
#define PAD    166
#define LCH    33        // tokens per landmark chunk
#define SCALE  0.125f
#define HS     91
#define KSPLIT 8
#define KCH    (NP / KSPLIT)   // 1056

typedef __attribute__((ext_vector_type(8))) _Float16 half8;
typedef __attribute__((ext_vector_type(8))) short short8;
typedef __attribute__((ext_vector_type(4))) float f32x4;
typedef unsigned short ushort_t;

#define GPTR(p) ((const __attribute__((address_space(1))) void*)(p))
#define LPTR(p) ((__attribute__((address_space(3))) void*)(p))

__device__ __forceinline__ ushort_t f2h(float f) {
    union { _Float16 h; ushort_t u; } v; v.h = (_Float16)f;
    return v.u;
}
__device__ __forceinline__ float h2f(ushort_t u) {
    union { ushort_t u; _Float16 h; } v; v.u = u;
    return (float)v.h;
}

// ---------------- reduce helpers (256-thread blocks) ----------------
__device__ __forceinline__ float blockReduceSumF(float v, float* red, int tid) {
    red[tid] = v; __syncthreads();
    for (int s = 128; s > 0; s >>= 1) {
        if (tid < s) red[tid] += red[tid + s];
        __syncthreads();
    }
    float r = red[0]; __syncthreads();
    return r;
}
__device__ __forceinline__ float blockReduceMaxF(float v, float* red, int tid) {
    red[tid] = v; __syncthreads();
    for (int s = 128; s > 0; s >>= 1) {
        if (tid < s) red[tid] = fmaxf(red[tid], red[tid + s]);
        __syncthreads();
    }
    float r = red[0]; __syncthreads();
    return r;
}

// ---------------- weight transpose+cast: wT[n][k] = fp16(w[k][n]) ----------------
__global__ __launch_bounds__(256) void tcast_k(const float* __restrict__ w, ushort_t* __restrict__ wT,
                                               int K, int N)
{
    __shared__ float tb[32][33];
    int tx = threadIdx.x & 31, ty = threadIdx.x >> 5;
    int n0 = blockIdx.x * 32, k0 = blockIdx.y * 32;
#pragma unroll
    for (int i = 0; i < 4; ++i)
        tb[ty + i * 8][tx] = w[(size_t)(k0 + ty + i * 8) * N + n0 + tx];
    __syncthreads();
#pragma unroll
    for (int i = 0; i < 4; ++i)
        wT[(size_t)(n0 + ty + i * 8) * K + k0 + tx] = f2h(tb[tx][ty + i * 8]);
}

// ---------------- cast f32 -> fp16 (4 els/thread) ----------------
__global__ void bcast_k(const float* __restrict__ x, ushort_t* __restrict__ o)
{
    int i = blockIdx.x * 256 + threadIdx.x;
    float4 v = reinterpret_cast<const float4*>(x)[i];
    ushort4 u;
    u.x = f2h(v.x); u.y = f2h(v.y); u.z = f2h(v.z); u.w = f2h(v.w);
    reinterpret_cast<ushort4*>(o)[i] = u;
}

// ---------------- fp16 MFMA GEMM: out = [res +] A@B [+ bias] [relu] ----------------
// A: fp16 [.][lda]; BT: fp16 [N][ldb] = B^T. Output f32 C (if Ch==null) or fp16 Ch.
// qscale: multiply cols < 512 by SCALE (for fused q-scaling in the qkv projection).
__global__ __launch_bounds__(256) void gemm_f16(
    const ushort_t* __restrict__ A, const ushort_t* __restrict__ BT,
    const float* __restrict__ bias, const float* __restrict__ res,
    float* __restrict__ C, ushort_t* __restrict__ Ch,
    int Mvalid, int K, int lda, int ldb, int ldc, int relu, int qscale)
{
    __shared__ ushort_t As[128 * 32];
    __shared__ ushort_t Bs[128 * 32];
    const int tid = threadIdx.x;
    const int wave = tid >> 6, lane = tid & 63;
    const int row0 = blockIdx.y * 128, col0 = blockIdx.x * 128;
    const int wr = (wave >> 1) * 64, wc = (wave & 1) * 64;
    const int sRow = wave * 16 + (lane >> 2);
    const int sCh = (lane & 3) * 8;
    const int lr = lane & 15, lk = (lane >> 4) * 8, lq = (lane >> 4) * 4;
    f32x4 acc[4][4] = {};
    for (int k0 = 0; k0 < K; k0 += 32) {
        __syncthreads();
#pragma unroll
        for (int i = 0; i < 2; ++i) {
            const ushort_t* gp = A + (size_t)(row0 + i * 64 + sRow) * lda + k0 + sCh;
            __builtin_amdgcn_global_load_lds(GPTR(gp), LPTR(As + (i * 64 + wave * 16) * 32), 16, 0, 0);
            const ushort_t* gq = BT + (size_t)(col0 + i * 64 + sRow) * ldb + k0 + sCh;
            __builtin_amdgcn_global_load_lds(GPTR(gq), LPTR(Bs + (i * 64 + wave * 16) * 32), 16, 0, 0);
        }
        __syncthreads();
        half8 af[4], bfr[4];
#pragma unroll
        for (int mi = 0; mi < 4; ++mi)
            af[mi] = *reinterpret_cast<const half8*>(&As[(wr + mi * 16 + lr) * 32 + lk]);
#pragma unroll
        for (int ni = 0; ni < 4; ++ni)
            bfr[ni] = *reinterpret_cast<const half8*>(&Bs[(wc + ni * 16 + lr) * 32 + lk]);
#pragma unroll
        for (int mi = 0; mi < 4; ++mi)
#pragma unroll
            for (int ni = 0; ni < 4; ++ni)
                acc[mi][ni] = __builtin_amdgcn_mfma_f32_16x16x32_f16(af[mi], bfr[ni], acc[mi][ni], 0, 0, 0);
    }
#pragma unroll
    for (int mi = 0; mi < 4; ++mi) {
#pragma unroll
        for (int q = 0; q < 4; ++q) {
            int r = row0 + wr + mi * 16 + lq + q;
            if (r >= Mvalid) continue;
#pragma unroll
            for (int ni = 0; ni < 4; ++ni) {
                int c = col0 + wc + ni * 16 + lr;
                float v = acc[mi][ni][q];
                if (bias) v += bias[c];
                if (res)  v += res[(size_t)r * ldc + c];
                if (relu) v = fmaxf(v, 0.f);
                if (Ch) {
                    if (qscale && c < 512) v *= SCALE;
                    Ch[(size_t)r * ldc + c] = f2h(v);
                } else {
                    C[(size_t)r * ldc + c] = v;
                }
            }
        }
    }
}

// ---------------- batched fp16 MFMA 256^3 (per head): C = diag*I + ss*(A@B) ----------------
__global__ __launch_bounds__(256) void bgemm_f16(
    const ushort_t* __restrict__ A, const ushort_t* __restrict__ B,
    ushort_t* __restrict__ C, float diag, float ss,
    ushort_t* __restrict__ C2, float diag2, float ss2)
{
    __shared__ ushort_t As[128 * 32];
    __shared__ ushort_t Bs[128 * 32];
    const int h = blockIdx.z;
    const ushort_t* Ah = A + (size_t)h * 65536;
    const ushort_t* Bh = B + (size_t)h * 65536;
    const int tid = threadIdx.x;
    const int wave = tid >> 6, lane = tid & 63;
    const int row0 = blockIdx.y * 128, col0 = blockIdx.x * 128;
    const int wr = (wave >> 1) * 64, wc = (wave & 1) * 64;
    const int sRow = lane >> 2;
    const int sCh = (lane & 3) * 8;
    const int kp = tid >> 4;
    const int nc = tid & 15;
    const int kk = (kp * 2) ^ ((nc & 3) << 3);
    const int lr = lane & 15, lk = (lane >> 4) * 8, lq = (lane >> 4) * 4;
    f32x4 acc[4][4] = {};
    for (int k0 = 0; k0 < 256; k0 += 32) {
        __syncthreads();
#pragma unroll
        for (int i = 0; i < 2; ++i) {
            const ushort_t* gp = Ah + (size_t)(row0 + i * 64 + wave * 16 + sRow) * 256 + k0 + sCh;
            __builtin_amdgcn_global_load_lds(GPTR(gp), LPTR(As + (i * 64 + wave * 16) * 32), 16, 0, 0);
        }
        const ushort_t* bp = Bh + (size_t)(k0 + kp * 2) * 256 + col0 + nc * 8;
        short8 v0 = *reinterpret_cast<const short8*>(bp);
        short8 v1 = *reinterpret_cast<const short8*>(bp + 256);
#pragma unroll
        for (int j = 0; j < 8; ++j) {
            unsigned int pk = ((unsigned int)(ushort_t)v1[j] << 16) | (unsigned int)(ushort_t)v0[j];
            *reinterpret_cast<unsigned int*>(&Bs[(nc * 8 + j) * 32 + kk]) = pk;
        }
        __syncthreads();
        half8 af[4], bfr[4];
#pragma unroll
        for (int mi = 0; mi < 4; ++mi)
            af[mi] = *reinterpret_cast<const half8*>(&As[(wr + mi * 16 + lr) * 32 + lk]);
#pragma unroll
        for (int ni = 0; ni < 4; ++ni) {
            int nn = wc + ni * 16 + lr;
            bfr[ni] = *reinterpret_cast<const half8*>(&Bs[nn * 32 + (lk ^ (((nn >> 3) & 3) << 3))]);
        }
#pragma unroll
        for (int mi = 0; mi < 4; ++mi)
#pragma unroll
            for (int ni = 0; ni < 4; ++ni)
                acc[mi][ni] = __builtin_amdgcn_mfma_f32_16x16x32_f16(af[mi], bfr[ni], acc[mi][ni], 0, 0, 0);
    }
    ushort_t* Chp = C + (size_t)h * 65536;
#pragma unroll
    for (int mi = 0; mi < 4; ++mi)
#pragma unroll
        for (int ni = 0; ni < 4; ++ni)
#pragma unroll
            for (int q = 0; q < 4; ++q) {
                int r = row0 + wr + mi * 16 + lq + q;
                int c = col0 + wc + ni * 16 + lr;
                float v = ss * acc[mi][ni][q];
                if (r == c) v += diag;
                Chp[(size_t)r * 256 + c] = f2h(v);
                if (C2) {
                    float v2 = ss2 * acc[mi][ni][q];
                    if (r == c) v2 += diag2;
                    C2[(size_t)h * 65536 + (size_t)r * 256 + c] = f2h(v2);
                }
            }
}

// ---------------- generic fp16 A@B^T MFMA (per head): C[m][n] = sum_k A[m][k] BT[n][k] ----------------
// grid (N/128, M/128, 8). All of M,N multiples of 128. Output fp16.
__global__ __launch_bounds__(256) void hgemm_abT_k(
    const ushort_t* __restrict__ A, long sAh, int lda,
    const ushort_t* __restrict__ BT, long sBh, int ldb,
    ushort_t* __restrict__ C, long sCh, int ldc, int K)
{
    __shared__ ushort_t As[128 * 32];
    __shared__ ushort_t Bs[128 * 32];
    const int h = blockIdx.z;
    const ushort_t* Ah = A + (size_t)h * sAh;
    const ushort_t* Bh = BT + (size_t)h * sBh;
    ushort_t* Chp = C + (size_t)h * sCh;
    const int tid = threadIdx.x;
    const int wave = tid >> 6, lane = tid & 63;
    const int row0 = blockIdx.y * 128, col0 = blockIdx.x * 128;
    const int wr = (wave >> 1) * 64, wc = (wave & 1) * 64;
    const int sRow = wave * 16 + (lane >> 2);
    const int sChk = (lane & 3) * 8;
    const int lr = lane & 15, lk = (lane >> 4) * 8, lq = (lane >> 4) * 4;
    f32x4 acc[4][4] = {};
    for (int k0 = 0; k0 < K; k0 += 32) {
        __syncthreads();
#pragma unroll
        for (int i = 0; i < 2; ++i) {
            const ushort_t* gp = Ah + (size_t)(row0 + i * 64 + sRow) * lda + k0 + sChk;
            __builtin_amdgcn_global_load_lds(GPTR(gp), LPTR(As + (i * 64 + wave * 16) * 32), 16, 0, 0);
            const ushort_t* gq = Bh + (size_t)(col0 + i * 64 + sRow) * ldb + k0 + sChk;
            __builtin_amdgcn_global_load_lds(GPTR(gq), LPTR(Bs + (i * 64 + wave * 16) * 32), 16, 0, 0);
        }
        __syncthreads();
        half8 af[4], bfr[4];
#pragma unroll
        for (int mi = 0; mi < 4; ++mi)
            af[mi] = *reinterpret_cast<const half8*>(&As[(wr + mi * 16 + lr) * 32 + lk]);
#pragma unroll
        for (int ni = 0; ni < 4; ++ni)
            bfr[ni] = *reinterpret_cast<const half8*>(&Bs[(wc + ni * 16 + lr) * 32 + lk]);
#pragma unroll
        for (int mi = 0; mi < 4; ++mi)
#pragma unroll
            for (int ni = 0; ni < 4; ++ni)
                acc[mi][ni] = __builtin_amdgcn_mfma_f32_16x16x32_f16(af[mi], bfr[ni], acc[mi][ni], 0, 0, 0);
    }
#pragma unroll
    for (int mi = 0; mi < 4; ++mi)
#pragma unroll
        for (int q = 0; q < 4; ++q) {
            int r = row0 + wr + mi * 16 + lq + q;
#pragma unroll
            for (int ni = 0; ni < 4; ++ni)
                Chp[(size_t)r * ldc + col0 + wc + ni * 16 + lr] = f2h(acc[mi][ni][q]);
        }
}

// ---------------- fused rowmax+exp (in-place) + rowsum, rows of length NP ----------------
__global__ __launch_bounds__(256) void rs3exp_k(ushort_t* __restrict__ S, float* __restrict__ rsum)
{
    __shared__ float red[256];
    int row = blockIdx.x, tid = threadIdx.x;
    ushort_t* p = S + (size_t)row * NP;
    float mx = -1e30f;
    for (int i = tid; i < NP; i += 256) mx = fmaxf(mx, h2f(p[i]));
    mx = blockReduceMaxF(mx, red, tid);
    float s = 0.f;
    for (int i = tid; i < NP; i += 256) {
        float e = __expf(h2f(p[i]) - mx);
        p[i] = f2h(e);
        s += e;
    }
    s = blockReduceSumF(s, red, tid);
    if (!tid) rsum[row] = s;
}

// ---------------- fused rowmax+exp (in-place) + rowsum, rows of length 256, wave/row ----------------
__global__ __launch_bounds__(256) void rs1exp_k(ushort_t* __restrict__ S, float* __restrict__ rsum)
{
    int wave = threadIdx.x >> 6, lane = threadIdx.x & 63;
    size_t row = (size_t)blockIdx.x * 4 + wave;
    ushort_t* p = S + row * 256;
    ushort4 u = *reinterpret_cast<const ushort4*>(p + lane * 4);
    float v0 = h2f(u.x), v1 = h2f(u.y), v2 = h2f(u.z), v3 = h2f(u.w);
    float mx = fmaxf(fmaxf(v0, v1), fmaxf(v2, v3));
    for (int off = 32; off; off >>= 1) mx = fmaxf(mx, __shfl_xor(mx, off, 64));
    float e0 = __expf(v0 - mx), e1 = __expf(v1 - mx), e2 = __expf(v2 - mx), e3 = __expf(v3 - mx);
    ushort4 w;
    w.x = f2h(e0); w.y = f2h(e1); w.z = f2h(e2); w.w = f2h(e3);
    *reinterpret_cast<ushort4*>(p + lane * 4) = w;
    float s = e0 + e1 + e2 + e3;
    for (int off = 32; off; off >>= 1) s += __shfl_xor(s, off, 64);
    if (!lane) rsum[row] = s;
}

// ---------------- pv: split-K fp16 MFMA, part += P[256][NP] @ V[NP][64] ----------------
// grid (KSPLIT, 2, 8). V rows from qkv16 (stride 1536). Wave tile 32x64.
__global__ __launch_bounds__(256) void hgemm_pv_k(
    const ushort_t* __restrict__ P, const ushort_t* __restrict__ qkv16,
    float* __restrict__ part)
{
    __shared__ ushort_t As[128 * 32];
    __shared__ ushort_t Bs[64 * 32];
    const int ks = blockIdx.x, row0 = blockIdx.y * 128, h = blockIdx.z;
    const ushort_t* Ph = P + (size_t)h * 256 * NP;
    const ushort_t* V = qkv16 + 1024 + h * 64;
    const int tid = threadIdx.x;
    const int wave = tid >> 6, lane = tid & 63;
    const int wr = wave * 32;
    const int sRow = wave * 16 + (lane >> 2);
    const int sChk = (lane & 3) * 8;
    const int lr = lane & 15, lk = (lane >> 4) * 8, lq = (lane >> 4) * 4;
    const int kp = (tid >> 3) & 15, nc = tid & 7;    // staging (first 128 threads)
    const int kk = (kp * 2) ^ ((nc & 3) << 3);
    f32x4 acc[2][4] = {};
    for (int k0 = ks * KCH; k0 < (ks + 1) * KCH; k0 += 32) {
        __syncthreads();
#pragma unroll
        for (int i = 0; i < 2; ++i) {
            const ushort_t* gp = Ph + (size_t)(row0 + i * 64 + sRow) * NP + k0 + sChk;
            __builtin_amdgcn_global_load_lds(GPTR(gp), LPTR(As + (i * 64 + wave * 16) * 32), 16, 0, 0);
        }
        if (tid < 128) {
            const ushort_t* bp = V + (size_t)(k0 + kp * 2) * 1536 + nc * 8;
            short8 v0 = *reinterpret_cast<const short8*>(bp);
            short8 v1 = *reinterpret_cast<const short8*>(bp + 1536);
#pragma unroll
            for (int j = 0; j < 8; ++j) {
                unsigned int pk = ((unsigned int)(ushort_t)v1[j] << 16) | (unsigned int)(ushort_t)v0[j];
                *reinterpret_cast<unsigned int*>(&Bs[(nc * 8 + j) * 32 + kk]) = pk;
            }
        }
        __syncthreads();
        half8 af[2], bfr[4];
#pragma unroll
        for (int mi = 0; mi < 2; ++mi)
            af[mi] = *reinterpret_cast<const half8*>(&As[(wr + mi * 16 + lr) * 32 + lk]);
#pragma unroll
        for (int ni = 0; ni < 4; ++ni) {
            int nn = ni * 16 + lr;
            bfr[ni] = *reinterpret_cast<const half8*>(&Bs[nn * 32 + (lk ^ (((nn >> 3) & 3) << 3))]);
        }
#pragma unroll
        for (int mi = 0; mi < 2; ++mi)
#pragma unroll
            for (int ni = 0; ni < 4; ++ni)
                acc[mi][ni] = __builtin_amdgcn_mfma_f32_16x16x32_f16(af[mi], bfr[ni], acc[mi][ni], 0, 0, 0);
    }
    float* pp = part + ((size_t)(ks * 8 + h) * 256) * 64;
#pragma unroll
    for (int mi = 0; mi < 2; ++mi)
#pragma unroll
        for (int q = 0; q < 4; ++q) {
            int r = row0 + wr + mi * 16 + lq + q;
#pragma unroll
            for (int ni = 0; ni < 4; ++ni)
                pp[(size_t)r * 64 + ni * 16 + lr] = acc[mi][ni][q];
        }
}

__global__ __launch_bounds__(256) void pv_reduce_k(const float* __restrict__ part,
                                                   const float* __restrict__ rsum,
                                                   ushort_t* __restrict__ av)
{
    int idx = blockIdx.x * 256 + threadIdx.x;   // 131072
    int rc = idx >> 6;
    float s = 0.f;
#pragma unroll
    for (int ks = 0; ks < KSPLIT; ++ks)
        s += part[(size_t)ks * 131072 + idx];
    av[idx] = f2h(s / rsum[rc]);
}

// ---------------- W = z @ av (per head 256x256 @ 256x64), fp16 ----------------
__global__ void wmat_k(const ushort_t* __restrict__ z, const ushort_t* __restrict__ av,
                       ushort_t* __restrict__ W)
{
    int h = blockIdx.x >> 8, m = blockIdx.x & 255, d = threadIdx.x;
    const ushort_t* zp = z + (size_t)h * 65536 + (size_t)m * 256;
    const ushort_t* ap = av + (size_t)h * 16384 + d;
    float acc = 0.f;
    for (int j = 0; j < 256; ++j) acc += h2f(zp[j]) * h2f(ap[(size_t)j * 64]);
    W[((size_t)h * 256 + m) * 64 + d] = f2h(acc);
}

// ---------------- pw: attn[t][h*64+n] = (P1[t][:] @ W[:][n]) / rsum1 (fp16 MFMA) ----------------
// grid (1, NP/128, 8). Wave tile 32x64, K=256.
__global__ __launch_bounds__(256) void hgemm_pw_k(
    const ushort_t* __restrict__ P1, const ushort_t* __restrict__ W,
    const float* __restrict__ rsum, ushort_t* __restrict__ attn)
{
    __shared__ ushort_t As[128 * 32];
    __shared__ ushort_t Bs[64 * 32];
    const int row0 = blockIdx.y * 128, h = blockIdx.z;
    const ushort_t* Ph = P1 + (size_t)h * NP * 256;
    const ushort_t* Wh = W + (size_t)h * 16384;
    const int tid = threadIdx.x;
    const int wave = tid >> 6, lane = tid & 63;
    const int wr = wave * 32;
    const int sRow = wave * 16 + (lane >> 2);
    const int sChk = (lane & 3) * 8;
    const int lr = lane & 15, lk = (lane >> 4) * 8, lq = (lane >> 4) * 4;
    const int kp = (tid >> 3) & 15, nc = tid & 7;
    const int kk = (kp * 2) ^ ((nc & 3) << 3);
    f32x4 acc[2][4] = {};
    for (int k0 = 0; k0 < 256; k0 += 32) {
        __syncthreads();
#pragma unroll
        for (int i = 0; i < 2; ++i) {
            const ushort_t* gp = Ph + (size_t)(row0 + i * 64 + sRow) * 256 + k0 + sChk;
            __builtin_amdgcn_global_load_lds(GPTR(gp), LPTR(As + (i * 64 + wave * 16) * 32), 16, 0, 0);
        }
        if (tid < 128) {
            const ushort_t* bp = Wh + (size_t)(k0 + kp * 2) * 64 + nc * 8;
            short8 v0 = *reinterpret_cast<const short8*>(bp);
            short8 v1 = *reinterpret_cast<const short8*>(bp + 64);
#pragma unroll
            for (int j = 0; j < 8; ++j) {
                unsigned int pk = ((unsigned int)(ushort_t)v1[j] << 16) | (unsigned int)(ushort_t)v0[j];
                *reinterpret_cast<unsigned int*>(&Bs[(nc * 8 + j) * 32 + kk]) = pk;
            }
        }
        __syncthreads();
        half8 af[2], bfr[4];
#pragma unroll
        for (int mi = 0; mi < 2; ++mi)
            af[mi] = *reinterpret_cast<const half8*>(&As[(wr + mi * 16 + lr) * 32 + lk]);
#pragma unroll
        for (int ni = 0; ni < 4; ++ni) {
            int nn = ni * 16 + lr;
            bfr[ni] = *reinterpret_cast<const half8*>(&Bs[nn * 32 + (lk ^ (((nn >> 3) & 3) << 3))]);
        }
#pragma unroll
        for (int mi = 0; mi < 2; ++mi)
#pragma unroll
            for (int ni = 0; ni < 4; ++ni)
                acc[mi][ni] = __builtin_amdgcn_mfma_f32_16x16x32_f16(af[mi], bfr[ni], acc[mi][ni], 0, 0, 0);
    }
#pragma unroll
    for (int mi = 0; mi < 2; ++mi)
#pragma unroll
        for (int q = 0; q < 4; ++q) {
            int t = row0 + wr + mi * 16 + lq + q;
            float inv = 1.f / rsum[(size_t)h * NP + t];
#pragma unroll
            for (int ni = 0; ni < 4; ++ni)
                attn[(size_t)t * 512 + h * 64 + ni * 16 + lr] = f2h(acc[mi][ni][q] * inv);
        }
}

// ---------------- fixup: cls token + wrap rows ----------------
__global__ void fixup_k(const float* __restrict__ cls, float* __restrict__ h)
{
    int i = blockIdx.x * 256 + threadIdx.x;
    if (i < 512) {
        h[i] = cls[i];
    } else {
        int j = i - 512;
        h[(size_t)8193 * 512 + j] = h[512 + j];
    }
}

// ---------------- layernorm + front zero-pad: out[NP][512] fp16 ----------------
__global__ __launch_bounds__(256) void ln_pad_k(
    const float* __restrict__ h, const float* __restrict__ g, const float* __restrict__ b,
    ushort_t* __restrict__ out)
{
    int row = blockIdx.x, tid = threadIdx.x;
    __shared__ float red[256];
    ushort_t* o = out + (size_t)row * 512;
    if (row < PAD) { o[tid] = 0; o[tid + 256] = 0; return; }
    const float* x = h + (size_t)(row - PAD) * 512;
    float v0 = x[tid], v1 = x[tid + 256];
    float mu = blockReduceSumF(v0 + v1, red, tid) * (1.f / 512.f);
    float d0 = v0 - mu, d1 = v1 - mu;
    float var = blockReduceSumF(d0 * d0 + d1 * d1, red, tid) * (1.f / 512.f);
    float rstd = rsqrtf(var + 1e-5f);
    o[tid]       = f2h(d0 * rstd * g[tid] + b[tid]);
    o[tid + 256] = f2h(d1 * rstd * g[tid + 256] + b[tid + 256]);
}

// ---------------- landmark means (q already pre-scaled) ----------------
__global__ void landmark_k(const ushort_t* __restrict__ qkv, ushort_t* __restrict__ ql,
                           ushort_t* __restrict__ kl)
{
    int h = blockIdx.x >> 8, m = blockIdx.x & 255, d = threadIdx.x;
    const ushort_t* base = qkv + (size_t)(m * LCH) * 1536 + h * 64 + d;
    float sq = 0.f, sk = 0.f;
    for (int i = 0; i < LCH; ++i) {
        sq += h2f(base[(size_t)i * 1536]);
        sk += h2f(base[(size_t)i * 1536 + 512]);
    }
    ql[((size_t)h * 256 + m) * 64 + d] = f2h(sq * (1.f / (float)LCH));
    kl[((size_t)h * 256 + m) * 64 + d] = f2h(sk * (1.f / (float)LCH));
}

// ---------------- a2 = softmax(ql @ kl^T), fp16 out ----------------
__global__ __launch_bounds__(256) void a2_k(
    const ushort_t* __restrict__ ql, const ushort_t* __restrict__ kl, ushort_t* __restrict__ a2)
{
    int h = blockIdx.x >> 8, r = blockIdx.x & 255, tid = threadIdx.x;
    __shared__ float qv[64]; __shared__ float red[256];
    if (tid < 64) qv[tid] = h2f(ql[((size_t)h * 256 + r) * 64 + tid]);
    __syncthreads();
    const ushort_t* kp = kl + ((size_t)h * 256 + tid) * 64;
    float dot = 0.f;
#pragma unroll
    for (int d = 0; d < 64; ++d) dot += qv[d] * h2f(kp[d]);
    float mx = blockReduceMaxF(dot, red, tid);
    float e = expf(dot - mx);
    float s = blockReduceSumF(e, red, tid);
    a2[((size_t)h * 256 + r) * 256 + tid] = f2h(e / s);
}

// ---------------- pinv init helpers (fp16 a2) ----------------
__global__ __launch_bounds__(256) void rowsum_k(const ushort_t* __restrict__ a2, float* __restrict__ rs)
{
    int r = blockIdx.x; __shared__ float red[256];
    float v = fabsf(h2f(a2[(size_t)r * 256 + threadIdx.x]));
    float s = blockReduceSumF(v, red, threadIdx.x);
    if (!threadIdx.x) rs[r] = s;
}
__global__ __launch_bounds__(256) void colsum_k(const ushort_t* __restrict__ a2, float* __restrict__ cs)
{
    int h = blockIdx.x >> 8, c = blockIdx.x & 255;
    __shared__ float red[256];
    float v = fabsf(h2f(a2[(size_t)h * 65536 + (size_t)threadIdx.x * 256 + c]));
    float s = blockReduceSumF(v, red, threadIdx.x);
    if (!threadIdx.x) cs[blockIdx.x] = s;
}
__global__ __launch_bounds__(256) void pinv_scal_k(const float* __restrict__ rs, const float* __restrict__ cs,
                                                   float* __restrict__ scal)
{
    int tid = threadIdx.x; __shared__ float red[256];
    float m1 = -1e30f, m2 = -1e30f;
    for (int i = tid; i < 2048; i += 256) { m1 = fmaxf(m1, rs[i]); m2 = fmaxf(m2, cs[i]); }
    m1 = blockReduceMaxF(m1, red, tid);
    m2 = blockReduceMaxF(m2, red, tid);
    if (!tid) scal[0] = 1.f / (m1 * m2);
}
__global__ __launch_bounds__(256) void zinit_k(const ushort_t* __restrict__ a2, const float* __restrict__ scal,
                                               ushort_t* __restrict__ z)
{
    int h = blockIdx.x >> 8, r = blockIdx.x & 255, c = threadIdx.x;
    z[(size_t)h * 65536 + (size_t)r * 256 + c] =
        f2h(h2f(a2[(size_t)h * 65536 + (size_t)c * 256 + r]) * scal[0]);
}

// ---------------- tiled depthwise 33-tap conv over tokens on v (fp16), added to fp16 attn ----------------
#define CTT 64
__global__ __launch_bounds__(256) void conv2_k(const ushort_t* __restrict__ qkv,
                                               const float* __restrict__ cw,
                                               ushort_t* __restrict__ attn)
{
    __shared__ float vt[CTT + 32][64];
    int t0 = blockIdx.x * CTT;
    int h = blockIdx.y;
    int tid = threadIdx.x;
    for (int s = tid; s < (CTT + 32) * 8; s += 256) {
        int row = s >> 3, q8 = s & 7;
        int tt = t0 - 16 + row;
        if (tt >= 0 && tt < NP) {
            short8 v = *reinterpret_cast<const short8*>(qkv + (size_t)tt * 1536 + 1024 + h * 64 + q8 * 8);
#pragma unroll
            for (int j = 0; j < 8; ++j) vt[row][q8 * 8 + j] = h2f((ushort_t)v[j]);
        } else {
#pragma unroll
            for (int j = 0; j < 8; ++j) vt[row][q8 * 8 + j] = 0.f;
        }
    }
    float w33[33];
#pragma unroll
    for (int j = 0; j < 33; ++j) w33[j] = cw[h * 33 + j];
    __syncthreads();
    int c = tid & 63, tr = tid >> 6;
    float win[48];
#pragma unroll
    for (int j = 0; j < 48; ++j) win[j] = vt[tr * 16 + j][c];
#pragma unroll
    for (int i = 0; i < 16; ++i) {
        float acc = 0.f;
#pragma unroll
        for (int j = 0; j < 33; ++j) acc += w33[j] * win[i + j];
        size_t idx = (size_t)(t0 + tr * 16 + i) * 512 + h * 64 + c;
        attn[idx] = f2h(h2f(attn[idx]) + acc);
    }
}

// ---------------- PPEG tiled ----------------
#define PTS  16
#define PIT  22
#define PITT (PIT*PIT)
#define PCG  16
__global__ __launch_bounds__(256) void ppeg_tiled_k(
    const float* __restrict__ hin,
    const float* __restrict__ w7, const float* __restrict__ b7,
    const float* __restrict__ w5, const float* __restrict__ b5,
    const float* __restrict__ w3, const float* __restrict__ b3,
    float* __restrict__ hout)
{
    __shared__ float inb[PCG][PITT + 1];
    __shared__ float wc[PCG][49];
    __shared__ float bs[PCG];
    int tid = threadIdx.x;
    int c0 = blockIdx.z * PCG;
    int ty0 = blockIdx.y * PTS, tx0 = blockIdx.x * PTS;
    if (blockIdx.x == 0 && blockIdx.y == 0 && tid < PCG)
        hout[c0 + tid] = hin[c0 + tid];
    for (int idx = tid; idx < PITT * (PCG / 4); idx += 256) {
        int tok = idx >> 2, q = idx & 3;
        int gy = ty0 - 3 + tok / PIT, gx = tx0 - 3 + tok % PIT;
        float4 v = make_float4(0.f, 0.f, 0.f, 0.f);
        if (gy >= 0 && gy < HS && gx >= 0 && gx < HS)
            v = *reinterpret_cast<const float4*>(hin + (size_t)(1 + gy * HS + gx) * 512 + c0 + q * 4);
        inb[q * 4 + 0][tok] = v.x; inb[q * 4 + 1][tok] = v.y;
        inb[q * 4 + 2][tok] = v.z; inb[q * 4 + 3][tok] = v.w;
    }
    for (int idx = tid; idx < PCG * 49; idx += 256) {
        int c = idx / 49, t = idx % 49;
        int ky = t / 7, kx = t % 7, dy = ky - 3, dx = kx - 3;
        float w = w7[(size_t)(c0 + c) * 49 + t];
        if (dy >= -2 && dy <= 2 && dx >= -2 && dx <= 2)
            w += w5[(size_t)(c0 + c) * 25 + (dy + 2) * 5 + (dx + 2)];
        if (dy >= -1 && dy <= 1 && dx >= -1 && dx <= 1)
            w += w3[(size_t)(c0 + c) * 9 + (dy + 1) * 3 + (dx + 1)];
        wc[c][t] = w;
    }
    if (tid < PCG) bs[tid] = b7[c0 + tid] + b5[c0 + tid] + b3[c0 + tid];
    __syncthreads();
    int oy = tid >> 4, ox = tid & 15;
    int gy = ty0 + oy, gx = tx0 + ox;
    if (gy >= HS || gx >= HS) return;
    float* out = hout + (size_t)(1 + gy * HS + gx) * 512 + c0;
#pragma unroll 4
    for (int c = 0; c < PCG; ++c) {
        float acc = inb[c][(oy + 3) * PIT + ox + 3] + bs[c];
#pragma unroll
        for (int ky = 0; ky < 7; ++ky)
#pragma unroll
            for (int kx = 0; kx < 7; ++kx)
                acc += wc[c][ky * 7 + kx] * inb[c][(oy + ky) * PIT + ox + kx];
        out[c] = acc;
    }
}

// ---------------- final LN(row0) + fc2 + softmax + argmax ----------------
__global__ __launch_bounds__(256) void final_k(const float* __restrict__ h,
                                               const float* __restrict__ g, const float* __restrict__ bb,
                                               const float* __restrict__ w, const float* __restrict__ fb,
                                               float* __restrict__ out)
{
    __shared__ float red[256];
    int tid = threadIdx.x;
    float v0 = h[tid], v1 = h[tid + 256];
    float mu = blockReduceSumF(v0 + v1, red, tid) * (1.f / 512.f);
    float d0 = v0 - mu, d1 = v1 - mu;
    float var = blockReduceSumF(d0 * d0 + d1 * d1, red, tid) * (1.f / 512.f);
    float rstd = rsqrtf(var + 1e-5f);
    float e0 = d0 * rstd * g[tid] + bb[tid];
    float e1 = d1 * rstd * g[tid + 256] + bb[tid + 256];
    out[5 + tid] = e0;
    out[5 + 256 + tid] = e1;
    float l0p = e0 * w[tid * 2] + e1 * w[(tid + 256) * 2];
    float l1p = e0 * w[tid * 2 + 1] + e1 * w[(tid + 256) * 2 + 1];
    float l0 = blockReduceSumF(l0p, red, tid);
    float l1 = blockReduceSumF(l1p, red, tid);
    if (!tid) {
        l0 += fb[0]; l1 += fb[1];
        out[0] = l0; out[1] = l1;
        float mx = fmaxf(l0, l1);
        float p0 = expf(l0 - mx), p1 = expf(l1 - mx);
        float si = 1.f / (p0 + p1);
        out[2] = p0 * si; out[3] = p1 * si;
        out[4] = (l1 > l0) ? 1.f : 0.f;
    }
}

// ---------------- host orchestration ----------------
struct WsPtrs {
    float *h, *h2, *rs, *cs, *scal, *rsum3, *rsum1, *part;
    ushort_t *xbB, *qkv16, *ql16, *kl16, *a2h, *zh, *z2h, *xzh, *t1h, *t2h;
    ushort_t *av16, *W16, *qkvT, *outT, *x16, *fc1T, *S16;
};

static void run_attn(float* hbuf, const float* ln_g, const float* ln_b,
                     const float* qkv_w, const float* out_w, const float* out_b,
                     const float* conv_w, const WsPtrs& P, hipStream_t s)
{
    tcast_k<<<dim3(1536 / 32, 512 / 32), 256, 0, s>>>(qkv_w, P.qkvT, 512, 1536);
    tcast_k<<<dim3(512 / 32, 512 / 32), 256, 0, s>>>(out_w, P.outT, 512, 512);
    ln_pad_k<<<NP, 256, 0, s>>>(hbuf, ln_g, ln_b, P.xbB);
    // qkv = xb @ qkv_w -> fp16, q pre-scaled by SCALE
    gemm_f16<<<dim3(1536 / 128, NP / 128), 256, 0, s>>>(P.xbB, P.qkvT, nullptr, nullptr,
                                                        nullptr, P.qkv16, NP, 512, 512, 512, 1536, 0, 1);
    landmark_k<<<2048, 64, 0, s>>>(P.qkv16, P.ql16, P.kl16);
    a2_k<<<2048, 256, 0, s>>>(P.ql16, P.kl16, P.a2h);
    rowsum_k<<<2048, 256, 0, s>>>(P.a2h, P.rs);
    colsum_k<<<2048, 256, 0, s>>>(P.a2h, P.cs);
    pinv_scal_k<<<1, 256, 0, s>>>(P.rs, P.cs, P.scal);
    zinit_k<<<2048, 256, 0, s>>>(P.a2h, P.scal, P.zh);
    ushort_t* za = P.zh; ushort_t* zb = P.z2h;
    for (int it = 0; it < 6; ++it) {
        bgemm_f16<<<dim3(2, 2, 8), 256, 0, s>>>(P.a2h, za, P.xzh, 0.f, 1.f, P.t1h, 7.f, -1.f);
        bgemm_f16<<<dim3(2, 2, 8), 256, 0, s>>>(P.xzh, P.t1h, P.t2h, 15.f, -1.f, nullptr, 0.f, 0.f);
        bgemm_f16<<<dim3(2, 2, 8), 256, 0, s>>>(P.xzh, P.t2h, P.t1h, 13.f, -1.f, nullptr, 0.f, 0.f);
        bgemm_f16<<<dim3(2, 2, 8), 256, 0, s>>>(za, P.t1h, zb, 0.f, 0.25f, nullptr, 0.f, 0.f);
        ushort_t* tmp = za; za = zb; zb = tmp;
    }
    // av path: S3 = ql @ K^T (fp16 MFMA) -> exp in place -> PV split-K MFMA -> reduce
    hgemm_abT_k<<<dim3(NP / 128, 2, 8), 256, 0, s>>>(P.ql16, 16384, 64,
                                                     P.qkv16 + 512, 64, 1536,
                                                     P.S16, (long)256 * NP, NP, 64);
    rs3exp_k<<<2048, 256, 0, s>>>(P.S16, P.rsum3);
    hgemm_pv_k<<<dim3(KSPLIT, 2, 8), 256, 0, s>>>(P.S16, P.qkv16, P.part);
    pv_reduce_k<<<512, 256, 0, s>>>(P.part, P.rsum3, P.av16);
    wmat_k<<<2048, 64, 0, s>>>(za, P.av16, P.W16);
    // a1 path: S1 = q @ kl^T -> exp -> PW MFMA (token-major fp16 attn into xbB)
    hgemm_abT_k<<<dim3(2, NP / 128, 8), 256, 0, s>>>(P.qkv16, 64, 1536,
                                                     P.kl16, 16384, 64,
                                                     P.S16, (long)NP * 256, 256, 64);
    rs1exp_k<<<(8 * NP) / 4, 256, 0, s>>>(P.S16, P.rsum1);
    hgemm_pw_k<<<dim3(1, NP / 128, 8), 256, 0, s>>>(P.S16, P.W16, P.rsum1, P.xbB);
    conv2_k<<<dim3(NP / CTT, 8), 256, 0, s>>>(P.qkv16, conv_w, P.xbB);
    // h += attn[-N1:] @ out_w + out_b  (f32 residual epilogue)
    gemm_f16<<<dim3(512 / 128, (N1 + 127) / 128), 256, 0, s>>>(P.xbB + (size_t)PAD * 512, P.outT,
                                                               out_b, hbuf, hbuf, nullptr,
                                                               N1, 512, 512, 512, 512, 0, 0);
}

extern "C" void kernel_launch(void* const* d_in, const int* in_sizes, int n_in,
                              void* d_out, int out_size, void* d_ws, size_t ws_size,
                              hipStream_t stream)
{
    (void)in_sizes; (void)n_in; (void)out_size; (void)ws_size;
    const float* x       = (const float*)d_in[0];
    const float* fc1_w   = (const float*)d_in[1];
    const float* fc1_b   = (const float*)d_in[2];
    const float* cls_tok = (const float*)d_in[3];
    const float* ln1_g   = (const float*)d_in[4];
    const float* ln1_b   = (const float*)d_in[5];
    const float* qkv1_w  = (const float*)d_in[6];
    const float* out1_w  = (const float*)d_in[7];
    const float* out1_b  = (const float*)d_in[8];
    const float* conv1_w = (const float*)d_in[9];
    const float* ln2_g   = (const float*)d_in[10];
    const float* ln2_b   = (const float*)d_in[11];
    const float* qkv2_w  = (const float*)d_in[12];
    const float* out2_w  = (const float*)d_in[13];
    const float* out2_b  = (const float*)d_in[14];
    const float* conv2_w = (const float*)d_in[15];
    const float* pg7_w   = (const float*)d_in[16];
    const float* pg7_b   = (const float*)d_in[17];
    const float* pg5_w   = (const float*)d_in[18];
    const float* pg5_b   = (const float*)d_in[19];
    const float* pg3_w   = (const float*)d_in[20];
    const float* pg3_b   = (const float*)d_in[21];
    const float* norm_g  = (const float*)d_in[22];
    const float* norm_b  = (const float*)d_in[23];
    const float* fc2_w   = (const float*)d_in[24];
    const float* fc2_b   = (const float*)d_in[25];

    float* ws = (float*)d_ws;
    WsPtrs P;
    float* cur = ws;
    P.h     = cur; cur += (size_t)N1 * 512;
    P.h2    = cur; cur += (size_t)N1 * 512;
    P.xbB   = (ushort_t*)cur; cur += (size_t)NP * 512 / 2;
    P.qkv16 = (ushort_t*)cur; cur += (size_t)NP * 1536 / 2;
    P.ql16  = (ushort_t*)cur; cur += 65536;
    P.kl16  = (ushort_t*)cur; cur += 65536;
    P.a2h   = (ushort_t*)cur; cur += 262144;
    P.zh    = (ushort_t*)cur; cur += 262144;
    P.z2h   = (ushort_t*)cur; cur += 262144;
    P.xzh   = (ushort_t*)cur; cur += 262144;
    P.t1h   = (ushort_t*)cur; cur += 262144;
    P.t2h   = (ushort_t*)cur; cur += 262144;
    P.av16  = (ushort_t*)cur; cur += 65536;
    P.W16   = (ushort_t*)cur; cur += 65536;
    P.rs    = cur; cur += 2048;
    P.cs    = cur; cur += 2048;
    P.scal  = cur; cur += 64;
    P.qkvT  = (ushort_t*)cur; cur += 393216 + 64;   // 1536x512 halfs
    P.outT  = (ushort_t*)cur; cur += 131072 + 64;   // 512x512 halfs
    P.rsum3 = cur; cur += 2048;
    P.rsum1 = cur; cur += (size_t)8 * NP;
    P.part  = cur; cur += (size_t)KSPLIT * 131072;
    P.S16   = (ushort_t*)cur; cur += (size_t)8 * 256 * NP / 2;
    // x16 / fc1T alias S16 (used only before block 1's S-path)
    P.x16   = P.S16;                                         // 8192x1024 halfs
    P.fc1T  = P.S16 + (size_t)NTOK * INDIM;                  // 512x1024 halfs

    bcast_k<<<(NTOK * INDIM) / 1024, 256, 0, stream>>>(x, P.x16);
    tcast_k<<<dim3(512 / 32, 1024 / 32), 256, 0, stream>>>(fc1_w, P.fc1T, 1024, 512);
    gemm_f16<<<dim3(512 / 128, NTOK / 128), 256, 0, stream>>>(P.x16, P.fc1T, fc1_b, nullptr,
                                                              P.h + 512, nullptr,
                                                              NTOK, 1024, 1024, 1024, 512, 1, 0);
    fixup_k<<<180, 256, 0, stream>>>(cls_tok, P.h);
    run_attn(P.h, ln1_g, ln1_b, qkv1_w, out1_w, out1_b, conv1_w, P, stream);
    ppeg_tiled_k<<<dim3(6, 6, 512 / PCG), 256, 0, stream>>>(P.h, pg7_w, pg7_b, pg5_w, pg5_b,
                                                            pg3_w, pg3_b, P.h2);
    run_attn(P.h2, ln2_g, ln2_b, qkv2_w, out2_w, out2_b, conv2_w, P, stream);
    final_k<<<1, 256, 0, stream>>>(P.h2, norm_g, norm_b, fc2_w, fc2_b, (float*)d_out);
}

// Round 10
// 944.935 us; speedup vs baseline: 5.9626x; 1.1864x over previous
//
#include <hip/hip_runtime.h>
#include <math.h>

// ---------------- constants ----------------
#define NTOK   8192
#define INDIM  1024
#define NHEAD  8
#define N1     8282      // tokens incl cls (91*91 + 1)
#define NP     8448      // padded token count inside attention
#define PAD    166
#define LCH    33        // tokens per landmark chunk
#define SCALE  0.125f
#define HS     91
#define KSPLIT 8
#define KCH    (NP / KSPLIT)   // 1056

typedef __attribute__((ext_vector_type(8))) _Float16 half8;
typedef __attribute__((ext_vector_type(8))) short short8;
typedef __attribute__((ext_vector_type(4))) float f32x4;
typedef unsigned short ushort_t;

#define GPTR(p) ((const __attribute__((address_space(1))) void*)(p))
#define LPTR(p) ((__attribute__((address_space(3))) void*)(p))

__device__ __forceinline__ ushort_t f2h(float f) {
    union { _Float16 h; ushort_t u; } v; v.h = (_Float16)f;
    return v.u;
}
__device__ __forceinline__ float h2f(ushort_t u) {
    union { ushort_t u; _Float16 h; } v; v.u = u;
    return (float)v.h;
}

// ---------------- reduce helpers (256-thread blocks) ----------------
__device__ __forceinline__ float blockReduceSumF(float v, float* red, int tid) {
    red[tid] = v; __syncthreads();
    for (int s = 128; s > 0; s >>= 1) {
        if (tid < s) red[tid] += red[tid + s];
        __syncthreads();
    }
    float r = red[0]; __syncthreads();
    return r;
}
__device__ __forceinline__ float blockReduceMaxF(float v, float* red, int tid) {
    red[tid] = v; __syncthreads();
    for (int s = 128; s > 0; s >>= 1) {
        if (tid < s) red[tid] = fmaxf(red[tid], red[tid + s]);
        __syncthreads();
    }
    float r = red[0]; __syncthreads();
    return r;
}

// ---------------- weight transpose+cast: wT[n][k] = fp16(w[k][n]) ----------------
__global__ __launch_bounds__(256) void tcast_k(const float* __restrict__ w, ushort_t* __restrict__ wT,
                                               int K, int N)
{
    __shared__ float tb[32][33];
    int tx = threadIdx.x & 31, ty = threadIdx.x >> 5;
    int n0 = blockIdx.x * 32, k0 = blockIdx.y * 32;
#pragma unroll
    for (int i = 0; i < 4; ++i)
        tb[ty + i * 8][tx] = w[(size_t)(k0 + ty + i * 8) * N + n0 + tx];
    __syncthreads();
#pragma unroll
    for (int i = 0; i < 4; ++i)
        wT[(size_t)(n0 + ty + i * 8) * K + k0 + tx] = f2h(tb[tx][ty + i * 8]);
}

// ---------------- cast f32 -> fp16 (4 els/thread) ----------------
__global__ void bcast_k(const float* __restrict__ x, ushort_t* __restrict__ o)
{
    int i = blockIdx.x * 256 + threadIdx.x;
    float4 v = reinterpret_cast<const float4*>(x)[i];
    ushort4 u;
    u.x = f2h(v.x); u.y = f2h(v.y); u.z = f2h(v.z); u.w = f2h(v.w);
    reinterpret_cast<ushort4*>(o)[i] = u;
}

// ---------------- fp16 MFMA GEMM: out = [res +] A@B [+ bias] [relu] ----------------
// A: fp16 [.][lda]; BT: fp16 [N][ldb] = B^T. Output f32 C (if Ch==null) or fp16 Ch.
// qscale: multiply cols < 512 by SCALE (fused q-scaling in the qkv projection).
__global__ __launch_bounds__(256) void gemm_f16(
    const ushort_t* __restrict__ A, const ushort_t* __restrict__ BT,
    const float* __restrict__ bias, const float* __restrict__ res,
    float* __restrict__ C, ushort_t* __restrict__ Ch,
    int Mvalid, int K, int lda, int ldb, int ldc, int relu, int qscale)
{
    __shared__ ushort_t As[128 * 32];
    __shared__ ushort_t Bs[128 * 32];
    const int tid = threadIdx.x;
    const int wave = tid >> 6, lane = tid & 63;
    const int row0 = blockIdx.y * 128, col0 = blockIdx.x * 128;
    const int wr = (wave >> 1) * 64, wc = (wave & 1) * 64;
    const int sRow = wave * 16 + (lane >> 2);
    const int sCh = (lane & 3) * 8;
    const int lr = lane & 15, lk = (lane >> 4) * 8, lq = (lane >> 4) * 4;
    f32x4 acc[4][4] = {};
    for (int k0 = 0; k0 < K; k0 += 32) {
        __syncthreads();
#pragma unroll
        for (int i = 0; i < 2; ++i) {
            const ushort_t* gp = A + (size_t)(row0 + i * 64 + sRow) * lda + k0 + sCh;
            __builtin_amdgcn_global_load_lds(GPTR(gp), LPTR(As + (i * 64 + wave * 16) * 32), 16, 0, 0);
            const ushort_t* gq = BT + (size_t)(col0 + i * 64 + sRow) * ldb + k0 + sCh;
            __builtin_amdgcn_global_load_lds(GPTR(gq), LPTR(Bs + (i * 64 + wave * 16) * 32), 16, 0, 0);
        }
        __syncthreads();
        half8 af[4], bfr[4];
#pragma unroll
        for (int mi = 0; mi < 4; ++mi)
            af[mi] = *reinterpret_cast<const half8*>(&As[(wr + mi * 16 + lr) * 32 + lk]);
#pragma unroll
        for (int ni = 0; ni < 4; ++ni)
            bfr[ni] = *reinterpret_cast<const half8*>(&Bs[(wc + ni * 16 + lr) * 32 + lk]);
#pragma unroll
        for (int mi = 0; mi < 4; ++mi)
#pragma unroll
            for (int ni = 0; ni < 4; ++ni)
                acc[mi][ni] = __builtin_amdgcn_mfma_f32_16x16x32_f16(af[mi], bfr[ni], acc[mi][ni], 0, 0, 0);
    }
#pragma unroll
    for (int mi = 0; mi < 4; ++mi) {
#pragma unroll
        for (int q = 0; q < 4; ++q) {
            int r = row0 + wr + mi * 16 + lq + q;
            if (r >= Mvalid) continue;
#pragma unroll
            for (int ni = 0; ni < 4; ++ni) {
                int c = col0 + wc + ni * 16 + lr;
                float v = acc[mi][ni][q];
                if (bias) v += bias[c];
                if (res)  v += res[(size_t)r * ldc + c];
                if (relu) v = fmaxf(v, 0.f);
                if (Ch) {
                    if (qscale && c < 512) v *= SCALE;
                    Ch[(size_t)r * ldc + c] = f2h(v);
                } else {
                    C[(size_t)r * ldc + c] = v;
                }
            }
        }
    }
}

// ---------------- batched fp16 MFMA 256^3, 64x64 tiles: C = diag*I + ss*(A@B) ----------------
// grid (4,4,8) = 128 WGs. 4 waves x 32x32 tile. B transpose-staged (validated swizzle).
__global__ __launch_bounds__(256) void bgemm64_f16(
    const ushort_t* __restrict__ A, const ushort_t* __restrict__ B,
    ushort_t* __restrict__ C, float diag, float ss,
    ushort_t* __restrict__ C2, float diag2, float ss2)
{
    __shared__ ushort_t As[64 * 32];
    __shared__ ushort_t Bs[64 * 32];
    const int h = blockIdx.z;
    const ushort_t* Ah = A + (size_t)h * 65536;
    const ushort_t* Bh = B + (size_t)h * 65536;
    const int tid = threadIdx.x;
    const int wave = tid >> 6, lane = tid & 63;
    const int row0 = blockIdx.y * 64, col0 = blockIdx.x * 64;
    const int wr = (wave >> 1) * 32, wc = (wave & 1) * 32;
    const int aRow = tid >> 2, aCh = (tid & 3) * 8;
    const int kp = (tid >> 3) & 15, nc = tid & 7;
    const int kk = (kp * 2) ^ ((nc & 3) << 3);
    const int lr = lane & 15, lk = (lane >> 4) * 8, lq = (lane >> 4) * 4;
    f32x4 acc[2][2] = {};
    for (int k0 = 0; k0 < 256; k0 += 32) {
        __syncthreads();
        const ushort_t* gp = Ah + (size_t)(row0 + aRow) * 256 + k0 + aCh;
        __builtin_amdgcn_global_load_lds(GPTR(gp), LPTR(As + tid * 8), 16, 0, 0);
        if (tid < 128) {
            const ushort_t* bp = Bh + (size_t)(k0 + kp * 2) * 256 + col0 + nc * 8;
            short8 v0 = *reinterpret_cast<const short8*>(bp);
            short8 v1 = *reinterpret_cast<const short8*>(bp + 256);
#pragma unroll
            for (int j = 0; j < 8; ++j) {
                unsigned int pk = ((unsigned int)(ushort_t)v1[j] << 16) | (unsigned int)(ushort_t)v0[j];
                *reinterpret_cast<unsigned int*>(&Bs[(nc * 8 + j) * 32 + kk]) = pk;
            }
        }
        __syncthreads();
        half8 af[2], bfr[2];
#pragma unroll
        for (int mi = 0; mi < 2; ++mi)
            af[mi] = *reinterpret_cast<const half8*>(&As[(wr + mi * 16 + lr) * 32 + lk]);
#pragma unroll
        for (int ni = 0; ni < 2; ++ni) {
            int nn = wc + ni * 16 + lr;
            bfr[ni] = *reinterpret_cast<const half8*>(&Bs[nn * 32 + (lk ^ (((nn >> 3) & 3) << 3))]);
        }
#pragma unroll
        for (int mi = 0; mi < 2; ++mi)
#pragma unroll
            for (int ni = 0; ni < 2; ++ni)
                acc[mi][ni] = __builtin_amdgcn_mfma_f32_16x16x32_f16(af[mi], bfr[ni], acc[mi][ni], 0, 0, 0);
    }
    ushort_t* Chp = C + (size_t)h * 65536;
#pragma unroll
    for (int mi = 0; mi < 2; ++mi)
#pragma unroll
        for (int ni = 0; ni < 2; ++ni)
#pragma unroll
            for (int q = 0; q < 4; ++q) {
                int r = row0 + wr + mi * 16 + lq + q;
                int c = col0 + wc + ni * 16 + lr;
                float v = ss * acc[mi][ni][q];
                if (r == c) v += diag;
                Chp[(size_t)r * 256 + c] = f2h(v);
                if (C2) {
                    float v2 = ss2 * acc[mi][ni][q];
                    if (r == c) v2 += diag2;
                    C2[(size_t)h * 65536 + (size_t)r * 256 + c] = f2h(v2);
                }
            }
}

// ---------------- generic fp16 A@B^T MFMA (per head) ----------------
__global__ __launch_bounds__(256) void hgemm_abT_k(
    const ushort_t* __restrict__ A, long sAh, int lda,
    const ushort_t* __restrict__ BT, long sBh, int ldb,
    ushort_t* __restrict__ C, long sCh, int ldc, int K)
{
    __shared__ ushort_t As[128 * 32];
    __shared__ ushort_t Bs[128 * 32];
    const int h = blockIdx.z;
    const ushort_t* Ah = A + (size_t)h * sAh;
    const ushort_t* Bh = BT + (size_t)h * sBh;
    ushort_t* Chp = C + (size_t)h * sCh;
    const int tid = threadIdx.x;
    const int wave = tid >> 6, lane = tid & 63;
    const int row0 = blockIdx.y * 128, col0 = blockIdx.x * 128;
    const int wr = (wave >> 1) * 64, wc = (wave & 1) * 64;
    const int sRow = wave * 16 + (lane >> 2);
    const int sChk = (lane & 3) * 8;
    const int lr = lane & 15, lk = (lane >> 4) * 8, lq = (lane >> 4) * 4;
    f32x4 acc[4][4] = {};
    for (int k0 = 0; k0 < K; k0 += 32) {
        __syncthreads();
#pragma unroll
        for (int i = 0; i < 2; ++i) {
            const ushort_t* gp = Ah + (size_t)(row0 + i * 64 + sRow) * lda + k0 + sChk;
            __builtin_amdgcn_global_load_lds(GPTR(gp), LPTR(As + (i * 64 + wave * 16) * 32), 16, 0, 0);
            const ushort_t* gq = Bh + (size_t)(col0 + i * 64 + sRow) * ldb + k0 + sChk;
            __builtin_amdgcn_global_load_lds(GPTR(gq), LPTR(Bs + (i * 64 + wave * 16) * 32), 16, 0, 0);
        }
        __syncthreads();
        half8 af[4], bfr[4];
#pragma unroll
        for (int mi = 0; mi < 4; ++mi)
            af[mi] = *reinterpret_cast<const half8*>(&As[(wr + mi * 16 + lr) * 32 + lk]);
#pragma unroll
        for (int ni = 0; ni < 4; ++ni)
            bfr[ni] = *reinterpret_cast<const half8*>(&Bs[(wc + ni * 16 + lr) * 32 + lk]);
#pragma unroll
        for (int mi = 0; mi < 4; ++mi)
#pragma unroll
            for (int ni = 0; ni < 4; ++ni)
                acc[mi][ni] = __builtin_amdgcn_mfma_f32_16x16x32_f16(af[mi], bfr[ni], acc[mi][ni], 0, 0, 0);
    }
#pragma unroll
    for (int mi = 0; mi < 4; ++mi)
#pragma unroll
        for (int q = 0; q < 4; ++q) {
            int r = row0 + wr + mi * 16 + lq + q;
#pragma unroll
            for (int ni = 0; ni < 4; ++ni)
                Chp[(size_t)r * ldc + col0 + wc + ni * 16 + lr] = f2h(acc[mi][ni][q]);
        }
}

// ---------------- fused rowmax+exp (in-place) + rowsum, rows of length NP ----------------
__global__ __launch_bounds__(256) void rs3exp_k(ushort_t* __restrict__ S, float* __restrict__ rsum)
{
    __shared__ float red[256];
    int row = blockIdx.x, tid = threadIdx.x;
    ushort_t* p = S + (size_t)row * NP;
    float mx = -1e30f;
    for (int i = tid; i < NP; i += 256) mx = fmaxf(mx, h2f(p[i]));
    mx = blockReduceMaxF(mx, red, tid);
    float s = 0.f;
    for (int i = tid; i < NP; i += 256) {
        float e = __expf(h2f(p[i]) - mx);
        p[i] = f2h(e);
        s += e;
    }
    s = blockReduceSumF(s, red, tid);
    if (!tid) rsum[row] = s;
}

// ---------------- fused rowmax+exp (in-place) + rowsum, rows of length 256, wave/row ----------------
__global__ __launch_bounds__(256) void rs1exp_k(ushort_t* __restrict__ S, float* __restrict__ rsum)
{
    int wave = threadIdx.x >> 6, lane = threadIdx.x & 63;
    size_t row = (size_t)blockIdx.x * 4 + wave;
    ushort_t* p = S + row * 256;
    ushort4 u = *reinterpret_cast<const ushort4*>(p + lane * 4);
    float v0 = h2f(u.x), v1 = h2f(u.y), v2 = h2f(u.z), v3 = h2f(u.w);
    float mx = fmaxf(fmaxf(v0, v1), fmaxf(v2, v3));
    for (int off = 32; off; off >>= 1) mx = fmaxf(mx, __shfl_xor(mx, off, 64));
    float e0 = __expf(v0 - mx), e1 = __expf(v1 - mx), e2 = __expf(v2 - mx), e3 = __expf(v3 - mx);
    ushort4 w;
    w.x = f2h(e0); w.y = f2h(e1); w.z = f2h(e2); w.w = f2h(e3);
    *reinterpret_cast<ushort4*>(p + lane * 4) = w;
    float s = e0 + e1 + e2 + e3;
    for (int off = 32; off; off >>= 1) s += __shfl_xor(s, off, 64);
    if (!lane) rsum[row] = s;
}

// ---------------- pv: split-K fp16 MFMA, part = P[256][NP] @ V[NP][64] ----------------
__global__ __launch_bounds__(256) void hgemm_pv_k(
    const ushort_t* __restrict__ P, const ushort_t* __restrict__ qkv16,
    float* __restrict__ part)
{
    __shared__ ushort_t As[128 * 32];
    __shared__ ushort_t Bs[64 * 32];
    const int ks = blockIdx.x, row0 = blockIdx.y * 128, h = blockIdx.z;
    const ushort_t* Ph = P + (size_t)h * 256 * NP;
    const ushort_t* V = qkv16 + 1024 + h * 64;
    const int tid = threadIdx.x;
    const int wave = tid >> 6, lane = tid & 63;
    const int wr = wave * 32;
    const int sRow = wave * 16 + (lane >> 2);
    const int sChk = (lane & 3) * 8;
    const int lr = lane & 15, lk = (lane >> 4) * 8, lq = (lane >> 4) * 4;
    const int kp = (tid >> 3) & 15, nc = tid & 7;
    const int kk = (kp * 2) ^ ((nc & 3) << 3);
    f32x4 acc[2][4] = {};
    for (int k0 = ks * KCH; k0 < (ks + 1) * KCH; k0 += 32) {
        __syncthreads();
#pragma unroll
        for (int i = 0; i < 2; ++i) {
            const ushort_t* gp = Ph + (size_t)(row0 + i * 64 + sRow) * NP + k0 + sChk;
            __builtin_amdgcn_global_load_lds(GPTR(gp), LPTR(As + (i * 64 + wave * 16) * 32), 16, 0, 0);
        }
        if (tid < 128) {
            const ushort_t* bp = V + (size_t)(k0 + kp * 2) * 1536 + nc * 8;
            short8 v0 = *reinterpret_cast<const short8*>(bp);
            short8 v1 = *reinterpret_cast<const short8*>(bp + 1536);
#pragma unroll
            for (int j = 0; j < 8; ++j) {
                unsigned int pk = ((unsigned int)(ushort_t)v1[j] << 16) | (unsigned int)(ushort_t)v0[j];
                *reinterpret_cast<unsigned int*>(&Bs[(nc * 8 + j) * 32 + kk]) = pk;
            }
        }
        __syncthreads();
        half8 af[2], bfr[4];
#pragma unroll
        for (int mi = 0; mi < 2; ++mi)
            af[mi] = *reinterpret_cast<const half8*>(&As[(wr + mi * 16 + lr) * 32 + lk]);
#pragma unroll
        for (int ni = 0; ni < 4; ++ni) {
            int nn = ni * 16 + lr;
            bfr[ni] = *reinterpret_cast<const half8*>(&Bs[nn * 32 + (lk ^ (((nn >> 3) & 3) << 3))]);
        }
#pragma unroll
        for (int mi = 0; mi < 2; ++mi)
#pragma unroll
            for (int ni = 0; ni < 4; ++ni)
                acc[mi][ni] = __builtin_amdgcn_mfma_f32_16x16x32_f16(af[mi], bfr[ni], acc[mi][ni], 0, 0, 0);
    }
    float* pp = part + ((size_t)(ks * 8 + h) * 256) * 64;
#pragma unroll
    for (int mi = 0; mi < 2; ++mi)
#pragma unroll
        for (int q = 0; q < 4; ++q) {
            int r = row0 + wr + mi * 16 + lq + q;
#pragma unroll
            for (int ni = 0; ni < 4; ++ni)
                pp[(size_t)r * 64 + ni * 16 + lr] = acc[mi][ni][q];
        }
}

__global__ __launch_bounds__(256) void pv_reduce_k(const float* __restrict__ part,
                                                   const float* __restrict__ rsum,
                                                   ushort_t* __restrict__ av)
{
    int idx = blockIdx.x * 256 + threadIdx.x;   // 131072
    int rc = idx >> 6;
    float s = 0.f;
#pragma unroll
    for (int ks = 0; ks < KSPLIT; ++ks)
        s += part[(size_t)ks * 131072 + idx];
    av[idx] = f2h(s / rsum[rc]);
}

// ---------------- W = z @ av (per head 256x256 @ 256x64), fp16 ----------------
__global__ void wmat_k(const ushort_t* __restrict__ z, const ushort_t* __restrict__ av,
                       ushort_t* __restrict__ W)
{
    int h = blockIdx.x >> 8, m = blockIdx.x & 255, d = threadIdx.x;
    const ushort_t* zp = z + (size_t)h * 65536 + (size_t)m * 256;
    const ushort_t* ap = av + (size_t)h * 16384 + d;
    float acc = 0.f;
    for (int j = 0; j < 256; ++j) acc += h2f(zp[j]) * h2f(ap[(size_t)j * 64]);
    W[((size_t)h * 256 + m) * 64 + d] = f2h(acc);
}

// ---------------- pw: attn = (P1 @ W) / rsum1 (fp16 MFMA, token-major out) ----------------
__global__ __launch_bounds__(256) void hgemm_pw_k(
    const ushort_t* __restrict__ P1, const ushort_t* __restrict__ W,
    const float* __restrict__ rsum, ushort_t* __restrict__ attn)
{
    __shared__ ushort_t As[128 * 32];
    __shared__ ushort_t Bs[64 * 32];
    const int row0 = blockIdx.y * 128, h = blockIdx.z;
    const ushort_t* Ph = P1 + (size_t)h * NP * 256;
    const ushort_t* Wh = W + (size_t)h * 16384;
    const int tid = threadIdx.x;
    const int wave = tid >> 6, lane = tid & 63;
    const int wr = wave * 32;
    const int sRow = wave * 16 + (lane >> 2);
    const int sChk = (lane & 3) * 8;
    const int lr = lane & 15, lk = (lane >> 4) * 8, lq = (lane >> 4) * 4;
    const int kp = (tid >> 3) & 15, nc = tid & 7;
    const int kk = (kp * 2) ^ ((nc & 3) << 3);
    f32x4 acc[2][4] = {};
    for (int k0 = 0; k0 < 256; k0 += 32) {
        __syncthreads();
#pragma unroll
        for (int i = 0; i < 2; ++i) {
            const ushort_t* gp = Ph + (size_t)(row0 + i * 64 + sRow) * 256 + k0 + sChk;
            __builtin_amdgcn_global_load_lds(GPTR(gp), LPTR(As + (i * 64 + wave * 16) * 32), 16, 0, 0);
        }
        if (tid < 128) {
            const ushort_t* bp = Wh + (size_t)(k0 + kp * 2) * 64 + nc * 8;
            short8 v0 = *reinterpret_cast<const short8*>(bp);
            short8 v1 = *reinterpret_cast<const short8*>(bp + 64);
#pragma unroll
            for (int j = 0; j < 8; ++j) {
                unsigned int pk = ((unsigned int)(ushort_t)v1[j] << 16) | (unsigned int)(ushort_t)v0[j];
                *reinterpret_cast<unsigned int*>(&Bs[(nc * 8 + j) * 32 + kk]) = pk;
            }
        }
        __syncthreads();
        half8 af[2], bfr[4];
#pragma unroll
        for (int mi = 0; mi < 2; ++mi)
            af[mi] = *reinterpret_cast<const half8*>(&As[(wr + mi * 16 + lr) * 32 + lk]);
#pragma unroll
        for (int ni = 0; ni < 4; ++ni) {
            int nn = ni * 16 + lr;
            bfr[ni] = *reinterpret_cast<const half8*>(&Bs[nn * 32 + (lk ^ (((nn >> 3) & 3) << 3))]);
        }
#pragma unroll
        for (int mi = 0; mi < 2; ++mi)
#pragma unroll
            for (int ni = 0; ni < 4; ++ni)
                acc[mi][ni] = __builtin_amdgcn_mfma_f32_16x16x32_f16(af[mi], bfr[ni], acc[mi][ni], 0, 0, 0);
    }
#pragma unroll
    for (int mi = 0; mi < 2; ++mi)
#pragma unroll
        for (int q = 0; q < 4; ++q) {
            int t = row0 + wr + mi * 16 + lq + q;
            float inv = 1.f / rsum[(size_t)h * NP + t];
#pragma unroll
            for (int ni = 0; ni < 4; ++ni)
                attn[(size_t)t * 512 + h * 64 + ni * 16 + lr] = f2h(acc[mi][ni][q] * inv);
        }
}

// ---------------- fixup: cls token + wrap rows ----------------
__global__ void fixup_k(const float* __restrict__ cls, float* __restrict__ h)
{
    int i = blockIdx.x * 256 + threadIdx.x;
    if (i < 512) {
        h[i] = cls[i];
    } else {
        int j = i - 512;
        h[(size_t)8193 * 512 + j] = h[512 + j];
    }
}

// ---------------- layernorm + front zero-pad: out[NP][512] fp16 ----------------
__global__ __launch_bounds__(256) void ln_pad_k(
    const float* __restrict__ h, const float* __restrict__ g, const float* __restrict__ b,
    ushort_t* __restrict__ out)
{
    int row = blockIdx.x, tid = threadIdx.x;
    __shared__ float red[256];
    ushort_t* o = out + (size_t)row * 512;
    if (row < PAD) { o[tid] = 0; o[tid + 256] = 0; return; }
    const float* x = h + (size_t)(row - PAD) * 512;
    float v0 = x[tid], v1 = x[tid + 256];
    float mu = blockReduceSumF(v0 + v1, red, tid) * (1.f / 512.f);
    float d0 = v0 - mu, d1 = v1 - mu;
    float var = blockReduceSumF(d0 * d0 + d1 * d1, red, tid) * (1.f / 512.f);
    float rstd = rsqrtf(var + 1e-5f);
    o[tid]       = f2h(d0 * rstd * g[tid] + b[tid]);
    o[tid + 256] = f2h(d1 * rstd * g[tid + 256] + b[tid + 256]);
}

// ---------------- landmark means (q already pre-scaled) ----------------
__global__ void landmark_k(const ushort_t* __restrict__ qkv, ushort_t* __restrict__ ql,
                           ushort_t* __restrict__ kl)
{
    int h = blockIdx.x >> 8, m = blockIdx.x & 255, d = threadIdx.x;
    const ushort_t* base = qkv + (size_t)(m * LCH) * 1536 + h * 64 + d;
    float sq = 0.f, sk = 0.f;
    for (int i = 0; i < LCH; ++i) {
        sq += h2f(base[(size_t)i * 1536]);
        sk += h2f(base[(size_t)i * 1536 + 512]);
    }
    ql[((size_t)h * 256 + m) * 64 + d] = f2h(sq * (1.f / (float)LCH));
    kl[((size_t)h * 256 + m) * 64 + d] = f2h(sk * (1.f / (float)LCH));
}

// ---------------- a2 = softmax(ql @ kl^T), fp16 out ----------------
__global__ __launch_bounds__(256) void a2_k(
    const ushort_t* __restrict__ ql, const ushort_t* __restrict__ kl, ushort_t* __restrict__ a2)
{
    int h = blockIdx.x >> 8, r = blockIdx.x & 255, tid = threadIdx.x;
    __shared__ float qv[64]; __shared__ float red[256];
    if (tid < 64) qv[tid] = h2f(ql[((size_t)h * 256 + r) * 64 + tid]);
    __syncthreads();
    const ushort_t* kp = kl + ((size_t)h * 256 + tid) * 64;
    float dot = 0.f;
#pragma unroll
    for (int d = 0; d < 64; ++d) dot += qv[d] * h2f(kp[d]);
    float mx = blockReduceMaxF(dot, red, tid);
    float e = expf(dot - mx);
    float s = blockReduceSumF(e, red, tid);
    a2[((size_t)h * 256 + r) * 256 + tid] = f2h(e / s);
}

// ---------------- pinv init: col = 1 exactly (softmax rows), so scal = 1/max(colsum) ----------------
__global__ __launch_bounds__(256) void colsum_k(const ushort_t* __restrict__ a2, float* __restrict__ cs)
{
    int h = blockIdx.x >> 8, c = blockIdx.x & 255;
    __shared__ float red[256];
    float v = fabsf(h2f(a2[(size_t)h * 65536 + (size_t)threadIdx.x * 256 + c]));
    float s = blockReduceSumF(v, red, threadIdx.x);
    if (!threadIdx.x) cs[blockIdx.x] = s;
}
__global__ __launch_bounds__(256) void pinv_scal_k(const float* __restrict__ cs, float* __restrict__ scal)
{
    int tid = threadIdx.x; __shared__ float red[256];
    float m2 = -1e30f;
    for (int i = tid; i < 2048; i += 256) m2 = fmaxf(m2, cs[i]);
    m2 = blockReduceMaxF(m2, red, tid);
    if (!tid) scal[0] = 1.f / m2;
}
__global__ __launch_bounds__(256) void zinit_k(const ushort_t* __restrict__ a2, const float* __restrict__ scal,
                                               ushort_t* __restrict__ z)
{
    int h = blockIdx.x >> 8, r = blockIdx.x & 255, c = threadIdx.x;
    z[(size_t)h * 65536 + (size_t)r * 256 + c] =
        f2h(h2f(a2[(size_t)h * 65536 + (size_t)c * 256 + r]) * scal[0]);
}

// ---------------- tiled depthwise 33-tap conv over tokens on v (fp16), added to fp16 attn ----------------
#define CTT 64
__global__ __launch_bounds__(256) void conv2_k(const ushort_t* __restrict__ qkv,
                                               const float* __restrict__ cw,
                                               ushort_t* __restrict__ attn)
{
    __shared__ float vt[CTT + 32][64];
    int t0 = blockIdx.x * CTT;
    int h = blockIdx.y;
    int tid = threadIdx.x;
    for (int s = tid; s < (CTT + 32) * 8; s += 256) {
        int row = s >> 3, q8 = s & 7;
        int tt = t0 - 16 + row;
        if (tt >= 0 && tt < NP) {
            short8 v = *reinterpret_cast<const short8*>(qkv + (size_t)tt * 1536 + 1024 + h * 64 + q8 * 8);
#pragma unroll
            for (int j = 0; j < 8; ++j) vt[row][q8 * 8 + j] = h2f((ushort_t)v[j]);
        } else {
#pragma unroll
            for (int j = 0; j < 8; ++j) vt[row][q8 * 8 + j] = 0.f;
        }
    }
    float w33[33];
#pragma unroll
    for (int j = 0; j < 33; ++j) w33[j] = cw[h * 33 + j];
    __syncthreads();
    int c = tid & 63, tr = tid >> 6;
    float win[48];
#pragma unroll
    for (int j = 0; j < 48; ++j) win[j] = vt[tr * 16 + j][c];
#pragma unroll
    for (int i = 0; i < 16; ++i) {
        float acc = 0.f;
#pragma unroll
        for (int j = 0; j < 33; ++j) acc += w33[j] * win[i + j];
        size_t idx = (size_t)(t0 + tr * 16 + i) * 512 + h * 64 + c;
        attn[idx] = f2h(h2f(attn[idx]) + acc);
    }
}

// ---------------- PPEG tiled (fp16 LDS staging for occupancy) ----------------
#define PTS  16
#define PIT  22
#define PITT (PIT*PIT)
#define PCG  16
__global__ __launch_bounds__(256) void ppeg_tiled_k(
    const float* __restrict__ hin,
    const float* __restrict__ w7, const float* __restrict__ b7,
    const float* __restrict__ w5, const float* __restrict__ b5,
    const float* __restrict__ w3, const float* __restrict__ b3,
    float* __restrict__ hout)
{
    __shared__ ushort_t inb[PCG][PITT + 3];
    __shared__ float wc[PCG][49];
    __shared__ float bs[PCG];
    int tid = threadIdx.x;
    int c0 = blockIdx.z * PCG;
    int ty0 = blockIdx.y * PTS, tx0 = blockIdx.x * PTS;
    if (blockIdx.x == 0 && blockIdx.y == 0 && tid < PCG)
        hout[c0 + tid] = hin[c0 + tid];
    for (int idx = tid; idx < PITT * (PCG / 4); idx += 256) {
        int tok = idx >> 2, q = idx & 3;
        int gy = ty0 - 3 + tok / PIT, gx = tx0 - 3 + tok % PIT;
        float4 v = make_float4(0.f, 0.f, 0.f, 0.f);
        if (gy >= 0 && gy < HS && gx >= 0 && gx < HS)
            v = *reinterpret_cast<const float4*>(hin + (size_t)(1 + gy * HS + gx) * 512 + c0 + q * 4);
        inb[q * 4 + 0][tok] = f2h(v.x); inb[q * 4 + 1][tok] = f2h(v.y);
        inb[q * 4 + 2][tok] = f2h(v.z); inb[q * 4 + 3][tok] = f2h(v.w);
    }
    for (int idx = tid; idx < PCG * 49; idx += 256) {
        int c = idx / 49, t = idx % 49;
        int ky = t / 7, kx = t % 7, dy = ky - 3, dx = kx - 3;
        float w = w7[(size_t)(c0 + c) * 49 + t];
        if (dy >= -2 && dy <= 2 && dx >= -2 && dx <= 2)
            w += w5[(size_t)(c0 + c) * 25 + (dy + 2) * 5 + (dx + 2)];
        if (dy >= -1 && dy <= 1 && dx >= -1 && dx <= 1)
            w += w3[(size_t)(c0 + c) * 9 + (dy + 1) * 3 + (dx + 1)];
        wc[c][t] = w;
    }
    if (tid < PCG) bs[tid] = b7[c0 + tid] + b5[c0 + tid] + b3[c0 + tid];
    __syncthreads();
    int oy = tid >> 4, ox = tid & 15;
    int gy = ty0 + oy, gx = tx0 + ox;
    if (gy >= HS || gx >= HS) return;
    float* out = hout + (size_t)(1 + gy * HS + gx) * 512 + c0;
#pragma unroll 4
    for (int c = 0; c < PCG; ++c) {
        float acc = h2f(inb[c][(oy + 3) * PIT + ox + 3]) + bs[c];
#pragma unroll
        for (int ky = 0; ky < 7; ++ky)
#pragma unroll
            for (int kx = 0; kx < 7; ++kx)
                acc += wc[c][ky * 7 + kx] * h2f(inb[c][(oy + ky) * PIT + ox + kx]);
        out[c] = acc;
    }
}

// ---------------- final LN(row0) + fc2 + softmax + argmax ----------------
__global__ __launch_bounds__(256) void final_k(const float* __restrict__ h,
                                               const float* __restrict__ g, const float* __restrict__ bb,
                                               const float* __restrict__ w, const float* __restrict__ fb,
                                               float* __restrict__ out)
{
    __shared__ float red[256];
    int tid = threadIdx.x;
    float v0 = h[tid], v1 = h[tid + 256];
    float mu = blockReduceSumF(v0 + v1, red, tid) * (1.f / 512.f);
    float d0 = v0 - mu, d1 = v1 - mu;
    float var = blockReduceSumF(d0 * d0 + d1 * d1, red, tid) * (1.f / 512.f);
    float rstd = rsqrtf(var + 1e-5f);
    float e0 = d0 * rstd * g[tid] + bb[tid];
    float e1 = d1 * rstd * g[tid + 256] + bb[tid + 256];
    out[5 + tid] = e0;
    out[5 + 256 + tid] = e1;
    float l0p = e0 * w[tid * 2] + e1 * w[(tid + 256) * 2];
    float l1p = e0 * w[tid * 2 + 1] + e1 * w[(tid + 256) * 2 + 1];
    float l0 = blockReduceSumF(l0p, red, tid);
    float l1 = blockReduceSumF(l1p, red, tid);
    if (!tid) {
        l0 += fb[0]; l1 += fb[1];
        out[0] = l0; out[1] = l1;
        float mx = fmaxf(l0, l1);
        float p0 = expf(l0 - mx), p1 = expf(l1 - mx);
        float si = 1.f / (p0 + p1);
        out[2] = p0 * si; out[3] = p1 * si;
        out[4] = (l1 > l0) ? 1.f : 0.f;
    }
}

// ---------------- host orchestration ----------------
struct WsPtrs {
    float *h, *h2, *cs, *scal, *rsum3, *rsum1, *part;
    ushort_t *xbB, *qkv16, *ql16, *kl16, *a2h, *zh, *z2h, *xzh, *t1h, *t2h;
    ushort_t *av16, *W16, *qkvT, *outT, *x16, *fc1T, *S16;
};

static void run_attn(float* hbuf, const float* ln_g, const float* ln_b,
                     const float* qkv_w, const float* out_w, const float* out_b,
                     const float* conv_w, const WsPtrs& P, hipStream_t s)
{
    tcast_k<<<dim3(1536 / 32, 512 / 32), 256, 0, s>>>(qkv_w, P.qkvT, 512, 1536);
    tcast_k<<<dim3(512 / 32, 512 / 32), 256, 0, s>>>(out_w, P.outT, 512, 512);
    ln_pad_k<<<NP, 256, 0, s>>>(hbuf, ln_g, ln_b, P.xbB);
    gemm_f16<<<dim3(1536 / 128, NP / 128), 256, 0, s>>>(P.xbB, P.qkvT, nullptr, nullptr,
                                                        nullptr, P.qkv16, NP, 512, 512, 512, 1536, 0, 1);
    landmark_k<<<2048, 64, 0, s>>>(P.qkv16, P.ql16, P.kl16);
    a2_k<<<2048, 256, 0, s>>>(P.ql16, P.kl16, P.a2h);
    colsum_k<<<2048, 256, 0, s>>>(P.a2h, P.cs);
    pinv_scal_k<<<1, 256, 0, s>>>(P.cs, P.scal);
    zinit_k<<<2048, 256, 0, s>>>(P.a2h, P.scal, P.zh);
    ushort_t* za = P.zh; ushort_t* zb = P.z2h;
    for (int it = 0; it < 6; ++it) {
        bgemm64_f16<<<dim3(4, 4, 8), 256, 0, s>>>(P.a2h, za, P.xzh, 0.f, 1.f, P.t1h, 7.f, -1.f);
        bgemm64_f16<<<dim3(4, 4, 8), 256, 0, s>>>(P.xzh, P.t1h, P.t2h, 15.f, -1.f, nullptr, 0.f, 0.f);
        bgemm64_f16<<<dim3(4, 4, 8), 256, 0, s>>>(P.xzh, P.t2h, P.t1h, 13.f, -1.f, nullptr, 0.f, 0.f);
        bgemm64_f16<<<dim3(4, 4, 8), 256, 0, s>>>(za, P.t1h, zb, 0.f, 0.25f, nullptr, 0.f, 0.f);
        ushort_t* tmp = za; za = zb; zb = tmp;
    }
    // av path
    hgemm_abT_k<<<dim3(NP / 128, 2, 8), 256, 0, s>>>(P.ql16, 16384, 64,
                                                     P.qkv16 + 512, 64, 1536,
                                                     P.S16, (long)256 * NP, NP, 64);
    rs3exp_k<<<2048, 256, 0, s>>>(P.S16, P.rsum3);
    hgemm_pv_k<<<dim3(KSPLIT, 2, 8), 256, 0, s>>>(P.S16, P.qkv16, P.part);
    pv_reduce_k<<<512, 256, 0, s>>>(P.part, P.rsum3, P.av16);
    wmat_k<<<2048, 64, 0, s>>>(za, P.av16, P.W16);
    // a1 path
    hgemm_abT_k<<<dim3(2, NP / 128, 8), 256, 0, s>>>(P.qkv16, 64, 1536,
                                                     P.kl16, 16384, 64,
                                                     P.S16, (long)NP * 256, 256, 64);
    rs1exp_k<<<(8 * NP) / 4, 256, 0, s>>>(P.S16, P.rsum1);
    hgemm_pw_k<<<dim3(1, NP / 128, 8), 256, 0, s>>>(P.S16, P.W16, P.rsum1, P.xbB);
    conv2_k<<<dim3(NP / CTT, 8), 256, 0, s>>>(P.qkv16, conv_w, P.xbB);
    gemm_f16<<<dim3(512 / 128, (N1 + 127) / 128), 256, 0, s>>>(P.xbB + (size_t)PAD * 512, P.outT,
                                                               out_b, hbuf, hbuf, nullptr,
                                                               N1, 512, 512, 512, 512, 0, 0);
}

extern "C" void kernel_launch(void* const* d_in, const int* in_sizes, int n_in,
                              void* d_out, int out_size, void* d_ws, size_t ws_size,
                              hipStream_t stream)
{
    (void)in_sizes; (void)n_in; (void)out_size; (void)ws_size;
    const float* x       = (const float*)d_in[0];
    const float* fc1_w   = (const float*)d_in[1];
    const float* fc1_b   = (const float*)d_in[2];
    const float* cls_tok = (const float*)d_in[3];
    const float* ln1_g   = (const float*)d_in[4];
    const float* ln1_b   = (const float*)d_in[5];
    const float* qkv1_w  = (const float*)d_in[6];
    const float* out1_w  = (const float*)d_in[7];
    const float* out1_b  = (const float*)d_in[8];
    const float* conv1_w = (const float*)d_in[9];
    const float* ln2_g   = (const float*)d_in[10];
    const float* ln2_b   = (const float*)d_in[11];
    const float* qkv2_w  = (const float*)d_in[12];
    const float* out2_w  = (const float*)d_in[13];
    const float* out2_b  = (const float*)d_in[14];
    const float* conv2_w = (const float*)d_in[15];
    const float* pg7_w   = (const float*)d_in[16];
    const float* pg7_b   = (const float*)d_in[17];
    const float* pg5_w   = (const float*)d_in[18];
    const float* pg5_b   = (const float*)d_in[19];
    const float* pg3_w   = (const float*)d_in[20];
    const float* pg3_b   = (const float*)d_in[21];
    const float* norm_g  = (const float*)d_in[22];
    const float* norm_b  = (const float*)d_in[23];
    const float* fc2_w   = (const float*)d_in[24];
    const float* fc2_b   = (const float*)d_in[25];

    float* ws = (float*)d_ws;
    WsPtrs P;
    float* cur = ws;
    P.h     = cur; cur += (size_t)N1 * 512;
    P.h2    = cur; cur += (size_t)N1 * 512;
    P.xbB   = (ushort_t*)cur; cur += (size_t)NP * 512 / 2;
    P.qkv16 = (ushort_t*)cur; cur += (size_t)NP * 1536 / 2;
    P.ql16  = (ushort_t*)cur; cur += 65536;
    P.kl16  = (ushort_t*)cur; cur += 65536;
    P.a2h   = (ushort_t*)cur; cur += 262144;
    P.zh    = (ushort_t*)cur; cur += 262144;
    P.z2h   = (ushort_t*)cur; cur += 262144;
    P.xzh   = (ushort_t*)cur; cur += 262144;
    P.t1h   = (ushort_t*)cur; cur += 262144;
    P.t2h   = (ushort_t*)cur; cur += 262144;
    P.av16  = (ushort_t*)cur; cur += 65536;
    P.W16   = (ushort_t*)cur; cur += 65536;
    P.cs    = cur; cur += 2048;
    P.scal  = cur; cur += 64;
    P.qkvT  = (ushort_t*)cur; cur += 393216 + 64;   // 1536x512 halfs
    P.outT  = (ushort_t*)cur; cur += 131072 + 64;   // 512x512 halfs
    P.rsum3 = cur; cur += 2048;
    P.rsum1 = cur; cur += (size_t)8 * NP;
    P.part  = cur; cur += (size_t)KSPLIT * 131072;
    P.S16   = (ushort_t*)cur; cur += (size_t)8 * 256 * NP / 2;
    P.x16   = P.S16;                                         // 8192x1024 halfs (alias, pre-S use)
    P.fc1T  = P.S16 + (size_t)NTOK * INDIM;                  // 512x1024 halfs

    bcast_k<<<(NTOK * INDIM) / 1024, 256, 0, stream>>>(x, P.x16);
    tcast_k<<<dim3(512 / 32, 1024 / 32), 256, 0, stream>>>(fc1_w, P.fc1T, 1024, 512);
    gemm_f16<<<dim3(512 / 128, NTOK / 128), 256, 0, stream>>>(P.x16, P.fc1T, fc1_b, nullptr,
                                                              P.h + 512, nullptr,
                                                              NTOK, 1024, 1024, 1024, 512, 1, 0);
    fixup_k<<<180, 256, 0, stream>>>(cls_tok, P.h);
    run_attn(P.h, ln1_g, ln1_b, qkv1_w, out1_w, out1_b, conv1_w, P, stream);
    ppeg_tiled_k<<<dim3(6, 6, 512 / PCG), 256, 0, stream>>>(P.h, pg7_w, pg7_b, pg5_w, pg5_b,
                                                            pg3_w, pg3_b, P.h2);
    run_attn(P.h2, ln2_g, ln2_b, qkv2_w, out2_w, out2_b, conv2_w, P, stream);
    final_k<<<1, 256, 0, stream>>>(P.h2, norm_g, norm_b, fc2_w, fc2_b, (float*)d_out);
}